// Round 13
// baseline (564.293 us; speedup 1.0000x reference)
//
#include <hip/hip_runtime.h>
#include <cstdint>
#include <cstddef>

#define N_NODES 50000
#define N_EDGES 500000
#define NG 512
#define HID 256
#define EPS 1e-5f
#define SCB 49  // scan blocks: ceil(50000/1024)

typedef __attribute__((ext_vector_type(8))) __bf16 bf16x8;
typedef __attribute__((ext_vector_type(8))) ushort u16x8;
typedef __attribute__((ext_vector_type(4))) float f32x4;

__device__ __forceinline__ ushort f2bf(float f) {
  uint32_t u = __float_as_uint(f);
  uint32_t r = (u + 0x7fffu + ((u >> 16) & 1u)) >> 16;
  return (ushort)r;
}
__device__ __forceinline__ float bfu(ushort u) { return __uint_as_float(((uint32_t)u) << 16); }
__device__ __forceinline__ float4 bf4(ushort4 u) {
  return make_float4(bfu(u.x), bfu(u.y), bfu(u.z), bfu(u.w));
}

// ---------------- CSR build ----------------
__global__ void k_csr_count(const int* __restrict__ ei, int* __restrict__ cnt) {
  int e = blockIdx.x * 256 + threadIdx.x;
  if (e < N_EDGES) atomicAdd(&cnt[ei[N_EDGES + e]], 1);
}

__global__ void k_scan_part(const int* __restrict__ cnt, int* __restrict__ psum) {
  __shared__ int red[256];
  int tid = threadIdx.x;
  int i0 = blockIdx.x * 1024 + tid * 4;
  int s = 0;
  if (i0 + 4 <= N_NODES) {
    int4 v = *reinterpret_cast<const int4*>(cnt + i0);
    s = v.x + v.y + v.z + v.w;
  } else {
    for (int k = 0; k < 4; k++)
      if (i0 + k < N_NODES) s += cnt[i0 + k];
  }
  red[tid] = s;
  __syncthreads();
  for (int o = 128; o > 0; o >>= 1) {
    if (tid < o) red[tid] += red[tid + o];
    __syncthreads();
  }
  if (tid == 0) psum[blockIdx.x] = red[0];
}

__global__ void k_scan_top(const int* __restrict__ psum, int* __restrict__ boff,
                           int* __restrict__ row_ptr) {
  int t = threadIdx.x;  // 64
  int v = (t < SCB) ? psum[t] : 0;
  int own = v;
  for (int o = 1; o < 64; o <<= 1) {
    int u = __shfl_up(v, o);
    if (t >= o) v += u;
  }
  if (t < SCB) boff[t] = v - own;
  if (t == 63) row_ptr[N_NODES] = v;
}

__global__ void k_scan_out(const int* __restrict__ cnt, const int* __restrict__ boff,
                           int* __restrict__ row_ptr, float* __restrict__ dis) {
  __shared__ int ps[256];
  int tid = threadIdx.x;
  int i0 = blockIdx.x * 1024 + tid * 4;
  int v[4];
#pragma unroll
  for (int k = 0; k < 4; k++) v[k] = (i0 + k < N_NODES) ? cnt[i0 + k] : 0;
  int s = v[0] + v[1] + v[2] + v[3];
  ps[tid] = s;
  __syncthreads();
  for (int o = 1; o < 256; o <<= 1) {
    int add = (tid >= o) ? ps[tid - o] : 0;
    __syncthreads();
    ps[tid] += add;
    __syncthreads();
  }
  int run = boff[blockIdx.x] + ((tid > 0) ? ps[tid - 1] : 0);
#pragma unroll
  for (int k = 0; k < 4; k++) {
    if (i0 + k < N_NODES) {
      row_ptr[i0 + k] = run;
      dis[i0 + k] = rsqrtf((float)v[k] + 1.0f);
      run += v[k];
    }
  }
}

__global__ void k_csr_fill(const int* __restrict__ ei, const int* __restrict__ row_ptr,
                           int* __restrict__ fill, int* __restrict__ col_src) {
  int e = blockIdx.x * 256 + threadIdx.x;
  if (e >= N_EDGES) return;
  int s = ei[e], d = ei[N_EDGES + e];
  int pos = row_ptr[d] + atomicAdd(&fill[d], 1);
  col_src[pos] = s;
}

// ---------------- batched weight transpose: W[K,C] fp32 -> Wt[C,K] bf16 ----------------
struct WtArgs {
  const float* src[6];
  ushort* dst[6];
  int K[6];
  int C[6];
  int off[6];
};

__global__ void k_wt_all(WtArgs a) {
  int b = blockIdx.x;
  int ji = 0;
#pragma unroll
  for (int t = 1; t < 6; t++)
    if (b >= a.off[t]) ji = t;
  int K = a.K[ji], C = a.C[ji];
  int i = (b - a.off[ji]) * 256 + threadIdx.x;
  int c = i / K, k = i - c * K;
  a.dst[ji][i] = f2bf(a.src[ji][k * C + c]);
}

// ---------------- weight fold: Wc_t[c][k] = sum_j W_emb[k][j]*W_gcn[j][c]; bc = b_emb@W_gcn --
__global__ void k_wfold(const float* __restrict__ We, const ushort* __restrict__ Wg_t,
                        ushort* __restrict__ Wc_t, float* __restrict__ bc,
                        const float* __restrict__ b_emb, const float* __restrict__ W_gcn) {
  int c = blockIdx.x;      // 256
  int k = threadIdx.x;     // 128
  const float* wr = We + k * 256;
  const ushort* gr = Wg_t + c * 256;
  float s = 0.f;
  for (int j = 0; j < 256; j++) s = fmaf(wr[j], bfu(gr[j]), s);
  Wc_t[c * 128 + k] = f2bf(s);
  if (k == 0) {
    float t = 0.f;
    for (int j = 0; j < 256; j++) t = fmaf(b_emb[j], W_gcn[j * 256 + c], t);
    bc[c] = t;
  }
}

// ---------------- MFMA GEMM: 64-row/256-thread blocks, K-split double-buffered panels -------
// out_bf[M,C] = A1@W1t^T (+A2@W2t^T) + bias. Wt [C,K] bf16. Grid: ceil(M/64) = 782.
// Sub-step = (panel, pass, k-half); half-panels double-buffered in LDS.
// BNF: A = hbuf + relu(A1v*sc+sh) inline (BN fold); hbuf written back.
// GATE: fused gate head. GATAL: fused attention logits -> als/ald[node][head].
template <int K, int C, bool DUAL, bool AFP32, bool GATE, bool GATAL, bool BNF>
__global__ __launch_bounds__(256) void k_mgemm(
    const void* __restrict__ A1v, const ushort* __restrict__ W1t,
    const ushort* __restrict__ A2, const ushort* __restrict__ W2t,
    const float* __restrict__ bias, ushort* __restrict__ out_bf,
    const float* __restrict__ gw, const float* __restrict__ gb,
    float* __restrict__ gate, const float* __restrict__ asv,
    const float* __restrict__ adv, float* __restrict__ als,
    float* __restrict__ ald, const float* __restrict__ scsh,
    ushort* __restrict__ hbuf, int M, int relu) {
  constexpr int KS = K / 32;             // MFMA k-steps total
  constexpr int KSH = KS / 2;            // k-steps per half
  constexpr int KHALF = K / 2;
  constexpr int CHKH = KHALF / 8;        // 16B chunks per col per half
  constexpr int NPAN = C / 64;
  constexpr int LOWB = DUAL ? 4 : 2;     // sub-steps per panel
  constexpr int NTOT = NPAN * LOWB;
  constexpr int NISS = (64 * CHKH) / 256;
  constexpr int PELEM = 64 * KHALF;      // ushorts per half-panel buffer
  __shared__ ushort wlds[2 * PELEM];
  const int tid = threadIdx.x;
  const int lane = tid & 63;
  const int wid = tid >> 6;
  const int r16 = lane & 15;
  const int kg = lane >> 4;
  const int rbase = blockIdx.x * 64 + wid * 16;

  const bool avalid = (rbase + r16) < M;
  int arow = rbase + r16;
  if (arow >= M) arow = M - 1;

  // A fragments, loaded once
  bf16x8 af[KS], af2[KS];
  if constexpr (BNF) {
    const ushort* xp = (const ushort*)A1v + (size_t)arow * K + kg * 8;
    ushort* hp = hbuf + (size_t)arow * K + kg * 8;
#pragma unroll
    for (int ks = 0; ks < KS; ks++) {
      int col = kg * 8 + ks * 32;
      u16x8 xv = *reinterpret_cast<const u16x8*>(xp + ks * 32);
      u16x8 hv = *reinterpret_cast<const u16x8*>(hp + ks * 32);
      float4 sc0 = *reinterpret_cast<const float4*>(scsh + col);
      float4 sc1 = *reinterpret_cast<const float4*>(scsh + col + 4);
      float4 sh0 = *reinterpret_cast<const float4*>(scsh + 256 + col);
      float4 sh1 = *reinterpret_cast<const float4*>(scsh + 256 + col + 4);
      float scv[8] = {sc0.x, sc0.y, sc0.z, sc0.w, sc1.x, sc1.y, sc1.z, sc1.w};
      float shv[8] = {sh0.x, sh0.y, sh0.z, sh0.w, sh1.x, sh1.y, sh1.z, sh1.w};
      union { u16x8 u; bf16x8 b; } cv;
#pragma unroll
      for (int j = 0; j < 8; j++) {
        float v = fmaf(bfu(xv[j]), scv[j], shv[j]);
        float hn = bfu(hv[j]) + fmaxf(v, 0.f);
        cv.u[j] = f2bf(hn);
      }
      af[ks] = cv.b;
      if (avalid) *reinterpret_cast<u16x8*>(hp + ks * 32) = cv.u;
    }
  } else if constexpr (AFP32) {
    const float* ap = (const float*)A1v + (size_t)arow * K + kg * 8;
#pragma unroll
    for (int ks = 0; ks < KS; ks++) {
      float4 lo = *reinterpret_cast<const float4*>(ap + ks * 32);
      float4 hi = *reinterpret_cast<const float4*>(ap + ks * 32 + 4);
      union { u16x8 u; bf16x8 b; } cv;
      cv.u = (u16x8){f2bf(lo.x), f2bf(lo.y), f2bf(lo.z), f2bf(lo.w),
                     f2bf(hi.x), f2bf(hi.y), f2bf(hi.z), f2bf(hi.w)};
      af[ks] = cv.b;
    }
  } else {
    const ushort* ap = (const ushort*)A1v + (size_t)arow * K + kg * 8;
#pragma unroll
    for (int ks = 0; ks < KS; ks++)
      af[ks] = *reinterpret_cast<const bf16x8*>(ap + ks * 32);
  }
  if constexpr (DUAL) {
    const ushort* ap = A2 + (size_t)arow * K + kg * 8;
#pragma unroll
    for (int ks = 0; ks < KS; ks++)
      af2[ks] = *reinterpret_cast<const bf16x8*>(ap + ks * 32);
  }

  float greg[4] = {0.f, 0.f, 0.f, 0.f};
  f32x4 acc[4];

  // async stage of one K-half panel; linear LDS chunk p = c*CHKH + jj holds
  // W[c, kh*KHALF + (jj^(c&7))*8 ..], so read-side swizzle sees W(c,m) at c*CHKH+(m^(c&7)).
#define STAGE_ASYNC(WSRC, PAN, KH, BUF)                                        \
  {                                                                            \
    const ushort* base_ = (WSRC) + (size_t)((PAN) * 64) * K + (KH) * KHALF;    \
    _Pragma("unroll") for (int j = 0; j < NISS; j++) {                         \
      int p_ = j * 256 + tid;                                                  \
      int c_ = p_ / CHKH, jj_ = p_ % CHKH;                                     \
      const ushort* g_ = base_ + c_ * K + (jj_ ^ (c_ & 7)) * 8;                \
      ushort* l_ = &wlds[(BUF) * PELEM + (j * 256 + wid * 64) * 8];            \
      __builtin_amdgcn_global_load_lds(                                        \
          (const __attribute__((address_space(1))) void*)(g_),                 \
          (__attribute__((address_space(3))) void*)(l_), 16, 0, 0);            \
    }                                                                          \
  }

#define COMPUTE(AF, KH, BUF)                                                   \
  {                                                                            \
    const ushort* wb_ = &wlds[(BUF) * PELEM];                                  \
    _Pragma("unroll") for (int ct = 0; ct < 4; ct++) {                         \
      bf16x8 wf[KSH];                                                          \
      int colr = ct * 16 + r16;                                                \
      _Pragma("unroll") for (int ksl = 0; ksl < KSH; ksl++) {                  \
        int slot = colr * CHKH + ((ksl * 4 + kg) ^ (r16 & 7));                 \
        wf[ksl] = *reinterpret_cast<const bf16x8*>(&wb_[slot * 8]);            \
      }                                                                        \
      _Pragma("unroll") for (int ksl = 0; ksl < KSH; ksl++)                    \
        acc[ct] = __builtin_amdgcn_mfma_f32_16x16x32_bf16(                     \
            (AF)[(KH) * KSH + ksl], wf[ksl], acc[ct], 0, 0, 0);                \
    }                                                                          \
  }

  // prologue: stage sub-step 0 (panel 0, pass 0, half 0) into buffer 0
  STAGE_ASYNC(W1t, 0, 0, 0);
  __syncthreads();

#pragma unroll
  for (int q = 0; q < NTOT; q++) {
    const int kh = q & 1;
    const int pass = DUAL ? ((q >> 1) & 1) : 0;
    const int pan = DUAL ? (q >> 2) : (q >> 1);
    const int bufq = q & 1;
    const int c0 = pan * 64;
    if ((q & (LOWB - 1)) == 0) {
#pragma unroll
      for (int ct = 0; ct < 4; ct++) acc[ct] = (f32x4){0.f, 0.f, 0.f, 0.f};
    }
    // issue next sub-step's async loads into the other buffer
    if (q + 1 < NTOT) {
      const int nkh = (q + 1) & 1;
      const int npass = DUAL ? (((q + 1) >> 1) & 1) : 0;
      const int npan = DUAL ? ((q + 1) >> 2) : ((q + 1) >> 1);
      const ushort* Wq = (DUAL && npass) ? W2t : W1t;
      STAGE_ASYNC(Wq, npan, nkh, bufq ^ 1);
    }
    // compute current sub-step from LDS
    if (DUAL && pass) {
      COMPUTE(af2, kh, bufq);
    } else {
      COMPUTE(af, kh, bufq);
    }
    // epilogue when panel complete
    if ((q & (LOWB - 1)) == (LOWB - 1)) {
      if constexpr (GATE) {
#pragma unroll
        for (int ct = 0; ct < 4; ct++) {
          int col = c0 + ct * 16 + r16;
          float bv = bias[col];
          float wv = gw[col];
#pragma unroll
          for (int i = 0; i < 4; i++) {
            float v = fmaxf(acc[ct][i] + bv, 0.f);
            greg[i] = fmaf(v, wv, greg[i]);
          }
        }
      } else {
#pragma unroll
        for (int ct = 0; ct < 4; ct++) {
          int col = c0 + ct * 16 + r16;
          float bv = bias ? bias[col] : 0.f;
#pragma unroll
          for (int i = 0; i < 4; i++) {
            int row = rbase + kg * 4 + i;
            if (row < M) {
              float v = acc[ct][i] + bv;
              if (relu) v = fmaxf(v, 0.f);
              out_bf[(size_t)row * C + col] = f2bf(v);
            }
          }
        }
      }
      if constexpr (GATAL) {
        // fused GAT attention logits, [node][head] layout (edge-gather friendly)
        float ps_[2][4], pd_[2][4];
#pragma unroll
        for (int h2 = 0; h2 < 2; h2++)
#pragma unroll
          for (int i = 0; i < 4; i++) { ps_[h2][i] = 0.f; pd_[h2][i] = 0.f; }
#pragma unroll
        for (int ct = 0; ct < 4; ct++) {
          int col = c0 + ct * 16 + r16;
          float as_ = asv[col], ad_ = adv[col];
          int h2 = ct >> 1;
#pragma unroll
          for (int i = 0; i < 4; i++) {
            ps_[h2][i] = fmaf(acc[ct][i], as_, ps_[h2][i]);
            pd_[h2][i] = fmaf(acc[ct][i], ad_, pd_[h2][i]);
          }
        }
#pragma unroll
        for (int h2 = 0; h2 < 2; h2++)
#pragma unroll
          for (int i = 0; i < 4; i++) {
#pragma unroll
            for (int o = 1; o < 16; o <<= 1) {
              ps_[h2][i] += __shfl_xor(ps_[h2][i], o);
              pd_[h2][i] += __shfl_xor(pd_[h2][i], o);
            }
          }
        if (r16 == 0) {
#pragma unroll
          for (int i = 0; i < 4; i++) {
            int row = rbase + kg * 4 + i;
            if (row < M) {
              als[row * 8 + pan * 2 + 0] = ps_[0][i];
              ald[row * 8 + pan * 2 + 0] = pd_[0][i];
              als[row * 8 + pan * 2 + 1] = ps_[1][i];
              ald[row * 8 + pan * 2 + 1] = pd_[1][i];
            }
          }
        }
      }
    }
    __syncthreads();  // drains next sub-step loads + read fence
  }

  if constexpr (GATE) {
#pragma unroll
    for (int i = 0; i < 4; i++) {
#pragma unroll
      for (int o = 1; o < 16; o <<= 1) greg[i] += __shfl_xor(greg[i], o);
    }
    if (r16 == 0) {
      float b0 = gb[0];
#pragma unroll
      for (int i = 0; i < 4; i++) {
        int row = rbase + kg * 4 + i;
        if (row < M) gate[row] = greg[i] + b0;
      }
    }
  }
#undef STAGE_ASYNC
#undef COMPUTE
}

// ---------------- GCN aggregation: wave/node, 32 lanes/row, 8-edge ILP, bf16 out ------------
__global__ void k_gcn_agg(const ushort* __restrict__ xt, const float* __restrict__ dis,
                          const int* __restrict__ row_ptr, const int* __restrict__ col_src,
                          const float* __restrict__ b_gcn, ushort* __restrict__ outb) {
  int node = blockIdx.x * 4 + (threadIdx.x >> 6);
  if (node >= N_NODES) return;
  int lane = threadIdx.x & 63;
  int half = lane >> 5;
  int c0 = (lane & 31) * 8;
  float di = dis[node];
  float acc[8];
#pragma unroll
  for (int j = 0; j < 8; j++) acc[j] = 0.f;
  int b = row_ptr[node], e = row_ptr[node + 1];
  int g0 = b;
  for (; g0 + 8 <= e; g0 += 8) {
    int i0 = g0 + half * 4;
    int s0 = col_src[i0], s1 = col_src[i0 + 1], s2 = col_src[i0 + 2], s3 = col_src[i0 + 3];
    float w0 = di * dis[s0], w1 = di * dis[s1], w2 = di * dis[s2], w3 = di * dis[s3];
    u16x8 u0 = *reinterpret_cast<const u16x8*>(xt + (size_t)s0 * HID + c0);
    u16x8 u1 = *reinterpret_cast<const u16x8*>(xt + (size_t)s1 * HID + c0);
    u16x8 u2 = *reinterpret_cast<const u16x8*>(xt + (size_t)s2 * HID + c0);
    u16x8 u3 = *reinterpret_cast<const u16x8*>(xt + (size_t)s3 * HID + c0);
#pragma unroll
    for (int j = 0; j < 8; j++) {
      acc[j] = fmaf(bfu(u0[j]), w0, acc[j]);
      acc[j] = fmaf(bfu(u1[j]), w1, acc[j]);
      acc[j] = fmaf(bfu(u2[j]), w2, acc[j]);
      acc[j] = fmaf(bfu(u3[j]), w3, acc[j]);
    }
  }
  for (; g0 + 4 <= e; g0 += 4) {
    int i0 = g0 + half * 2;
    int s0 = col_src[i0], s1 = col_src[i0 + 1];
    float w0 = di * dis[s0], w1 = di * dis[s1];
    u16x8 u0 = *reinterpret_cast<const u16x8*>(xt + (size_t)s0 * HID + c0);
    u16x8 u1 = *reinterpret_cast<const u16x8*>(xt + (size_t)s1 * HID + c0);
#pragma unroll
    for (int j = 0; j < 8; j++) {
      acc[j] = fmaf(bfu(u0[j]), w0, acc[j]);
      acc[j] = fmaf(bfu(u1[j]), w1, acc[j]);
    }
  }
  {  // tail (0..3 edges), guarded
    int i0 = g0 + half * 2;
    int s0 = 0, s1 = 0;
    float w0 = 0.f, w1 = 0.f;
    if (i0 < e) { s0 = col_src[i0]; w0 = di * dis[s0]; }
    if (i0 + 1 < e) { s1 = col_src[i0 + 1]; w1 = di * dis[s1]; }
    u16x8 u0 = *reinterpret_cast<const u16x8*>(xt + (size_t)s0 * HID + c0);
    u16x8 u1 = *reinterpret_cast<const u16x8*>(xt + (size_t)s1 * HID + c0);
#pragma unroll
    for (int j = 0; j < 8; j++) {
      acc[j] = fmaf(bfu(u0[j]), w0, acc[j]);
      acc[j] = fmaf(bfu(u1[j]), w1, acc[j]);
    }
  }
#pragma unroll
  for (int j = 0; j < 8; j++) acc[j] += __shfl_xor(acc[j], 32);
  if (!half) {
    u16x8 un = *reinterpret_cast<const u16x8*>(xt + (size_t)node * HID + c0);
    float w0 = di * di;
    u16x8 r;
#pragma unroll
    for (int j = 0; j < 8; j++) {
      float v = fmaf(bfu(un[j]), w0, acc[j]) + b_gcn[c0 + j];
      r[j] = f2bf(v);
    }
    *reinterpret_cast<u16x8*>(outb + (size_t)node * HID + c0) = r;
  }
}

__device__ __forceinline__ float leaky02(float x) { return x > 0.f ? x : 0.2f * x; }

// ---------------- Single-pass GAT agg, 32 lanes/row, 8-edge ILP; al in [node][head] ---------
__global__ void k_gat_agg(const ushort* __restrict__ xt, const float* __restrict__ alsrc,
                          const float* __restrict__ aldst, const int* __restrict__ row_ptr,
                          const int* __restrict__ col_src, const float* __restrict__ b_gat,
                          ushort* __restrict__ outb) {
  int node = blockIdx.x * 4 + (threadIdx.x >> 6);
  if (node >= N_NODES) return;
  int lane = threadIdx.x & 63;
  int half = lane >> 5;
  int l32 = lane & 31;
  int c0 = l32 * 8;
  int hh = l32 >> 2;
  float ad = aldst[node * 8 + hh];
  float acc[8];
#pragma unroll
  for (int j = 0; j < 8; j++) acc[j] = 0.f;
  float s = 0.f;
  int b = row_ptr[node], e = row_ptr[node + 1];
  int g0 = b;
  for (; g0 + 8 <= e; g0 += 8) {
    int i0 = g0 + half * 4;
    int s0 = col_src[i0], s1 = col_src[i0 + 1], s2 = col_src[i0 + 2], s3 = col_src[i0 + 3];
    float g0v = alsrc[s0 * 8 + hh], g1v = alsrc[s1 * 8 + hh];
    float g2v = alsrc[s2 * 8 + hh], g3v = alsrc[s3 * 8 + hh];
    u16x8 u0 = *reinterpret_cast<const u16x8*>(xt + (size_t)s0 * HID + c0);
    u16x8 u1 = *reinterpret_cast<const u16x8*>(xt + (size_t)s1 * HID + c0);
    u16x8 u2 = *reinterpret_cast<const u16x8*>(xt + (size_t)s2 * HID + c0);
    u16x8 u3 = *reinterpret_cast<const u16x8*>(xt + (size_t)s3 * HID + c0);
    float a0 = __expf(leaky02(g0v + ad));
    float a1 = __expf(leaky02(g1v + ad));
    float a2 = __expf(leaky02(g2v + ad));
    float a3 = __expf(leaky02(g3v + ad));
    s += a0 + a1 + a2 + a3;
#pragma unroll
    for (int j = 0; j < 8; j++) {
      acc[j] = fmaf(bfu(u0[j]), a0, acc[j]);
      acc[j] = fmaf(bfu(u1[j]), a1, acc[j]);
      acc[j] = fmaf(bfu(u2[j]), a2, acc[j]);
      acc[j] = fmaf(bfu(u3[j]), a3, acc[j]);
    }
  }
  for (; g0 + 4 <= e; g0 += 4) {
    int i0 = g0 + half * 2;
    int s0 = col_src[i0], s1 = col_src[i0 + 1];
    float a0 = __expf(leaky02(alsrc[s0 * 8 + hh] + ad));
    float a1 = __expf(leaky02(alsrc[s1 * 8 + hh] + ad));
    u16x8 u0 = *reinterpret_cast<const u16x8*>(xt + (size_t)s0 * HID + c0);
    u16x8 u1 = *reinterpret_cast<const u16x8*>(xt + (size_t)s1 * HID + c0);
    s += a0 + a1;
#pragma unroll
    for (int j = 0; j < 8; j++) {
      acc[j] = fmaf(bfu(u0[j]), a0, acc[j]);
      acc[j] = fmaf(bfu(u1[j]), a1, acc[j]);
    }
  }
  {  // tail, guarded
    int i0 = g0 + half * 2;
    int s0 = 0, s1 = 0;
    float a0 = 0.f, a1 = 0.f;
    if (i0 < e) { s0 = col_src[i0]; a0 = __expf(leaky02(alsrc[s0 * 8 + hh] + ad)); }
    if (i0 + 1 < e) { s1 = col_src[i0 + 1]; a1 = __expf(leaky02(alsrc[s1 * 8 + hh] + ad)); }
    u16x8 u0 = *reinterpret_cast<const u16x8*>(xt + (size_t)s0 * HID + c0);
    u16x8 u1 = *reinterpret_cast<const u16x8*>(xt + (size_t)s1 * HID + c0);
    s += a0 + a1;
#pragma unroll
    for (int j = 0; j < 8; j++) {
      acc[j] = fmaf(bfu(u0[j]), a0, acc[j]);
      acc[j] = fmaf(bfu(u1[j]), a1, acc[j]);
    }
  }
#pragma unroll
  for (int j = 0; j < 8; j++) acc[j] += __shfl_xor(acc[j], 32);
  s += __shfl_xor(s, 32);
  if (!half) {
    float e0 = __expf(leaky02(alsrc[node * 8 + hh] + ad));
    u16x8 un = *reinterpret_cast<const u16x8*>(xt + (size_t)node * HID + c0);
    float inv_s = 1.0f / (s + e0);
    u16x8 r;
#pragma unroll
    for (int j = 0; j < 8; j++) {
      float v = fmaf(bfu(un[j]), e0, acc[j]) * inv_s + b_gat[c0 + j];
      r[j] = f2bf(v);
    }
    *reinterpret_cast<u16x8*>(outb + (size_t)node * HID + c0) = r;
  }
}

// ---------------- SAGE mean aggregation: 32 lanes/row, 8-edge ILP, bf16 in/out --------------
__global__ void k_sage_agg(const ushort* __restrict__ h, const int* __restrict__ row_ptr,
                           const int* __restrict__ col_src, ushort* __restrict__ outb) {
  int node = blockIdx.x * 4 + (threadIdx.x >> 6);
  if (node >= N_NODES) return;
  int lane = threadIdx.x & 63;
  int half = lane >> 5;
  int c0 = (lane & 31) * 8;
  float acc[8];
#pragma unroll
  for (int j = 0; j < 8; j++) acc[j] = 0.f;
  int b = row_ptr[node], e = row_ptr[node + 1];
  int g0 = b;
  for (; g0 + 8 <= e; g0 += 8) {
    int i0 = g0 + half * 4;
    int s0 = col_src[i0], s1 = col_src[i0 + 1], s2 = col_src[i0 + 2], s3 = col_src[i0 + 3];
    u16x8 u0 = *reinterpret_cast<const u16x8*>(h + (size_t)s0 * HID + c0);
    u16x8 u1 = *reinterpret_cast<const u16x8*>(h + (size_t)s1 * HID + c0);
    u16x8 u2 = *reinterpret_cast<const u16x8*>(h + (size_t)s2 * HID + c0);
    u16x8 u3 = *reinterpret_cast<const u16x8*>(h + (size_t)s3 * HID + c0);
#pragma unroll
    for (int j = 0; j < 8; j++)
      acc[j] += (bfu(u0[j]) + bfu(u1[j])) + (bfu(u2[j]) + bfu(u3[j]));
  }
  for (; g0 + 4 <= e; g0 += 4) {
    int i0 = g0 + half * 2;
    int s0 = col_src[i0], s1 = col_src[i0 + 1];
    u16x8 u0 = *reinterpret_cast<const u16x8*>(h + (size_t)s0 * HID + c0);
    u16x8 u1 = *reinterpret_cast<const u16x8*>(h + (size_t)s1 * HID + c0);
#pragma unroll
    for (int j = 0; j < 8; j++) acc[j] += bfu(u0[j]) + bfu(u1[j]);
  }
  {
    int i0 = g0 + half * 2;
    int s0 = 0, s1 = 0;
    float w0 = 0.f, w1 = 0.f;
    if (i0 < e) { s0 = col_src[i0]; w0 = 1.f; }
    if (i0 + 1 < e) { s1 = col_src[i0 + 1]; w1 = 1.f; }
    u16x8 u0 = *reinterpret_cast<const u16x8*>(h + (size_t)s0 * HID + c0);
    u16x8 u1 = *reinterpret_cast<const u16x8*>(h + (size_t)s1 * HID + c0);
#pragma unroll
    for (int j = 0; j < 8; j++) {
      acc[j] = fmaf(bfu(u0[j]), w0, acc[j]);
      acc[j] = fmaf(bfu(u1[j]), w1, acc[j]);
    }
  }
#pragma unroll
  for (int j = 0; j < 8; j++) acc[j] += __shfl_xor(acc[j], 32);
  if (!half) {
    float inv = 1.0f / fmaxf((float)(e - b), 1.0f);
    u16x8 r;
#pragma unroll
    for (int j = 0; j < 8; j++) r[j] = f2bf(acc[j] * inv);
    *reinterpret_cast<u16x8*>(outb + (size_t)node * HID + c0) = r;
  }
}

// ---------------- BatchNorm stats: vectorized 16B loads, LDS reduce, 1024 blocks ------------
__global__ __launch_bounds__(256) void k_bn_stats(const ushort* __restrict__ x,
                                                  float* __restrict__ stats) {
  int tid = threadIdx.x;
  int cg = tid & 31;   // column group (8 cols)
  int rs = tid >> 5;   // row slot (8 rows per block-iteration)
  int c0 = cg * 8;
  float s[8], q[8];
#pragma unroll
  for (int j = 0; j < 8; j++) { s[j] = 0.f; q[j] = 0.f; }
  for (int r = blockIdx.x * 8 + rs; r < N_NODES; r += gridDim.x * 8) {
    u16x8 v = *reinterpret_cast<const u16x8*>(x + (size_t)r * HID + c0);
#pragma unroll
    for (int j = 0; j < 8; j++) {
      float f = bfu(v[j]);
      s[j] += f;
      q[j] = fmaf(f, f, q[j]);
    }
  }
  __shared__ float ls[512];
  ls[tid] = 0.f;
  ls[tid + 256] = 0.f;
  __syncthreads();
#pragma unroll
  for (int j = 0; j < 8; j++) {
    atomicAdd(&ls[c0 + j], s[j]);
    atomicAdd(&ls[256 + c0 + j], q[j]);
  }
  __syncthreads();
  atomicAdd(&stats[tid], ls[tid]);
  atomicAdd(&stats[tid + 256], ls[tid + 256]);
}

// stats -> per-column scale/shift:  bn(x) = x*sc + sh
__global__ void k_bn_coef(const float* __restrict__ stats, const float* __restrict__ gamma,
                          const float* __restrict__ beta, float* __restrict__ scsh) {
  int c = threadIdx.x;
  const float invN = 1.0f / (float)N_NODES;
  float mu = stats[c] * invN;
  float var = stats[256 + c] * invN - mu * mu;
  float sc = gamma[c] * rsqrtf(var + EPS);
  scsh[c] = sc;
  scsh[256 + c] = beta[c] - mu * sc;
}

// h_bf += relu(x*sc + sh)  (bf16 trunk, coefficient form)
__global__ void k_bn_apply(const ushort* __restrict__ x, const float* __restrict__ scsh,
                           ushort* __restrict__ h_bf) {
  int total = N_NODES * 64;
  for (int i = blockIdx.x * 256 + threadIdx.x; i < total; i += gridDim.x * 256) {
    int c4 = (i & 63) * 4;
    float4 xv = bf4(*reinterpret_cast<const ushort4*>(x + (size_t)i * 4));
    float4 sc = *reinterpret_cast<const float4*>(scsh + c4);
    float4 sh = *reinterpret_cast<const float4*>(scsh + 256 + c4);
    float4 hv = bf4(*reinterpret_cast<const ushort4*>(h_bf + (size_t)i * 4));
    hv.x += fmaxf(fmaf(xv.x, sc.x, sh.x), 0.f);
    hv.y += fmaxf(fmaf(xv.y, sc.y, sh.y), 0.f);
    hv.z += fmaxf(fmaf(xv.z, sc.z, sh.z), 0.f);
    hv.w += fmaxf(fmaf(xv.w, sc.w, sh.w), 0.f);
    *reinterpret_cast<ushort4*>(h_bf + (size_t)i * 4) =
        make_ushort4(f2bf(hv.x), f2bf(hv.y), f2bf(hv.z), f2bf(hv.w));
  }
}

// ---------------- graph segment starts ----------------
__global__ void k_gstart(const int* __restrict__ batch, int* __restrict__ gstart) {
  int g = blockIdx.x * 256 + threadIdx.x;
  if (g > NG) return;
  int lo = 0, hi = N_NODES;
  while (lo < hi) {
    int mid = (lo + hi) >> 1;
    if (batch[mid] < g) lo = mid + 1; else hi = mid;
  }
  gstart[g] = lo;
}

// ---------------- global attention pooling (bf16 h) ----------------
__global__ void k_pool(const ushort* __restrict__ hb, const float* __restrict__ gate,
                       const int* __restrict__ gstart, float* __restrict__ hg) {
  __shared__ float red[256];
  __shared__ float wbuf[256];
  int g = blockIdx.x, tid = threadIdx.x;
  int b = gstart[g], e = gstart[g + 1];
  float m = -1e30f;
  for (int r = b + tid; r < e; r += 256) m = fmaxf(m, gate[r]);
  red[tid] = m;
  __syncthreads();
  for (int o = 128; o > 0; o >>= 1) {
    if (tid < o) red[tid] = fmaxf(red[tid], red[tid + o]);
    __syncthreads();
  }
  m = red[0];
  __syncthreads();
  float s = 0.f;
  for (int r = b + tid; r < e; r += 256) s += __expf(gate[r] - m);
  red[tid] = s;
  __syncthreads();
  for (int o = 128; o > 0; o >>= 1) {
    if (tid < o) red[tid] += red[tid + o];
    __syncthreads();
  }
  float inv = 1.0f / fmaxf(red[0], 1e-16f);
  __syncthreads();
  float acc = 0.f;
  for (int cb = b; cb < e; cb += 256) {
    int r = cb + tid;
    wbuf[tid] = (r < e) ? __expf(gate[r] - m) : 0.f;
    __syncthreads();
    int n = min(256, e - cb);
    for (int j = 0; j < n; j++)
      acc = fmaf(bfu(hb[(size_t)(cb + j) * HID + tid]), wbuf[j], acc);
    __syncthreads();
  }
  hg[(size_t)g * HID + tid] = acc * inv;
}

// ---------------- MLP head ----------------
__global__ void k_mlp(const float* __restrict__ hg, const float* __restrict__ W1,
                      const float* __restrict__ b1, const float* __restrict__ lng,
                      const float* __restrict__ lnb, const float* __restrict__ W2,
                      const float* __restrict__ b2, float* __restrict__ out) {
  __shared__ float row[HID];
  __shared__ float z[HID];
  __shared__ float red[HID];
  int g = blockIdx.x, tid = threadIdx.x;
  row[tid] = hg[(size_t)g * HID + tid];
  __syncthreads();
  float acc = b1[tid];
  for (int k = 0; k < HID; k++) acc = fmaf(row[k], W1[(size_t)k * HID + tid], acc);
  red[tid] = acc;
  __syncthreads();
  for (int o = 128; o > 0; o >>= 1) {
    if (tid < o) red[tid] += red[tid + o];
    __syncthreads();
  }
  float mu = red[0] * (1.0f / HID);
  __syncthreads();
  red[tid] = acc * acc;
  __syncthreads();
  for (int o = 128; o > 0; o >>= 1) {
    if (tid < o) red[tid] += red[tid + o];
    __syncthreads();
  }
  float var = red[0] * (1.0f / HID) - mu * mu;
  float zz = (acc - mu) * rsqrtf(var + EPS) * lng[tid] + lnb[tid];
  z[tid] = fmaxf(zz, 0.f);
  __syncthreads();
  if (tid < 64) {
    float o = b2[tid];
    for (int k = 0; k < HID; k++) o = fmaf(z[k], W2[(size_t)k * 64 + tid], o);
    out[(size_t)g * 64 + tid] = o;
  }
}

// ---------------- launch ----------------
extern "C" void kernel_launch(void* const* d_in, const int* in_sizes, int n_in,
                              void* d_out, int out_size, void* d_ws, size_t ws_size,
                              hipStream_t stream) {
  const float* x     = (const float*)d_in[0];
  const float* W_emb = (const float*)d_in[1];
  const float* b_emb = (const float*)d_in[2];
  const float* W_gcn = (const float*)d_in[3];
  const float* b_gcn = (const float*)d_in[4];
  const float* W_gat = (const float*)d_in[5];
  const float* a_src = (const float*)d_in[6];
  const float* a_dst = (const float*)d_in[7];
  const float* b_gat = (const float*)d_in[8];
  const float* W_l   = (const float*)d_in[9];
  const float* b_l   = (const float*)d_in[10];
  const float* W_r   = (const float*)d_in[11];
  const float* bn_g  = (const float*)d_in[12];
  const float* bn_b  = (const float*)d_in[13];
  const float* Wg1   = (const float*)d_in[14];
  const float* bg1   = (const float*)d_in[15];
  const float* Wg2   = (const float*)d_in[16];
  const float* bg2   = (const float*)d_in[17];
  const float* Wm1   = (const float*)d_in[18];
  const float* bm1   = (const float*)d_in[19];
  const float* lnmg  = (const float*)d_in[20];
  const float* lnmb  = (const float*)d_in[21];
  const float* Wm2   = (const float*)d_in[22];
  const float* bm2   = (const float*)d_in[23];
  const float* Wv1   = (const float*)d_in[24];
  const float* bv1   = (const float*)d_in[25];
  const float* lnvg  = (const float*)d_in[26];
  const float* lnvb  = (const float*)d_in[27];
  const float* Wv2   = (const float*)d_in[28];
  const float* bv2   = (const float*)d_in[29];
  const int* ei      = (const int*)d_in[30];
  const int* batch   = (const int*)d_in[31];
  float* out = (float*)d_out;

  float* ws = (float*)d_ws;
  float* h     = ws;                          // spare region
  float* t1    = h + (size_t)N_NODES * HID;   // reused as bf16 t1b
  float* alsrc = t1 + (size_t)N_NODES * HID;  // [N][8]
  float* aldst = alsrc + N_NODES * 8;         // [N][8]
  float* dis   = aldst + N_NODES * 8;
  float* gate  = dis + N_NODES;
  float* hg    = gate + N_NODES;
  float* zbase = hg + NG * HID;
  float* bnst  = zbase;                // 3 * 512
  int* row_cnt = (int*)(zbase + 3 * 512);
  int* fill    = row_cnt + N_NODES;
  int* row_ptr = fill + N_NODES;
  int* col_src = row_ptr + N_NODES + 1;
  int* gstart  = col_src + N_EDGES;
  int* psum    = gstart + NG + 1;
  int* boff    = psum + 64;
  float* scsh  = (float*)(boff + 64);  // 3 * 512 coefficients
  float* bc    = scsh + 3 * 512;       // folded GCN bias (256)

  ushort* t1b = (ushort*)t1;

  size_t off = (size_t)((char*)(bc + 256) - (char*)d_ws);
  off = (off + 15) & ~(size_t)15;
  ushort* h_bf   = (ushort*)((char*)d_ws + off);
  ushort* t0_bf  = h_bf + (size_t)N_NODES * HID;
  ushort* wemb_t = t0_bf + (size_t)N_NODES * HID;
  ushort* wgcn_t = wemb_t + 128 * 256;
  ushort* wgat_t = wgcn_t + 256 * 256;
  ushort* wr_t   = wgat_t + 256 * 256;
  ushort* wl_t   = wr_t + 256 * 256;
  ushort* wg1_t  = wl_t + 256 * 256;   // 256*128
  ushort* wc_t   = wg1_t + 256 * 128;  // folded [256][128]

  size_t zbytes = (size_t)3 * 512 * 4 + 2 * (size_t)N_NODES * 4;
  hipMemsetAsync(zbase, 0, zbytes, stream);

  // CSR by dst (hierarchical scan + fused dis)
  k_csr_count<<<(N_EDGES + 255) / 256, 256, 0, stream>>>(ei, row_cnt);
  k_scan_part<<<SCB, 256, 0, stream>>>(row_cnt, psum);
  k_scan_top<<<1, 64, 0, stream>>>(psum, boff, row_ptr);
  k_scan_out<<<SCB, 256, 0, stream>>>(row_cnt, boff, row_ptr, dis);
  k_csr_fill<<<(N_EDGES + 255) / 256, 256, 0, stream>>>(ei, row_ptr, fill, col_src);

  // all weight transposes in one launch
  WtArgs wa;
  wa.src[0] = W_emb; wa.dst[0] = wemb_t; wa.K[0] = 128; wa.C[0] = 256; wa.off[0] = 0;
  wa.src[1] = W_gcn; wa.dst[1] = wgcn_t; wa.K[1] = 256; wa.C[1] = 256; wa.off[1] = 128;
  wa.src[2] = W_gat; wa.dst[2] = wgat_t; wa.K[2] = 256; wa.C[2] = 256; wa.off[2] = 384;
  wa.src[3] = W_r;   wa.dst[3] = wr_t;   wa.K[3] = 256; wa.C[3] = 256; wa.off[3] = 640;
  wa.src[4] = W_l;   wa.dst[4] = wl_t;   wa.K[4] = 256; wa.C[4] = 256; wa.off[4] = 896;
  wa.src[5] = Wg1;   wa.dst[5] = wg1_t;  wa.K[5] = 256; wa.C[5] = 128; wa.off[5] = 1152;
  k_wt_all<<<1280, 256, 0, stream>>>(wa);

  // folded GCN weight: wc_t = (W_emb @ W_gcn)^T bf16, bc = b_emb @ W_gcn
  k_wfold<<<256, 128, 0, stream>>>(W_emb, wgcn_t, wc_t, bc, b_emb, W_gcn);

  const int RB = (N_NODES + 63) / 64;   // 782 gemm blocks (256 thr)
  const int AB = (N_NODES + 3) / 4;     // 12500 agg blocks

  // embedding: h_bf = x @ W_emb + b_emb  (fp32 A converted on load)
  k_mgemm<128, 256, false, true, false, false, false><<<RB, 256, 0, stream>>>(
      x, wemb_t, nullptr, nullptr, b_emb, h_bf, nullptr, nullptr, nullptr,
      nullptr, nullptr, nullptr, nullptr, nullptr, nullptr, N_NODES, 0);

  // --- GCN: xt = x @ (W_emb@W_gcn) + b_emb@W_gcn  (K=128, folded weight) ---
  k_mgemm<128, 256, false, true, false, false, false><<<RB, 256, 0, stream>>>(
      x, wc_t, nullptr, nullptr, bc, t0_bf, nullptr, nullptr, nullptr,
      nullptr, nullptr, nullptr, nullptr, nullptr, nullptr, N_NODES, 0);
  k_gcn_agg<<<AB, 256, 0, stream>>>(t0_bf, dis, row_ptr, col_src, b_gcn, t1b);
  k_bn_stats<<<1024, 256, 0, stream>>>(t1b, bnst);
  k_bn_coef<<<1, 256, 0, stream>>>(bnst, bn_g, bn_b, scsh);

  // --- GAT: BN(gcn) folded into A-load; al fused into epilogue ---
  k_mgemm<256, 256, false, false, false, true, true><<<RB, 256, 0, stream>>>(
      t1b, wgat_t, nullptr, nullptr, nullptr, t0_bf, nullptr, nullptr, nullptr,
      a_src, a_dst, alsrc, aldst, scsh, h_bf, N_NODES, 0);
  k_gat_agg<<<AB, 256, 0, stream>>>(t0_bf, alsrc, aldst, row_ptr, col_src, b_gat, t1b);
  k_bn_stats<<<1024, 256, 0, stream>>>(t1b, bnst + 512);
  k_bn_coef<<<1, 256, 0, stream>>>(bnst + 512, bn_g + HID, bn_b + HID, scsh + 512);
  k_bn_apply<<<1024, 256, 0, stream>>>(t1b, scsh + 512, h_bf);

  // --- SAGE: t1b = h@W_r + b_l + mean@W_l (dual, double-buffered) ---
  k_sage_agg<<<AB, 256, 0, stream>>>(h_bf, row_ptr, col_src, t0_bf);
  k_mgemm<256, 256, true, false, false, false, false><<<RB, 256, 0, stream>>>(
      h_bf, wr_t, t0_bf, wl_t, b_l, t1b, nullptr, nullptr, nullptr,
      nullptr, nullptr, nullptr, nullptr, nullptr, nullptr, N_NODES, 0);
  k_bn_stats<<<1024, 256, 0, stream>>>(t1b, bnst + 1024);
  k_bn_coef<<<1, 256, 0, stream>>>(bnst + 1024, bn_g + 2 * HID, bn_b + 2 * HID, scsh + 1024);

  // --- gate: BN(sage) folded into A-load; gate head fused ---
  k_mgemm<256, 128, false, false, true, false, true><<<RB, 256, 0, stream>>>(
      t1b, wg1_t, nullptr, nullptr, bg1, nullptr, Wg2, bg2, gate,
      nullptr, nullptr, nullptr, nullptr, scsh + 1024, h_bf, N_NODES, 1);
  k_gstart<<<3, 256, 0, stream>>>(batch, gstart);
  k_pool<<<NG, 256, 0, stream>>>(h_bf, gate, gstart, hg);

  // --- heads ---
  k_mlp<<<NG, 256, 0, stream>>>(hg, Wm1, bm1, lnmg, lnmb, Wm2, bm2, out);
  k_mlp<<<NG, 256, 0, stream>>>(hg, Wv1, bv1, lnvg, lnvb, Wv2, bv2, out + (size_t)NG * 64);
}

// Round 14
// 556.425 us; speedup vs baseline: 1.0141x; 1.0141x over previous
//
#include <hip/hip_runtime.h>
#include <cstdint>
#include <cstddef>

#define N_NODES 50000
#define N_EDGES 500000
#define NG 512
#define HID 256
#define EPS 1e-5f
#define SCB 49  // scan blocks: ceil(50000/1024)

typedef __attribute__((ext_vector_type(8))) __bf16 bf16x8;
typedef __attribute__((ext_vector_type(8))) ushort u16x8;
typedef __attribute__((ext_vector_type(4))) float f32x4;

__device__ __forceinline__ ushort f2bf(float f) {
  uint32_t u = __float_as_uint(f);
  uint32_t r = (u + 0x7fffu + ((u >> 16) & 1u)) >> 16;
  return (ushort)r;
}
__device__ __forceinline__ float bfu(ushort u) { return __uint_as_float(((uint32_t)u) << 16); }
__device__ __forceinline__ float4 bf4(ushort4 u) {
  return make_float4(bfu(u.x), bfu(u.y), bfu(u.z), bfu(u.w));
}

// ---------------- CSR build ----------------
__global__ void k_csr_count(const int* __restrict__ ei, int* __restrict__ cnt) {
  int e = blockIdx.x * 256 + threadIdx.x;
  if (e < N_EDGES) atomicAdd(&cnt[ei[N_EDGES + e]], 1);
}

__global__ void k_scan_part(const int* __restrict__ cnt, int* __restrict__ psum) {
  __shared__ int red[256];
  int tid = threadIdx.x;
  int i0 = blockIdx.x * 1024 + tid * 4;
  int s = 0;
  if (i0 + 4 <= N_NODES) {
    int4 v = *reinterpret_cast<const int4*>(cnt + i0);
    s = v.x + v.y + v.z + v.w;
  } else {
    for (int k = 0; k < 4; k++)
      if (i0 + k < N_NODES) s += cnt[i0 + k];
  }
  red[tid] = s;
  __syncthreads();
  for (int o = 128; o > 0; o >>= 1) {
    if (tid < o) red[tid] += red[tid + o];
    __syncthreads();
  }
  if (tid == 0) psum[blockIdx.x] = red[0];
}

__global__ void k_scan_top(const int* __restrict__ psum, int* __restrict__ boff,
                           int* __restrict__ row_ptr) {
  int t = threadIdx.x;  // 64
  int v = (t < SCB) ? psum[t] : 0;
  int own = v;
  for (int o = 1; o < 64; o <<= 1) {
    int u = __shfl_up(v, o);
    if (t >= o) v += u;
  }
  if (t < SCB) boff[t] = v - own;
  if (t == 63) row_ptr[N_NODES] = v;
}

__global__ void k_scan_out(const int* __restrict__ cnt, const int* __restrict__ boff,
                           int* __restrict__ row_ptr, float* __restrict__ dis) {
  __shared__ int ps[256];
  int tid = threadIdx.x;
  int i0 = blockIdx.x * 1024 + tid * 4;
  int v[4];
#pragma unroll
  for (int k = 0; k < 4; k++) v[k] = (i0 + k < N_NODES) ? cnt[i0 + k] : 0;
  int s = v[0] + v[1] + v[2] + v[3];
  ps[tid] = s;
  __syncthreads();
  for (int o = 1; o < 256; o <<= 1) {
    int add = (tid >= o) ? ps[tid - o] : 0;
    __syncthreads();
    ps[tid] += add;
    __syncthreads();
  }
  int run = boff[blockIdx.x] + ((tid > 0) ? ps[tid - 1] : 0);
#pragma unroll
  for (int k = 0; k < 4; k++) {
    if (i0 + k < N_NODES) {
      row_ptr[i0 + k] = run;
      dis[i0 + k] = rsqrtf((float)v[k] + 1.0f);
      run += v[k];
    }
  }
}

__global__ void k_csr_fill(const int* __restrict__ ei, const int* __restrict__ row_ptr,
                           int* __restrict__ fill, int* __restrict__ col_src) {
  int e = blockIdx.x * 256 + threadIdx.x;
  if (e >= N_EDGES) return;
  int s = ei[e], d = ei[N_EDGES + e];
  int pos = row_ptr[d] + atomicAdd(&fill[d], 1);
  col_src[pos] = s;
}

// ---------------- batched weight transpose: W[K,C] fp32 -> Wt[C,K] bf16 ----------------
struct WtArgs {
  const float* src[6];
  ushort* dst[6];
  int K[6];
  int C[6];
  int off[6];
};

__global__ void k_wt_all(WtArgs a) {
  int b = blockIdx.x;
  int ji = 0;
#pragma unroll
  for (int t = 1; t < 6; t++)
    if (b >= a.off[t]) ji = t;
  int K = a.K[ji], C = a.C[ji];
  int i = (b - a.off[ji]) * 256 + threadIdx.x;
  int c = i / K, k = i - c * K;
  a.dst[ji][i] = f2bf(a.src[ji][k * C + c]);
}

// ---------------- MFMA GEMM: 64-row blocks, K-split dbuf panels, column-split grid ----------
// out_bf[M,C] = A1@W1t^T (+A2@W2t^T) + bias. Wt [C,K] bf16. Grid: (ceil(M/64), CSPLIT).
// Each y-block handles NPAN/CSPLIT column panels (A re-read per split; better CU overlap).
// BNF: A = hbin + relu(A1v*sc+sh) inline; y==0 writes new trunk to hbout (no in-place race).
// GATE: fused gate head via atomicAdd (gate must be zeroed). GATAL: fused attention logits.
template <int K, int C, int CSPLIT, bool DUAL, bool AFP32, bool GATE, bool GATAL, bool BNF>
__global__ __launch_bounds__(256) void k_mgemm(
    const void* __restrict__ A1v, const ushort* __restrict__ W1t,
    const ushort* __restrict__ A2, const ushort* __restrict__ W2t,
    const float* __restrict__ bias, ushort* __restrict__ out_bf,
    const float* __restrict__ gw, const float* __restrict__ gb,
    float* __restrict__ gate, const float* __restrict__ asv,
    const float* __restrict__ adv, float* __restrict__ als,
    float* __restrict__ ald, const float* __restrict__ scsh,
    const ushort* __restrict__ hbin, ushort* __restrict__ hbout, int M, int relu) {
  constexpr int KS = K / 32;             // MFMA k-steps total
  constexpr int KSH = KS / 2;            // k-steps per half
  constexpr int KHALF = K / 2;
  constexpr int CHKH = KHALF / 8;        // 16B chunks per col per half
  constexpr int NPAN = C / 64;
  constexpr int NPANL = NPAN / CSPLIT;   // panels per y-block
  constexpr int LOWB = DUAL ? 4 : 2;     // sub-steps per panel
  constexpr int NTOT = NPANL * LOWB;
  constexpr int NISS = (64 * CHKH) / 256;
  constexpr int PELEM = 64 * KHALF;      // ushorts per half-panel buffer
  __shared__ ushort wlds[2 * PELEM];
  const int tid = threadIdx.x;
  const int lane = tid & 63;
  const int wid = tid >> 6;
  const int r16 = lane & 15;
  const int kg = lane >> 4;
  const int rbase = blockIdx.x * 64 + wid * 16;
  const int pbase = blockIdx.y * NPANL;

  const bool avalid = (rbase + r16) < M;
  int arow = rbase + r16;
  if (arow >= M) arow = M - 1;

  // A fragments, loaded once
  bf16x8 af[KS], af2[KS];
  if constexpr (BNF) {
    const ushort* xp = (const ushort*)A1v + (size_t)arow * K + kg * 8;
    const ushort* hp = hbin + (size_t)arow * K + kg * 8;
    ushort* hq = hbout + (size_t)arow * K + kg * 8;
#pragma unroll
    for (int ks = 0; ks < KS; ks++) {
      int col = kg * 8 + ks * 32;
      u16x8 xv = *reinterpret_cast<const u16x8*>(xp + ks * 32);
      u16x8 hv = *reinterpret_cast<const u16x8*>(hp + ks * 32);
      float4 sc0 = *reinterpret_cast<const float4*>(scsh + col);
      float4 sc1 = *reinterpret_cast<const float4*>(scsh + col + 4);
      float4 sh0 = *reinterpret_cast<const float4*>(scsh + 256 + col);
      float4 sh1 = *reinterpret_cast<const float4*>(scsh + 256 + col + 4);
      float scv[8] = {sc0.x, sc0.y, sc0.z, sc0.w, sc1.x, sc1.y, sc1.z, sc1.w};
      float shv[8] = {sh0.x, sh0.y, sh0.z, sh0.w, sh1.x, sh1.y, sh1.z, sh1.w};
      union { u16x8 u; bf16x8 b; } cv;
#pragma unroll
      for (int j = 0; j < 8; j++) {
        float v = fmaf(bfu(xv[j]), scv[j], shv[j]);
        float hn = bfu(hv[j]) + fmaxf(v, 0.f);
        cv.u[j] = f2bf(hn);
      }
      af[ks] = cv.b;
      if (avalid && blockIdx.y == 0) *reinterpret_cast<u16x8*>(hq + ks * 32) = cv.u;
    }
  } else if constexpr (AFP32) {
    const float* ap = (const float*)A1v + (size_t)arow * K + kg * 8;
#pragma unroll
    for (int ks = 0; ks < KS; ks++) {
      float4 lo = *reinterpret_cast<const float4*>(ap + ks * 32);
      float4 hi = *reinterpret_cast<const float4*>(ap + ks * 32 + 4);
      union { u16x8 u; bf16x8 b; } cv;
      cv.u = (u16x8){f2bf(lo.x), f2bf(lo.y), f2bf(lo.z), f2bf(lo.w),
                     f2bf(hi.x), f2bf(hi.y), f2bf(hi.z), f2bf(hi.w)};
      af[ks] = cv.b;
    }
  } else {
    const ushort* ap = (const ushort*)A1v + (size_t)arow * K + kg * 8;
#pragma unroll
    for (int ks = 0; ks < KS; ks++)
      af[ks] = *reinterpret_cast<const bf16x8*>(ap + ks * 32);
  }
  if constexpr (DUAL) {
    const ushort* ap = A2 + (size_t)arow * K + kg * 8;
#pragma unroll
    for (int ks = 0; ks < KS; ks++)
      af2[ks] = *reinterpret_cast<const bf16x8*>(ap + ks * 32);
  }

  float greg[4] = {0.f, 0.f, 0.f, 0.f};
  f32x4 acc[4];

#define STAGE_ASYNC(WSRC, PAN, KH, BUF)                                        \
  {                                                                            \
    const ushort* base_ = (WSRC) + (size_t)((PAN) * 64) * K + (KH) * KHALF;    \
    _Pragma("unroll") for (int j = 0; j < NISS; j++) {                         \
      int p_ = j * 256 + tid;                                                  \
      int c_ = p_ / CHKH, jj_ = p_ % CHKH;                                     \
      const ushort* g_ = base_ + c_ * K + (jj_ ^ (c_ & 7)) * 8;                \
      ushort* l_ = &wlds[(BUF) * PELEM + (j * 256 + wid * 64) * 8];            \
      __builtin_amdgcn_global_load_lds(                                        \
          (const __attribute__((address_space(1))) void*)(g_),                 \
          (__attribute__((address_space(3))) void*)(l_), 16, 0, 0);            \
    }                                                                          \
  }

#define COMPUTE(AF, KH, BUF)                                                   \
  {                                                                            \
    const ushort* wb_ = &wlds[(BUF) * PELEM];                                  \
    _Pragma("unroll") for (int ct = 0; ct < 4; ct++) {                         \
      bf16x8 wf[KSH];                                                          \
      int colr = ct * 16 + r16;                                                \
      _Pragma("unroll") for (int ksl = 0; ksl < KSH; ksl++) {                  \
        int slot = colr * CHKH + ((ksl * 4 + kg) ^ (r16 & 7));                 \
        wf[ksl] = *reinterpret_cast<const bf16x8*>(&wb_[slot * 8]);            \
      }                                                                        \
      _Pragma("unroll") for (int ksl = 0; ksl < KSH; ksl++)                    \
        acc[ct] = __builtin_amdgcn_mfma_f32_16x16x32_bf16(                     \
            (AF)[(KH) * KSH + ksl], wf[ksl], acc[ct], 0, 0, 0);                \
    }                                                                          \
  }

  // prologue: stage sub-step 0 into buffer 0
  STAGE_ASYNC(W1t, pbase, 0, 0);
  __syncthreads();

#pragma unroll
  for (int q = 0; q < NTOT; q++) {
    const int kh = q & 1;
    const int pass = DUAL ? ((q >> 1) & 1) : 0;
    const int pan = pbase + (DUAL ? (q >> 2) : (q >> 1));
    const int bufq = q & 1;
    const int c0 = pan * 64;
    if ((q & (LOWB - 1)) == 0) {
#pragma unroll
      for (int ct = 0; ct < 4; ct++) acc[ct] = (f32x4){0.f, 0.f, 0.f, 0.f};
    }
    if (q + 1 < NTOT) {
      const int nkh = (q + 1) & 1;
      const int npass = DUAL ? (((q + 1) >> 1) & 1) : 0;
      const int npan = pbase + (DUAL ? ((q + 1) >> 2) : ((q + 1) >> 1));
      const ushort* Wq = (DUAL && npass) ? W2t : W1t;
      STAGE_ASYNC(Wq, npan, nkh, bufq ^ 1);
    }
    if (DUAL && pass) {
      COMPUTE(af2, kh, bufq);
    } else {
      COMPUTE(af, kh, bufq);
    }
    if ((q & (LOWB - 1)) == (LOWB - 1)) {
      if constexpr (GATE) {
#pragma unroll
        for (int ct = 0; ct < 4; ct++) {
          int col = c0 + ct * 16 + r16;
          float bv = bias[col];
          float wv = gw[col];
#pragma unroll
          for (int i = 0; i < 4; i++) {
            float v = fmaxf(acc[ct][i] + bv, 0.f);
            greg[i] = fmaf(v, wv, greg[i]);
          }
        }
      } else {
#pragma unroll
        for (int ct = 0; ct < 4; ct++) {
          int col = c0 + ct * 16 + r16;
          float bv = bias ? bias[col] : 0.f;
#pragma unroll
          for (int i = 0; i < 4; i++) {
            int row = rbase + kg * 4 + i;
            if (row < M) {
              float v = acc[ct][i] + bv;
              if (relu) v = fmaxf(v, 0.f);
              out_bf[(size_t)row * C + col] = f2bf(v);
            }
          }
        }
      }
      if constexpr (GATAL) {
        float ps_[2][4], pd_[2][4];
#pragma unroll
        for (int h2 = 0; h2 < 2; h2++)
#pragma unroll
          for (int i = 0; i < 4; i++) { ps_[h2][i] = 0.f; pd_[h2][i] = 0.f; }
#pragma unroll
        for (int ct = 0; ct < 4; ct++) {
          int col = c0 + ct * 16 + r16;
          float as_ = asv[col], ad_ = adv[col];
          int h2 = ct >> 1;
#pragma unroll
          for (int i = 0; i < 4; i++) {
            ps_[h2][i] = fmaf(acc[ct][i], as_, ps_[h2][i]);
            pd_[h2][i] = fmaf(acc[ct][i], ad_, pd_[h2][i]);
          }
        }
#pragma unroll
        for (int h2 = 0; h2 < 2; h2++)
#pragma unroll
          for (int i = 0; i < 4; i++) {
#pragma unroll
            for (int o = 1; o < 16; o <<= 1) {
              ps_[h2][i] += __shfl_xor(ps_[h2][i], o);
              pd_[h2][i] += __shfl_xor(pd_[h2][i], o);
            }
          }
        if (r16 == 0) {
#pragma unroll
          for (int i = 0; i < 4; i++) {
            int row = rbase + kg * 4 + i;
            if (row < M) {
              als[row * 8 + pan * 2 + 0] = ps_[0][i];
              ald[row * 8 + pan * 2 + 0] = pd_[0][i];
              als[row * 8 + pan * 2 + 1] = ps_[1][i];
              ald[row * 8 + pan * 2 + 1] = pd_[1][i];
            }
          }
        }
      }
    }
    __syncthreads();
  }

  if constexpr (GATE) {
#pragma unroll
    for (int i = 0; i < 4; i++) {
#pragma unroll
      for (int o = 1; o < 16; o <<= 1) greg[i] += __shfl_xor(greg[i], o);
    }
    if (r16 == 0) {
      float b0 = (blockIdx.y == 0) ? gb[0] : 0.f;
#pragma unroll
      for (int i = 0; i < 4; i++) {
        int row = rbase + kg * 4 + i;
        if (row < M) atomicAdd(&gate[row], greg[i] + b0);
      }
    }
  }
#undef STAGE_ASYNC
#undef COMPUTE
}

// ---------------- GCN aggregation: wave/node, 32 lanes/row, 8-edge ILP, bf16 out ------------
__global__ void k_gcn_agg(const ushort* __restrict__ xt, const float* __restrict__ dis,
                          const int* __restrict__ row_ptr, const int* __restrict__ col_src,
                          const float* __restrict__ b_gcn, ushort* __restrict__ outb) {
  int node = blockIdx.x * 4 + (threadIdx.x >> 6);
  if (node >= N_NODES) return;
  int lane = threadIdx.x & 63;
  int half = lane >> 5;
  int c0 = (lane & 31) * 8;
  float di = dis[node];
  float acc[8];
#pragma unroll
  for (int j = 0; j < 8; j++) acc[j] = 0.f;
  int b = row_ptr[node], e = row_ptr[node + 1];
  int g0 = b;
  for (; g0 + 8 <= e; g0 += 8) {
    int i0 = g0 + half * 4;
    int s0 = col_src[i0], s1 = col_src[i0 + 1], s2 = col_src[i0 + 2], s3 = col_src[i0 + 3];
    float w0 = di * dis[s0], w1 = di * dis[s1], w2 = di * dis[s2], w3 = di * dis[s3];
    u16x8 u0 = *reinterpret_cast<const u16x8*>(xt + (size_t)s0 * HID + c0);
    u16x8 u1 = *reinterpret_cast<const u16x8*>(xt + (size_t)s1 * HID + c0);
    u16x8 u2 = *reinterpret_cast<const u16x8*>(xt + (size_t)s2 * HID + c0);
    u16x8 u3 = *reinterpret_cast<const u16x8*>(xt + (size_t)s3 * HID + c0);
#pragma unroll
    for (int j = 0; j < 8; j++) {
      acc[j] = fmaf(bfu(u0[j]), w0, acc[j]);
      acc[j] = fmaf(bfu(u1[j]), w1, acc[j]);
      acc[j] = fmaf(bfu(u2[j]), w2, acc[j]);
      acc[j] = fmaf(bfu(u3[j]), w3, acc[j]);
    }
  }
  for (; g0 + 4 <= e; g0 += 4) {
    int i0 = g0 + half * 2;
    int s0 = col_src[i0], s1 = col_src[i0 + 1];
    float w0 = di * dis[s0], w1 = di * dis[s1];
    u16x8 u0 = *reinterpret_cast<const u16x8*>(xt + (size_t)s0 * HID + c0);
    u16x8 u1 = *reinterpret_cast<const u16x8*>(xt + (size_t)s1 * HID + c0);
#pragma unroll
    for (int j = 0; j < 8; j++) {
      acc[j] = fmaf(bfu(u0[j]), w0, acc[j]);
      acc[j] = fmaf(bfu(u1[j]), w1, acc[j]);
    }
  }
  {  // tail (0..3 edges), guarded
    int i0 = g0 + half * 2;
    int s0 = 0, s1 = 0;
    float w0 = 0.f, w1 = 0.f;
    if (i0 < e) { s0 = col_src[i0]; w0 = di * dis[s0]; }
    if (i0 + 1 < e) { s1 = col_src[i0 + 1]; w1 = di * dis[s1]; }
    u16x8 u0 = *reinterpret_cast<const u16x8*>(xt + (size_t)s0 * HID + c0);
    u16x8 u1 = *reinterpret_cast<const u16x8*>(xt + (size_t)s1 * HID + c0);
#pragma unroll
    for (int j = 0; j < 8; j++) {
      acc[j] = fmaf(bfu(u0[j]), w0, acc[j]);
      acc[j] = fmaf(bfu(u1[j]), w1, acc[j]);
    }
  }
#pragma unroll
  for (int j = 0; j < 8; j++) acc[j] += __shfl_xor(acc[j], 32);
  if (!half) {
    u16x8 un = *reinterpret_cast<const u16x8*>(xt + (size_t)node * HID + c0);
    float w0 = di * di;
    u16x8 r;
#pragma unroll
    for (int j = 0; j < 8; j++) {
      float v = fmaf(bfu(un[j]), w0, acc[j]) + b_gcn[c0 + j];
      r[j] = f2bf(v);
    }
    *reinterpret_cast<u16x8*>(outb + (size_t)node * HID + c0) = r;
  }
}

__device__ __forceinline__ float leaky02(float x) { return x > 0.f ? x : 0.2f * x; }

// ---------------- Single-pass GAT agg, 32 lanes/row, 8-edge ILP; al in [node][head] ---------
__global__ void k_gat_agg(const ushort* __restrict__ xt, const float* __restrict__ alsrc,
                          const float* __restrict__ aldst, const int* __restrict__ row_ptr,
                          const int* __restrict__ col_src, const float* __restrict__ b_gat,
                          ushort* __restrict__ outb) {
  int node = blockIdx.x * 4 + (threadIdx.x >> 6);
  if (node >= N_NODES) return;
  int lane = threadIdx.x & 63;
  int half = lane >> 5;
  int l32 = lane & 31;
  int c0 = l32 * 8;
  int hh = l32 >> 2;
  float ad = aldst[node * 8 + hh];
  float acc[8];
#pragma unroll
  for (int j = 0; j < 8; j++) acc[j] = 0.f;
  float s = 0.f;
  int b = row_ptr[node], e = row_ptr[node + 1];
  int g0 = b;
  for (; g0 + 8 <= e; g0 += 8) {
    int i0 = g0 + half * 4;
    int s0 = col_src[i0], s1 = col_src[i0 + 1], s2 = col_src[i0 + 2], s3 = col_src[i0 + 3];
    float g0v = alsrc[s0 * 8 + hh], g1v = alsrc[s1 * 8 + hh];
    float g2v = alsrc[s2 * 8 + hh], g3v = alsrc[s3 * 8 + hh];
    u16x8 u0 = *reinterpret_cast<const u16x8*>(xt + (size_t)s0 * HID + c0);
    u16x8 u1 = *reinterpret_cast<const u16x8*>(xt + (size_t)s1 * HID + c0);
    u16x8 u2 = *reinterpret_cast<const u16x8*>(xt + (size_t)s2 * HID + c0);
    u16x8 u3 = *reinterpret_cast<const u16x8*>(xt + (size_t)s3 * HID + c0);
    float a0 = __expf(leaky02(g0v + ad));
    float a1 = __expf(leaky02(g1v + ad));
    float a2 = __expf(leaky02(g2v + ad));
    float a3 = __expf(leaky02(g3v + ad));
    s += a0 + a1 + a2 + a3;
#pragma unroll
    for (int j = 0; j < 8; j++) {
      acc[j] = fmaf(bfu(u0[j]), a0, acc[j]);
      acc[j] = fmaf(bfu(u1[j]), a1, acc[j]);
      acc[j] = fmaf(bfu(u2[j]), a2, acc[j]);
      acc[j] = fmaf(bfu(u3[j]), a3, acc[j]);
    }
  }
  for (; g0 + 4 <= e; g0 += 4) {
    int i0 = g0 + half * 2;
    int s0 = col_src[i0], s1 = col_src[i0 + 1];
    float a0 = __expf(leaky02(alsrc[s0 * 8 + hh] + ad));
    float a1 = __expf(leaky02(alsrc[s1 * 8 + hh] + ad));
    u16x8 u0 = *reinterpret_cast<const u16x8*>(xt + (size_t)s0 * HID + c0);
    u16x8 u1 = *reinterpret_cast<const u16x8*>(xt + (size_t)s1 * HID + c0);
    s += a0 + a1;
#pragma unroll
    for (int j = 0; j < 8; j++) {
      acc[j] = fmaf(bfu(u0[j]), a0, acc[j]);
      acc[j] = fmaf(bfu(u1[j]), a1, acc[j]);
    }
  }
  {  // tail, guarded
    int i0 = g0 + half * 2;
    int s0 = 0, s1 = 0;
    float a0 = 0.f, a1 = 0.f;
    if (i0 < e) { s0 = col_src[i0]; a0 = __expf(leaky02(alsrc[s0 * 8 + hh] + ad)); }
    if (i0 + 1 < e) { s1 = col_src[i0 + 1]; a1 = __expf(leaky02(alsrc[s1 * 8 + hh] + ad)); }
    u16x8 u0 = *reinterpret_cast<const u16x8*>(xt + (size_t)s0 * HID + c0);
    u16x8 u1 = *reinterpret_cast<const u16x8*>(xt + (size_t)s1 * HID + c0);
    s += a0 + a1;
#pragma unroll
    for (int j = 0; j < 8; j++) {
      acc[j] = fmaf(bfu(u0[j]), a0, acc[j]);
      acc[j] = fmaf(bfu(u1[j]), a1, acc[j]);
    }
  }
#pragma unroll
  for (int j = 0; j < 8; j++) acc[j] += __shfl_xor(acc[j], 32);
  s += __shfl_xor(s, 32);
  if (!half) {
    float e0 = __expf(leaky02(alsrc[node * 8 + hh] + ad));
    u16x8 un = *reinterpret_cast<const u16x8*>(xt + (size_t)node * HID + c0);
    float inv_s = 1.0f / (s + e0);
    u16x8 r;
#pragma unroll
    for (int j = 0; j < 8; j++) {
      float v = fmaf(bfu(un[j]), e0, acc[j]) * inv_s + b_gat[c0 + j];
      r[j] = f2bf(v);
    }
    *reinterpret_cast<u16x8*>(outb + (size_t)node * HID + c0) = r;
  }
}

// ---------------- SAGE mean aggregation: 32 lanes/row, 8-edge ILP, bf16 in/out --------------
__global__ void k_sage_agg(const ushort* __restrict__ h, const int* __restrict__ row_ptr,
                           const int* __restrict__ col_src, ushort* __restrict__ outb) {
  int node = blockIdx.x * 4 + (threadIdx.x >> 6);
  if (node >= N_NODES) return;
  int lane = threadIdx.x & 63;
  int half = lane >> 5;
  int c0 = (lane & 31) * 8;
  float acc[8];
#pragma unroll
  for (int j = 0; j < 8; j++) acc[j] = 0.f;
  int b = row_ptr[node], e = row_ptr[node + 1];
  int g0 = b;
  for (; g0 + 8 <= e; g0 += 8) {
    int i0 = g0 + half * 4;
    int s0 = col_src[i0], s1 = col_src[i0 + 1], s2 = col_src[i0 + 2], s3 = col_src[i0 + 3];
    u16x8 u0 = *reinterpret_cast<const u16x8*>(h + (size_t)s0 * HID + c0);
    u16x8 u1 = *reinterpret_cast<const u16x8*>(h + (size_t)s1 * HID + c0);
    u16x8 u2 = *reinterpret_cast<const u16x8*>(h + (size_t)s2 * HID + c0);
    u16x8 u3 = *reinterpret_cast<const u16x8*>(h + (size_t)s3 * HID + c0);
#pragma unroll
    for (int j = 0; j < 8; j++)
      acc[j] += (bfu(u0[j]) + bfu(u1[j])) + (bfu(u2[j]) + bfu(u3[j]));
  }
  for (; g0 + 4 <= e; g0 += 4) {
    int i0 = g0 + half * 2;
    int s0 = col_src[i0], s1 = col_src[i0 + 1];
    u16x8 u0 = *reinterpret_cast<const u16x8*>(h + (size_t)s0 * HID + c0);
    u16x8 u1 = *reinterpret_cast<const u16x8*>(h + (size_t)s1 * HID + c0);
#pragma unroll
    for (int j = 0; j < 8; j++) acc[j] += bfu(u0[j]) + bfu(u1[j]);
  }
  {
    int i0 = g0 + half * 2;
    int s0 = 0, s1 = 0;
    float w0 = 0.f, w1 = 0.f;
    if (i0 < e) { s0 = col_src[i0]; w0 = 1.f; }
    if (i0 + 1 < e) { s1 = col_src[i0 + 1]; w1 = 1.f; }
    u16x8 u0 = *reinterpret_cast<const u16x8*>(h + (size_t)s0 * HID + c0);
    u16x8 u1 = *reinterpret_cast<const u16x8*>(h + (size_t)s1 * HID + c0);
#pragma unroll
    for (int j = 0; j < 8; j++) {
      acc[j] = fmaf(bfu(u0[j]), w0, acc[j]);
      acc[j] = fmaf(bfu(u1[j]), w1, acc[j]);
    }
  }
#pragma unroll
  for (int j = 0; j < 8; j++) acc[j] += __shfl_xor(acc[j], 32);
  if (!half) {
    float inv = 1.0f / fmaxf((float)(e - b), 1.0f);
    u16x8 r;
#pragma unroll
    for (int j = 0; j < 8; j++) r[j] = f2bf(acc[j] * inv);
    *reinterpret_cast<u16x8*>(outb + (size_t)node * HID + c0) = r;
  }
}

// ---------------- BatchNorm stats: vectorized 16B loads, LDS reduce, 1024 blocks ------------
__global__ __launch_bounds__(256) void k_bn_stats(const ushort* __restrict__ x,
                                                  float* __restrict__ stats) {
  int tid = threadIdx.x;
  int cg = tid & 31;
  int rs = tid >> 5;
  int c0 = cg * 8;
  float s[8], q[8];
#pragma unroll
  for (int j = 0; j < 8; j++) { s[j] = 0.f; q[j] = 0.f; }
  for (int r = blockIdx.x * 8 + rs; r < N_NODES; r += gridDim.x * 8) {
    u16x8 v = *reinterpret_cast<const u16x8*>(x + (size_t)r * HID + c0);
#pragma unroll
    for (int j = 0; j < 8; j++) {
      float f = bfu(v[j]);
      s[j] += f;
      q[j] = fmaf(f, f, q[j]);
    }
  }
  __shared__ float ls[512];
  ls[tid] = 0.f;
  ls[tid + 256] = 0.f;
  __syncthreads();
#pragma unroll
  for (int j = 0; j < 8; j++) {
    atomicAdd(&ls[c0 + j], s[j]);
    atomicAdd(&ls[256 + c0 + j], q[j]);
  }
  __syncthreads();
  atomicAdd(&stats[tid], ls[tid]);
  atomicAdd(&stats[tid + 256], ls[tid + 256]);
}

// stats -> per-column scale/shift:  bn(x) = x*sc + sh
__global__ void k_bn_coef(const float* __restrict__ stats, const float* __restrict__ gamma,
                          const float* __restrict__ beta, float* __restrict__ scsh) {
  int c = threadIdx.x;
  const float invN = 1.0f / (float)N_NODES;
  float mu = stats[c] * invN;
  float var = stats[256 + c] * invN - mu * mu;
  float sc = gamma[c] * rsqrtf(var + EPS);
  scsh[c] = sc;
  scsh[256 + c] = beta[c] - mu * sc;
}

// h_bf += relu(x*sc + sh)  (bf16 trunk, coefficient form)
__global__ void k_bn_apply(const ushort* __restrict__ x, const float* __restrict__ scsh,
                           ushort* __restrict__ h_bf) {
  int total = N_NODES * 64;
  for (int i = blockIdx.x * 256 + threadIdx.x; i < total; i += gridDim.x * 256) {
    int c4 = (i & 63) * 4;
    float4 xv = bf4(*reinterpret_cast<const ushort4*>(x + (size_t)i * 4));
    float4 sc = *reinterpret_cast<const float4*>(scsh + c4);
    float4 sh = *reinterpret_cast<const float4*>(scsh + 256 + c4);
    float4 hv = bf4(*reinterpret_cast<const ushort4*>(h_bf + (size_t)i * 4));
    hv.x += fmaxf(fmaf(xv.x, sc.x, sh.x), 0.f);
    hv.y += fmaxf(fmaf(xv.y, sc.y, sh.y), 0.f);
    hv.z += fmaxf(fmaf(xv.z, sc.z, sh.z), 0.f);
    hv.w += fmaxf(fmaf(xv.w, sc.w, sh.w), 0.f);
    *reinterpret_cast<ushort4*>(h_bf + (size_t)i * 4) =
        make_ushort4(f2bf(hv.x), f2bf(hv.y), f2bf(hv.z), f2bf(hv.w));
  }
}

// ---------------- graph segment starts ----------------
__global__ void k_gstart(const int* __restrict__ batch, int* __restrict__ gstart) {
  int g = blockIdx.x * 256 + threadIdx.x;
  if (g > NG) return;
  int lo = 0, hi = N_NODES;
  while (lo < hi) {
    int mid = (lo + hi) >> 1;
    if (batch[mid] < g) lo = mid + 1; else hi = mid;
  }
  gstart[g] = lo;
}

// ---------------- global attention pooling (bf16 h) ----------------
__global__ void k_pool(const ushort* __restrict__ hb, const float* __restrict__ gate,
                       const int* __restrict__ gstart, float* __restrict__ hg) {
  __shared__ float red[256];
  __shared__ float wbuf[256];
  int g = blockIdx.x, tid = threadIdx.x;
  int b = gstart[g], e = gstart[g + 1];
  float m = -1e30f;
  for (int r = b + tid; r < e; r += 256) m = fmaxf(m, gate[r]);
  red[tid] = m;
  __syncthreads();
  for (int o = 128; o > 0; o >>= 1) {
    if (tid < o) red[tid] = fmaxf(red[tid], red[tid + o]);
    __syncthreads();
  }
  m = red[0];
  __syncthreads();
  float s = 0.f;
  for (int r = b + tid; r < e; r += 256) s += __expf(gate[r] - m);
  red[tid] = s;
  __syncthreads();
  for (int o = 128; o > 0; o >>= 1) {
    if (tid < o) red[tid] += red[tid + o];
    __syncthreads();
  }
  float inv = 1.0f / fmaxf(red[0], 1e-16f);
  __syncthreads();
  float acc = 0.f;
  for (int cb = b; cb < e; cb += 256) {
    int r = cb + tid;
    wbuf[tid] = (r < e) ? __expf(gate[r] - m) : 0.f;
    __syncthreads();
    int n = min(256, e - cb);
    for (int j = 0; j < n; j++)
      acc = fmaf(bfu(hb[(size_t)(cb + j) * HID + tid]), wbuf[j], acc);
    __syncthreads();
  }
  hg[(size_t)g * HID + tid] = acc * inv;
}

// ---------------- MLP head ----------------
__global__ void k_mlp(const float* __restrict__ hg, const float* __restrict__ W1,
                      const float* __restrict__ b1, const float* __restrict__ lng,
                      const float* __restrict__ lnb, const float* __restrict__ W2,
                      const float* __restrict__ b2, float* __restrict__ out) {
  __shared__ float row[HID];
  __shared__ float z[HID];
  __shared__ float red[HID];
  int g = blockIdx.x, tid = threadIdx.x;
  row[tid] = hg[(size_t)g * HID + tid];
  __syncthreads();
  float acc = b1[tid];
  for (int k = 0; k < HID; k++) acc = fmaf(row[k], W1[(size_t)k * HID + tid], acc);
  red[tid] = acc;
  __syncthreads();
  for (int o = 128; o > 0; o >>= 1) {
    if (tid < o) red[tid] += red[tid + o];
    __syncthreads();
  }
  float mu = red[0] * (1.0f / HID);
  __syncthreads();
  red[tid] = acc * acc;
  __syncthreads();
  for (int o = 128; o > 0; o >>= 1) {
    if (tid < o) red[tid] += red[tid + o];
    __syncthreads();
  }
  float var = red[0] * (1.0f / HID) - mu * mu;
  float zz = (acc - mu) * rsqrtf(var + EPS) * lng[tid] + lnb[tid];
  z[tid] = fmaxf(zz, 0.f);
  __syncthreads();
  if (tid < 64) {
    float o = b2[tid];
    for (int k = 0; k < HID; k++) o = fmaf(z[k], W2[(size_t)k * 64 + tid], o);
    out[(size_t)g * 64 + tid] = o;
  }
}

// ---------------- launch ----------------
extern "C" void kernel_launch(void* const* d_in, const int* in_sizes, int n_in,
                              void* d_out, int out_size, void* d_ws, size_t ws_size,
                              hipStream_t stream) {
  const float* x     = (const float*)d_in[0];
  const float* W_emb = (const float*)d_in[1];
  const float* b_emb = (const float*)d_in[2];
  const float* W_gcn = (const float*)d_in[3];
  const float* b_gcn = (const float*)d_in[4];
  const float* W_gat = (const float*)d_in[5];
  const float* a_src = (const float*)d_in[6];
  const float* a_dst = (const float*)d_in[7];
  const float* b_gat = (const float*)d_in[8];
  const float* W_l   = (const float*)d_in[9];
  const float* b_l   = (const float*)d_in[10];
  const float* W_r   = (const float*)d_in[11];
  const float* bn_g  = (const float*)d_in[12];
  const float* bn_b  = (const float*)d_in[13];
  const float* Wg1   = (const float*)d_in[14];
  const float* bg1   = (const float*)d_in[15];
  const float* Wg2   = (const float*)d_in[16];
  const float* bg2   = (const float*)d_in[17];
  const float* Wm1   = (const float*)d_in[18];
  const float* bm1   = (const float*)d_in[19];
  const float* lnmg  = (const float*)d_in[20];
  const float* lnmb  = (const float*)d_in[21];
  const float* Wm2   = (const float*)d_in[22];
  const float* bm2   = (const float*)d_in[23];
  const float* Wv1   = (const float*)d_in[24];
  const float* bv1   = (const float*)d_in[25];
  const float* lnvg  = (const float*)d_in[26];
  const float* lnvb  = (const float*)d_in[27];
  const float* Wv2   = (const float*)d_in[28];
  const float* bv2   = (const float*)d_in[29];
  const int* ei      = (const int*)d_in[30];
  const int* batch   = (const int*)d_in[31];
  float* out = (float*)d_out;

  float* ws = (float*)d_ws;
  float* h     = ws;                          // region reused as hB (bf16 trunk v2)
  float* t1    = h + (size_t)N_NODES * HID;   // reused as bf16 t1b
  float* alsrc = t1 + (size_t)N_NODES * HID;  // [N][8]
  float* aldst = alsrc + N_NODES * 8;         // [N][8]
  float* dis   = aldst + N_NODES * 8;
  float* gate  = dis + N_NODES;
  float* hg    = gate + N_NODES;
  float* zbase = hg + NG * HID;
  float* bnst  = zbase;                // 3 * 512
  int* row_cnt = (int*)(zbase + 3 * 512);
  int* fill    = row_cnt + N_NODES;
  int* row_ptr = fill + N_NODES;
  int* col_src = row_ptr + N_NODES + 1;
  int* gstart  = col_src + N_EDGES;
  int* psum    = gstart + NG + 1;
  int* boff    = psum + 64;
  float* scsh  = (float*)(boff + 64);  // 3 * 512 coefficients

  ushort* t1b = (ushort*)t1;
  ushort* hB  = (ushort*)h;            // second trunk buffer (ping-pong)

  size_t off = (size_t)((char*)(scsh + 3 * 512) - (char*)d_ws);
  off = (off + 15) & ~(size_t)15;
  ushort* h_bf   = (ushort*)((char*)d_ws + off);
  ushort* t0_bf  = h_bf + (size_t)N_NODES * HID;
  ushort* wemb_t = t0_bf + (size_t)N_NODES * HID;
  ushort* wgcn_t = wemb_t + 128 * 256;
  ushort* wgat_t = wgcn_t + 256 * 256;
  ushort* wr_t   = wgat_t + 256 * 256;
  ushort* wl_t   = wr_t + 256 * 256;
  ushort* wg1_t  = wl_t + 256 * 256;   // 256*128

  size_t zbytes = (size_t)3 * 512 * 4 + 2 * (size_t)N_NODES * 4;
  hipMemsetAsync(zbase, 0, zbytes, stream);

  // CSR by dst (hierarchical scan + fused dis)
  k_csr_count<<<(N_EDGES + 255) / 256, 256, 0, stream>>>(ei, row_cnt);
  k_scan_part<<<SCB, 256, 0, stream>>>(row_cnt, psum);
  k_scan_top<<<1, 64, 0, stream>>>(psum, boff, row_ptr);
  k_scan_out<<<SCB, 256, 0, stream>>>(row_cnt, boff, row_ptr, dis);
  k_csr_fill<<<(N_EDGES + 255) / 256, 256, 0, stream>>>(ei, row_ptr, fill, col_src);

  // all weight transposes in one launch
  WtArgs wa;
  wa.src[0] = W_emb; wa.dst[0] = wemb_t; wa.K[0] = 128; wa.C[0] = 256; wa.off[0] = 0;
  wa.src[1] = W_gcn; wa.dst[1] = wgcn_t; wa.K[1] = 256; wa.C[1] = 256; wa.off[1] = 128;
  wa.src[2] = W_gat; wa.dst[2] = wgat_t; wa.K[2] = 256; wa.C[2] = 256; wa.off[2] = 384;
  wa.src[3] = W_r;   wa.dst[3] = wr_t;   wa.K[3] = 256; wa.C[3] = 256; wa.off[3] = 640;
  wa.src[4] = W_l;   wa.dst[4] = wl_t;   wa.K[4] = 256; wa.C[4] = 256; wa.off[4] = 896;
  wa.src[5] = Wg1;   wa.dst[5] = wg1_t;  wa.K[5] = 256; wa.C[5] = 128; wa.off[5] = 1152;
  k_wt_all<<<1280, 256, 0, stream>>>(wa);

  const int RB = (N_NODES + 63) / 64;   // 782 gemm row-blocks
  const int AB = (N_NODES + 3) / 4;     // 12500 agg blocks

  // embedding: h_bf = x @ W_emb + b_emb  (fp32 A converted on load)
  k_mgemm<128, 256, 1, false, true, false, false, false><<<dim3(RB, 1), 256, 0, stream>>>(
      x, wemb_t, nullptr, nullptr, b_emb, h_bf, nullptr, nullptr, nullptr,
      nullptr, nullptr, nullptr, nullptr, nullptr, nullptr, nullptr, N_NODES, 0);

  // --- GCN: xt = h @ W_gcn (column-split x2) ---
  k_mgemm<256, 256, 2, false, false, false, false, false><<<dim3(RB, 2), 256, 0, stream>>>(
      h_bf, wgcn_t, nullptr, nullptr, nullptr, t0_bf, nullptr, nullptr, nullptr,
      nullptr, nullptr, nullptr, nullptr, nullptr, nullptr, nullptr, N_NODES, 0);
  k_gcn_agg<<<AB, 256, 0, stream>>>(t0_bf, dis, row_ptr, col_src, b_gcn, t1b);
  k_bn_stats<<<1024, 256, 0, stream>>>(t1b, bnst);
  k_bn_coef<<<1, 256, 0, stream>>>(bnst, bn_g, bn_b, scsh);

  // --- GAT: BN(gcn) folded into A-load; new trunk -> hB; al fused; split x2 ---
  k_mgemm<256, 256, 2, false, false, false, true, true><<<dim3(RB, 2), 256, 0, stream>>>(
      t1b, wgat_t, nullptr, nullptr, nullptr, t0_bf, nullptr, nullptr, nullptr,
      a_src, a_dst, alsrc, aldst, scsh, h_bf, hB, N_NODES, 0);
  k_gat_agg<<<AB, 256, 0, stream>>>(t0_bf, alsrc, aldst, row_ptr, col_src, b_gat, t1b);
  k_bn_stats<<<1024, 256, 0, stream>>>(t1b, bnst + 512);
  k_bn_coef<<<1, 256, 0, stream>>>(bnst + 512, bn_g + HID, bn_b + HID, scsh + 512);
  k_bn_apply<<<1024, 256, 0, stream>>>(t1b, scsh + 512, hB);

  // --- SAGE: t1b = hB@W_r + b_l + mean@W_l (dual, split x2) ---
  k_sage_agg<<<AB, 256, 0, stream>>>(hB, row_ptr, col_src, t0_bf);
  k_mgemm<256, 256, 2, true, false, false, false, false><<<dim3(RB, 2), 256, 0, stream>>>(
      hB, wr_t, t0_bf, wl_t, b_l, t1b, nullptr, nullptr, nullptr,
      nullptr, nullptr, nullptr, nullptr, nullptr, nullptr, nullptr, N_NODES, 0);
  k_bn_stats<<<1024, 256, 0, stream>>>(t1b, bnst + 1024);
  k_bn_coef<<<1, 256, 0, stream>>>(bnst + 1024, bn_g + 2 * HID, bn_b + 2 * HID, scsh + 1024);

  // --- gate: BN(sage) folded; final trunk -> h_bf; gate head via atomics; split x2 ---
  hipMemsetAsync(gate, 0, (size_t)N_NODES * 4, stream);
  k_mgemm<256, 128, 2, false, false, true, false, true><<<dim3(RB, 2), 256, 0, stream>>>(
      t1b, wg1_t, nullptr, nullptr, bg1, nullptr, Wg2, bg2, gate,
      nullptr, nullptr, nullptr, nullptr, scsh + 1024, hB, h_bf, N_NODES, 1);
  k_gstart<<<3, 256, 0, stream>>>(batch, gstart);
  k_pool<<<NG, 256, 0, stream>>>(h_bf, gate, gstart, hg);

  // --- heads ---
  k_mlp<<<NG, 256, 0, stream>>>(hg, Wm1, bm1, lnmg, lnmb, Wm2, bm2, out);
  k_mlp<<<NG, 256, 0, stream>>>(hg, Wv1, bv1, lnvg, lnvb, Wv2, bv2, out + (size_t)NG * 64);
}

// Round 15
// 554.585 us; speedup vs baseline: 1.0175x; 1.0033x over previous
//
#include <hip/hip_runtime.h>
#include <cstdint>
#include <cstddef>

#define N_NODES 50000
#define N_EDGES 500000
#define NG 512
#define HID 256
#define EPS 1e-5f
#define SCB 49  // scan blocks: ceil(50000/1024)

typedef __attribute__((ext_vector_type(8))) __bf16 bf16x8;
typedef __attribute__((ext_vector_type(8))) ushort u16x8;
typedef __attribute__((ext_vector_type(4))) float f32x4;

__device__ __forceinline__ ushort f2bf(float f) {
  uint32_t u = __float_as_uint(f);
  uint32_t r = (u + 0x7fffu + ((u >> 16) & 1u)) >> 16;
  return (ushort)r;
}
__device__ __forceinline__ float bfu(ushort u) { return __uint_as_float(((uint32_t)u) << 16); }
__device__ __forceinline__ float4 bf4(ushort4 u) {
  return make_float4(bfu(u.x), bfu(u.y), bfu(u.z), bfu(u.w));
}

// ---------------- CSR build ----------------
__global__ void k_csr_count(const int* __restrict__ ei, int* __restrict__ cnt) {
  int e = blockIdx.x * 256 + threadIdx.x;
  if (e < N_EDGES) atomicAdd(&cnt[ei[N_EDGES + e]], 1);
}

__global__ void k_scan_part(const int* __restrict__ cnt, int* __restrict__ psum) {
  __shared__ int red[256];
  int tid = threadIdx.x;
  int i0 = blockIdx.x * 1024 + tid * 4;
  int s = 0;
  if (i0 + 4 <= N_NODES) {
    int4 v = *reinterpret_cast<const int4*>(cnt + i0);
    s = v.x + v.y + v.z + v.w;
  } else {
    for (int k = 0; k < 4; k++)
      if (i0 + k < N_NODES) s += cnt[i0 + k];
  }
  red[tid] = s;
  __syncthreads();
  for (int o = 128; o > 0; o >>= 1) {
    if (tid < o) red[tid] += red[tid + o];
    __syncthreads();
  }
  if (tid == 0) psum[blockIdx.x] = red[0];
}

__global__ void k_scan_top(const int* __restrict__ psum, int* __restrict__ boff,
                           int* __restrict__ row_ptr) {
  int t = threadIdx.x;  // 64
  int v = (t < SCB) ? psum[t] : 0;
  int own = v;
  for (int o = 1; o < 64; o <<= 1) {
    int u = __shfl_up(v, o);
    if (t >= o) v += u;
  }
  if (t < SCB) boff[t] = v - own;
  if (t == 63) row_ptr[N_NODES] = v;
}

__global__ void k_scan_out(const int* __restrict__ cnt, const int* __restrict__ boff,
                           int* __restrict__ row_ptr, float* __restrict__ dis) {
  __shared__ int ps[256];
  int tid = threadIdx.x;
  int i0 = blockIdx.x * 1024 + tid * 4;
  int v[4];
#pragma unroll
  for (int k = 0; k < 4; k++) v[k] = (i0 + k < N_NODES) ? cnt[i0 + k] : 0;
  int s = v[0] + v[1] + v[2] + v[3];
  ps[tid] = s;
  __syncthreads();
  for (int o = 1; o < 256; o <<= 1) {
    int add = (tid >= o) ? ps[tid - o] : 0;
    __syncthreads();
    ps[tid] += add;
    __syncthreads();
  }
  int run = boff[blockIdx.x] + ((tid > 0) ? ps[tid - 1] : 0);
#pragma unroll
  for (int k = 0; k < 4; k++) {
    if (i0 + k < N_NODES) {
      row_ptr[i0 + k] = run;
      dis[i0 + k] = rsqrtf((float)v[k] + 1.0f);
      run += v[k];
    }
  }
}

__global__ void k_csr_fill(const int* __restrict__ ei, const int* __restrict__ row_ptr,
                           int* __restrict__ fill, int* __restrict__ col_src) {
  int e = blockIdx.x * 256 + threadIdx.x;
  if (e >= N_EDGES) return;
  int s = ei[e], d = ei[N_EDGES + e];
  int pos = row_ptr[d] + atomicAdd(&fill[d], 1);
  col_src[pos] = s;
}

// ---------------- batched weight transpose: W[K,C] fp32 -> Wt[C,K] bf16 ----------------
struct WtArgs {
  const float* src[6];
  ushort* dst[6];
  int K[6];
  int C[6];
  int off[6];
};

__global__ void k_wt_all(WtArgs a) {
  int b = blockIdx.x;
  int ji = 0;
#pragma unroll
  for (int t = 1; t < 6; t++)
    if (b >= a.off[t]) ji = t;
  int K = a.K[ji], C = a.C[ji];
  int i = (b - a.off[ji]) * 256 + threadIdx.x;
  int c = i / K, k = i - c * K;
  a.dst[ji][i] = f2bf(a.src[ji][k * C + c]);
}

// ---------------- MFMA GEMM: 128-row/512-thread blocks, double-buffered async panels --------
// out_bf[M,C] = A1@W1t^T (+A2@W2t^T) + bias. Wt [C,K] bf16. Grid: ceil(M/128).
// 8 waves; wave owns 16 rows x 64 cols per panel. W staged via global_load_lds into
// 2x32KB LDS; next panel issued before current compute. GATE: fused gate head.
// GATAL: fused GAT attention-logit epilogue -> als/ald[node][head].
template <int K, int C, bool DUAL, bool AFP32, bool GATE, bool GATAL>
__global__ __launch_bounds__(512) void k_mgemm(
    const void* __restrict__ A1v, const ushort* __restrict__ W1t,
    const ushort* __restrict__ A2, const ushort* __restrict__ W2t,
    const float* __restrict__ bias, ushort* __restrict__ out_bf,
    const float* __restrict__ gw, const float* __restrict__ gb,
    float* __restrict__ gate, const float* __restrict__ asv,
    const float* __restrict__ adv, float* __restrict__ als,
    float* __restrict__ ald, int M, int relu) {
  constexpr int KS = K / 32;             // MFMA k-steps
  constexpr int CHK = K / 8;             // 16B chunks per panel row
  constexpr int NPAN = C / 64;           // column panels
  constexpr int NISS = (64 * CHK) / 512; // gload_lds issues per thread per panel
  constexpr int NTOT = NPAN * (DUAL ? 2 : 1);
  constexpr int PELEM = 64 * K;          // ushorts per panel buffer
  __shared__ ushort wlds[2 * PELEM];
  const int tid = threadIdx.x;
  const int lane = tid & 63;
  const int wid = tid >> 6;
  const int r16 = lane & 15;
  const int kg = lane >> 4;
  const int rbase = blockIdx.x * 128 + wid * 16;

  int arow = rbase + r16;
  if (arow >= M) arow = M - 1;

  // A fragments, loaded once
  bf16x8 af[KS], af2[KS];
  if constexpr (AFP32) {
    const float* ap = (const float*)A1v + (size_t)arow * K + kg * 8;
#pragma unroll
    for (int ks = 0; ks < KS; ks++) {
      float4 lo = *reinterpret_cast<const float4*>(ap + ks * 32);
      float4 hi = *reinterpret_cast<const float4*>(ap + ks * 32 + 4);
      union { u16x8 u; bf16x8 b; } cv;
      cv.u = (u16x8){f2bf(lo.x), f2bf(lo.y), f2bf(lo.z), f2bf(lo.w),
                     f2bf(hi.x), f2bf(hi.y), f2bf(hi.z), f2bf(hi.w)};
      af[ks] = cv.b;
    }
  } else {
    const ushort* ap = (const ushort*)A1v + (size_t)arow * K + kg * 8;
#pragma unroll
    for (int ks = 0; ks < KS; ks++)
      af[ks] = *reinterpret_cast<const bf16x8*>(ap + ks * 32);
  }
  if constexpr (DUAL) {
    const ushort* ap = A2 + (size_t)arow * K + kg * 8;
#pragma unroll
    for (int ks = 0; ks < KS; ks++)
      af2[ks] = *reinterpret_cast<const bf16x8*>(ap + ks * 32);
  }

  float greg[4] = {0.f, 0.f, 0.f, 0.f};
  f32x4 acc[4];

  // async stage: linear LDS chunk p holds W[c, (p%CHK)^(c&7)]; read-side swizzle matches.
#define STAGE_ASYNC(WSRC, PAN, BUF)                                            \
  {                                                                            \
    const ushort* base_ = (WSRC) + (size_t)((PAN) * 64) * K;                   \
    _Pragma("unroll") for (int j = 0; j < NISS; j++) {                         \
      int p_ = j * 512 + tid;                                                  \
      int c_ = p_ / CHK, jj_ = p_ % CHK;                                       \
      const ushort* g_ = base_ + c_ * K + (jj_ ^ (c_ & 7)) * 8;                \
      ushort* l_ = &wlds[(BUF) * PELEM + (j * 512 + wid * 64) * 8];            \
      __builtin_amdgcn_global_load_lds(                                        \
          (const __attribute__((address_space(1))) void*)(g_),                 \
          (__attribute__((address_space(3))) void*)(l_), 16, 0, 0);            \
    }                                                                          \
  }

#define COMPUTE(AF, BUF)                                                       \
  {                                                                            \
    const ushort* wb_ = &wlds[(BUF) * PELEM];                                  \
    _Pragma("unroll") for (int ct = 0; ct < 4; ct++) {                         \
      bf16x8 wf[KS];                                                           \
      int colr = ct * 16 + r16;                                                \
      _Pragma("unroll") for (int ks = 0; ks < KS; ks++) {                      \
        int slot = colr * CHK + ((ks * 4 + kg) ^ (r16 & 7));                   \
        wf[ks] = *reinterpret_cast<const bf16x8*>(&wb_[slot * 8]);             \
      }                                                                        \
      _Pragma("unroll") for (int ks = 0; ks < KS; ks++)                        \
        acc[ct] = __builtin_amdgcn_mfma_f32_16x16x32_bf16((AF)[ks], wf[ks],    \
                                                          acc[ct], 0, 0, 0);   \
    }                                                                          \
  }

  // prologue: stage panel 0 into buffer 0
  STAGE_ASYNC(W1t, 0, 0);
  __syncthreads();

#pragma unroll
  for (int q = 0; q < NTOT; q++) {
    const int pan = DUAL ? (q >> 1) : q;
    const int pass = DUAL ? (q & 1) : 0;
    const int cur = q & 1;
    const int c0 = pan * 64;
    if (pass == 0) {
#pragma unroll
      for (int ct = 0; ct < 4; ct++) acc[ct] = (f32x4){0.f, 0.f, 0.f, 0.f};
    }
    // issue next sub-panel's async loads into the other buffer
    if (q + 1 < NTOT) {
      const int npan = DUAL ? ((q + 1) >> 1) : (q + 1);
      const ushort* Wq = (DUAL && ((q + 1) & 1)) ? W2t : W1t;
      STAGE_ASYNC(Wq, npan, cur ^ 1);
    }
    // compute current sub-panel from LDS
    if (DUAL && pass) {
      COMPUTE(af2, cur);
    } else {
      COMPUTE(af, cur);
    }
    // epilogue when panel complete
    if (pass == (DUAL ? 1 : 0)) {
      if constexpr (GATE) {
#pragma unroll
        for (int ct = 0; ct < 4; ct++) {
          int col = c0 + ct * 16 + r16;
          float bv = bias[col];
          float wv = gw[col];
#pragma unroll
          for (int i = 0; i < 4; i++) {
            float v = fmaxf(acc[ct][i] + bv, 0.f);
            greg[i] = fmaf(v, wv, greg[i]);
          }
        }
      } else {
#pragma unroll
        for (int ct = 0; ct < 4; ct++) {
          int col = c0 + ct * 16 + r16;
          float bv = bias ? bias[col] : 0.f;
#pragma unroll
          for (int i = 0; i < 4; i++) {
            int row = rbase + kg * 4 + i;
            if (row < M) {
              float v = acc[ct][i] + bv;
              if (relu) v = fmaxf(v, 0.f);
              out_bf[(size_t)row * C + col] = f2bf(v);
            }
          }
        }
      }
      if constexpr (GATAL) {
        // fused GAT attention logits, [node][head] layout
        float ps_[2][4], pd_[2][4];
#pragma unroll
        for (int h2 = 0; h2 < 2; h2++)
#pragma unroll
          for (int i = 0; i < 4; i++) { ps_[h2][i] = 0.f; pd_[h2][i] = 0.f; }
#pragma unroll
        for (int ct = 0; ct < 4; ct++) {
          int col = c0 + ct * 16 + r16;
          float as_ = asv[col], ad_ = adv[col];
          int h2 = ct >> 1;
#pragma unroll
          for (int i = 0; i < 4; i++) {
            ps_[h2][i] = fmaf(acc[ct][i], as_, ps_[h2][i]);
            pd_[h2][i] = fmaf(acc[ct][i], ad_, pd_[h2][i]);
          }
        }
#pragma unroll
        for (int h2 = 0; h2 < 2; h2++)
#pragma unroll
          for (int i = 0; i < 4; i++) {
#pragma unroll
            for (int o = 1; o < 16; o <<= 1) {
              ps_[h2][i] += __shfl_xor(ps_[h2][i], o);
              pd_[h2][i] += __shfl_xor(pd_[h2][i], o);
            }
          }
        if (r16 == 0) {
#pragma unroll
          for (int i = 0; i < 4; i++) {
            int row = rbase + kg * 4 + i;
            if (row < M) {
              als[row * 8 + pan * 2 + 0] = ps_[0][i];
              ald[row * 8 + pan * 2 + 0] = pd_[0][i];
              als[row * 8 + pan * 2 + 1] = ps_[1][i];
              ald[row * 8 + pan * 2 + 1] = pd_[1][i];
            }
          }
        }
      }
    }
    __syncthreads();  // drains next-panel loads + read fence
  }

  if constexpr (GATE) {
#pragma unroll
    for (int i = 0; i < 4; i++) {
#pragma unroll
      for (int o = 1; o < 16; o <<= 1) greg[i] += __shfl_xor(greg[i], o);
    }
    if (r16 == 0) {
      float b0 = gb[0];
#pragma unroll
      for (int i = 0; i < 4; i++) {
        int row = rbase + kg * 4 + i;
        if (row < M) gate[row] = greg[i] + b0;
      }
    }
  }
#undef STAGE_ASYNC
#undef COMPUTE
}

// ---------------- GCN aggregation: wave/node, 32 lanes/row, 8-edge ILP, bf16 out ------------
__global__ void k_gcn_agg(const ushort* __restrict__ xt, const float* __restrict__ dis,
                          const int* __restrict__ row_ptr, const int* __restrict__ col_src,
                          const float* __restrict__ b_gcn, ushort* __restrict__ outb) {
  int node = blockIdx.x * 4 + (threadIdx.x >> 6);
  if (node >= N_NODES) return;
  int lane = threadIdx.x & 63;
  int half = lane >> 5;
  int c0 = (lane & 31) * 8;
  float di = dis[node];
  float acc[8];
#pragma unroll
  for (int j = 0; j < 8; j++) acc[j] = 0.f;
  int b = row_ptr[node], e = row_ptr[node + 1];
  int g0 = b;
  for (; g0 + 8 <= e; g0 += 8) {
    int i0 = g0 + half * 4;
    int s0 = col_src[i0], s1 = col_src[i0 + 1], s2 = col_src[i0 + 2], s3 = col_src[i0 + 3];
    float w0 = di * dis[s0], w1 = di * dis[s1], w2 = di * dis[s2], w3 = di * dis[s3];
    u16x8 u0 = *reinterpret_cast<const u16x8*>(xt + (size_t)s0 * HID + c0);
    u16x8 u1 = *reinterpret_cast<const u16x8*>(xt + (size_t)s1 * HID + c0);
    u16x8 u2 = *reinterpret_cast<const u16x8*>(xt + (size_t)s2 * HID + c0);
    u16x8 u3 = *reinterpret_cast<const u16x8*>(xt + (size_t)s3 * HID + c0);
#pragma unroll
    for (int j = 0; j < 8; j++) {
      acc[j] = fmaf(bfu(u0[j]), w0, acc[j]);
      acc[j] = fmaf(bfu(u1[j]), w1, acc[j]);
      acc[j] = fmaf(bfu(u2[j]), w2, acc[j]);
      acc[j] = fmaf(bfu(u3[j]), w3, acc[j]);
    }
  }
  for (; g0 + 4 <= e; g0 += 4) {
    int i0 = g0 + half * 2;
    int s0 = col_src[i0], s1 = col_src[i0 + 1];
    float w0 = di * dis[s0], w1 = di * dis[s1];
    u16x8 u0 = *reinterpret_cast<const u16x8*>(xt + (size_t)s0 * HID + c0);
    u16x8 u1 = *reinterpret_cast<const u16x8*>(xt + (size_t)s1 * HID + c0);
#pragma unroll
    for (int j = 0; j < 8; j++) {
      acc[j] = fmaf(bfu(u0[j]), w0, acc[j]);
      acc[j] = fmaf(bfu(u1[j]), w1, acc[j]);
    }
  }
  {  // tail (0..3 edges), guarded
    int i0 = g0 + half * 2;
    int s0 = 0, s1 = 0;
    float w0 = 0.f, w1 = 0.f;
    if (i0 < e) { s0 = col_src[i0]; w0 = di * dis[s0]; }
    if (i0 + 1 < e) { s1 = col_src[i0 + 1]; w1 = di * dis[s1]; }
    u16x8 u0 = *reinterpret_cast<const u16x8*>(xt + (size_t)s0 * HID + c0);
    u16x8 u1 = *reinterpret_cast<const u16x8*>(xt + (size_t)s1 * HID + c0);
#pragma unroll
    for (int j = 0; j < 8; j++) {
      acc[j] = fmaf(bfu(u0[j]), w0, acc[j]);
      acc[j] = fmaf(bfu(u1[j]), w1, acc[j]);
    }
  }
#pragma unroll
  for (int j = 0; j < 8; j++) acc[j] += __shfl_xor(acc[j], 32);
  if (!half) {
    u16x8 un = *reinterpret_cast<const u16x8*>(xt + (size_t)node * HID + c0);
    float w0 = di * di;
    u16x8 r;
#pragma unroll
    for (int j = 0; j < 8; j++) {
      float v = fmaf(bfu(un[j]), w0, acc[j]) + b_gcn[c0 + j];
      r[j] = f2bf(v);
    }
    *reinterpret_cast<u16x8*>(outb + (size_t)node * HID + c0) = r;
  }
}

__device__ __forceinline__ float leaky02(float x) { return x > 0.f ? x : 0.2f * x; }

// ---------------- Single-pass GAT agg, 32 lanes/row, 8-edge ILP; al in [node][head] ---------
__global__ void k_gat_agg(const ushort* __restrict__ xt, const float* __restrict__ alsrc,
                          const float* __restrict__ aldst, const int* __restrict__ row_ptr,
                          const int* __restrict__ col_src, const float* __restrict__ b_gat,
                          ushort* __restrict__ outb) {
  int node = blockIdx.x * 4 + (threadIdx.x >> 6);
  if (node >= N_NODES) return;
  int lane = threadIdx.x & 63;
  int half = lane >> 5;
  int l32 = lane & 31;
  int c0 = l32 * 8;
  int hh = l32 >> 2;
  float ad = aldst[node * 8 + hh];
  float acc[8];
#pragma unroll
  for (int j = 0; j < 8; j++) acc[j] = 0.f;
  float s = 0.f;
  int b = row_ptr[node], e = row_ptr[node + 1];
  int g0 = b;
  for (; g0 + 8 <= e; g0 += 8) {
    int i0 = g0 + half * 4;
    int s0 = col_src[i0], s1 = col_src[i0 + 1], s2 = col_src[i0 + 2], s3 = col_src[i0 + 3];
    float g0v = alsrc[s0 * 8 + hh], g1v = alsrc[s1 * 8 + hh];
    float g2v = alsrc[s2 * 8 + hh], g3v = alsrc[s3 * 8 + hh];
    u16x8 u0 = *reinterpret_cast<const u16x8*>(xt + (size_t)s0 * HID + c0);
    u16x8 u1 = *reinterpret_cast<const u16x8*>(xt + (size_t)s1 * HID + c0);
    u16x8 u2 = *reinterpret_cast<const u16x8*>(xt + (size_t)s2 * HID + c0);
    u16x8 u3 = *reinterpret_cast<const u16x8*>(xt + (size_t)s3 * HID + c0);
    float a0 = __expf(leaky02(g0v + ad));
    float a1 = __expf(leaky02(g1v + ad));
    float a2 = __expf(leaky02(g2v + ad));
    float a3 = __expf(leaky02(g3v + ad));
    s += a0 + a1 + a2 + a3;
#pragma unroll
    for (int j = 0; j < 8; j++) {
      acc[j] = fmaf(bfu(u0[j]), a0, acc[j]);
      acc[j] = fmaf(bfu(u1[j]), a1, acc[j]);
      acc[j] = fmaf(bfu(u2[j]), a2, acc[j]);
      acc[j] = fmaf(bfu(u3[j]), a3, acc[j]);
    }
  }
  for (; g0 + 4 <= e; g0 += 4) {
    int i0 = g0 + half * 2;
    int s0 = col_src[i0], s1 = col_src[i0 + 1];
    float a0 = __expf(leaky02(alsrc[s0 * 8 + hh] + ad));
    float a1 = __expf(leaky02(alsrc[s1 * 8 + hh] + ad));
    u16x8 u0 = *reinterpret_cast<const u16x8*>(xt + (size_t)s0 * HID + c0);
    u16x8 u1 = *reinterpret_cast<const u16x8*>(xt + (size_t)s1 * HID + c0);
    s += a0 + a1;
#pragma unroll
    for (int j = 0; j < 8; j++) {
      acc[j] = fmaf(bfu(u0[j]), a0, acc[j]);
      acc[j] = fmaf(bfu(u1[j]), a1, acc[j]);
    }
  }
  {  // tail, guarded
    int i0 = g0 + half * 2;
    int s0 = 0, s1 = 0;
    float a0 = 0.f, a1 = 0.f;
    if (i0 < e) { s0 = col_src[i0]; a0 = __expf(leaky02(alsrc[s0 * 8 + hh] + ad)); }
    if (i0 + 1 < e) { s1 = col_src[i0 + 1]; a1 = __expf(leaky02(alsrc[s1 * 8 + hh] + ad)); }
    u16x8 u0 = *reinterpret_cast<const u16x8*>(xt + (size_t)s0 * HID + c0);
    u16x8 u1 = *reinterpret_cast<const u16x8*>(xt + (size_t)s1 * HID + c0);
    s += a0 + a1;
#pragma unroll
    for (int j = 0; j < 8; j++) {
      acc[j] = fmaf(bfu(u0[j]), a0, acc[j]);
      acc[j] = fmaf(bfu(u1[j]), a1, acc[j]);
    }
  }
#pragma unroll
  for (int j = 0; j < 8; j++) acc[j] += __shfl_xor(acc[j], 32);
  s += __shfl_xor(s, 32);
  if (!half) {
    float e0 = __expf(leaky02(alsrc[node * 8 + hh] + ad));
    u16x8 un = *reinterpret_cast<const u16x8*>(xt + (size_t)node * HID + c0);
    float inv_s = 1.0f / (s + e0);
    u16x8 r;
#pragma unroll
    for (int j = 0; j < 8; j++) {
      float v = fmaf(bfu(un[j]), e0, acc[j]) * inv_s + b_gat[c0 + j];
      r[j] = f2bf(v);
    }
    *reinterpret_cast<u16x8*>(outb + (size_t)node * HID + c0) = r;
  }
}

// ---------------- SAGE mean aggregation: 32 lanes/row, 8-edge ILP, bf16 in/out --------------
__global__ void k_sage_agg(const ushort* __restrict__ h, const int* __restrict__ row_ptr,
                           const int* __restrict__ col_src, ushort* __restrict__ outb) {
  int node = blockIdx.x * 4 + (threadIdx.x >> 6);
  if (node >= N_NODES) return;
  int lane = threadIdx.x & 63;
  int half = lane >> 5;
  int c0 = (lane & 31) * 8;
  float acc[8];
#pragma unroll
  for (int j = 0; j < 8; j++) acc[j] = 0.f;
  int b = row_ptr[node], e = row_ptr[node + 1];
  int g0 = b;
  for (; g0 + 8 <= e; g0 += 8) {
    int i0 = g0 + half * 4;
    int s0 = col_src[i0], s1 = col_src[i0 + 1], s2 = col_src[i0 + 2], s3 = col_src[i0 + 3];
    u16x8 u0 = *reinterpret_cast<const u16x8*>(h + (size_t)s0 * HID + c0);
    u16x8 u1 = *reinterpret_cast<const u16x8*>(h + (size_t)s1 * HID + c0);
    u16x8 u2 = *reinterpret_cast<const u16x8*>(h + (size_t)s2 * HID + c0);
    u16x8 u3 = *reinterpret_cast<const u16x8*>(h + (size_t)s3 * HID + c0);
#pragma unroll
    for (int j = 0; j < 8; j++)
      acc[j] += (bfu(u0[j]) + bfu(u1[j])) + (bfu(u2[j]) + bfu(u3[j]));
  }
  for (; g0 + 4 <= e; g0 += 4) {
    int i0 = g0 + half * 2;
    int s0 = col_src[i0], s1 = col_src[i0 + 1];
    u16x8 u0 = *reinterpret_cast<const u16x8*>(h + (size_t)s0 * HID + c0);
    u16x8 u1 = *reinterpret_cast<const u16x8*>(h + (size_t)s1 * HID + c0);
#pragma unroll
    for (int j = 0; j < 8; j++) acc[j] += bfu(u0[j]) + bfu(u1[j]);
  }
  {
    int i0 = g0 + half * 2;
    int s0 = 0, s1 = 0;
    float w0 = 0.f, w1 = 0.f;
    if (i0 < e) { s0 = col_src[i0]; w0 = 1.f; }
    if (i0 + 1 < e) { s1 = col_src[i0 + 1]; w1 = 1.f; }
    u16x8 u0 = *reinterpret_cast<const u16x8*>(h + (size_t)s0 * HID + c0);
    u16x8 u1 = *reinterpret_cast<const u16x8*>(h + (size_t)s1 * HID + c0);
#pragma unroll
    for (int j = 0; j < 8; j++) {
      acc[j] = fmaf(bfu(u0[j]), w0, acc[j]);
      acc[j] = fmaf(bfu(u1[j]), w1, acc[j]);
    }
  }
#pragma unroll
  for (int j = 0; j < 8; j++) acc[j] += __shfl_xor(acc[j], 32);
  if (!half) {
    float inv = 1.0f / fmaxf((float)(e - b), 1.0f);
    u16x8 r;
#pragma unroll
    for (int j = 0; j < 8; j++) r[j] = f2bf(acc[j] * inv);
    *reinterpret_cast<u16x8*>(outb + (size_t)node * HID + c0) = r;
  }
}

// ---------------- BatchNorm stats: vectorized 16B loads, LDS reduce, 1024 blocks ------------
__global__ __launch_bounds__(256) void k_bn_stats(const ushort* __restrict__ x,
                                                  float* __restrict__ stats) {
  int tid = threadIdx.x;
  int cg = tid & 31;
  int rs = tid >> 5;
  int c0 = cg * 8;
  float s[8], q[8];
#pragma unroll
  for (int j = 0; j < 8; j++) { s[j] = 0.f; q[j] = 0.f; }
  for (int r = blockIdx.x * 8 + rs; r < N_NODES; r += gridDim.x * 8) {
    u16x8 v = *reinterpret_cast<const u16x8*>(x + (size_t)r * HID + c0);
#pragma unroll
    for (int j = 0; j < 8; j++) {
      float f = bfu(v[j]);
      s[j] += f;
      q[j] = fmaf(f, f, q[j]);
    }
  }
  __shared__ float ls[512];
  ls[tid] = 0.f;
  ls[tid + 256] = 0.f;
  __syncthreads();
#pragma unroll
  for (int j = 0; j < 8; j++) {
    atomicAdd(&ls[c0 + j], s[j]);
    atomicAdd(&ls[256 + c0 + j], q[j]);
  }
  __syncthreads();
  atomicAdd(&stats[tid], ls[tid]);
  atomicAdd(&stats[tid + 256], ls[tid + 256]);
}

// stats -> per-column scale/shift:  bn(x) = x*sc + sh
__global__ void k_bn_coef(const float* __restrict__ stats, const float* __restrict__ gamma,
                          const float* __restrict__ beta, float* __restrict__ scsh) {
  int c = threadIdx.x;
  const float invN = 1.0f / (float)N_NODES;
  float mu = stats[c] * invN;
  float var = stats[256 + c] * invN - mu * mu;
  float sc = gamma[c] * rsqrtf(var + EPS);
  scsh[c] = sc;
  scsh[256 + c] = beta[c] - mu * sc;
}

// h_bf += relu(x*sc + sh)  (bf16 trunk, coefficient form)
__global__ void k_bn_apply(const ushort* __restrict__ x, const float* __restrict__ scsh,
                           ushort* __restrict__ h_bf) {
  int total = N_NODES * 64;
  for (int i = blockIdx.x * 256 + threadIdx.x; i < total; i += gridDim.x * 256) {
    int c4 = (i & 63) * 4;
    float4 xv = bf4(*reinterpret_cast<const ushort4*>(x + (size_t)i * 4));
    float4 sc = *reinterpret_cast<const float4*>(scsh + c4);
    float4 sh = *reinterpret_cast<const float4*>(scsh + 256 + c4);
    float4 hv = bf4(*reinterpret_cast<const ushort4*>(h_bf + (size_t)i * 4));
    hv.x += fmaxf(fmaf(xv.x, sc.x, sh.x), 0.f);
    hv.y += fmaxf(fmaf(xv.y, sc.y, sh.y), 0.f);
    hv.z += fmaxf(fmaf(xv.z, sc.z, sh.z), 0.f);
    hv.w += fmaxf(fmaf(xv.w, sc.w, sh.w), 0.f);
    *reinterpret_cast<ushort4*>(h_bf + (size_t)i * 4) =
        make_ushort4(f2bf(hv.x), f2bf(hv.y), f2bf(hv.z), f2bf(hv.w));
  }
}

// ---------------- graph segment starts ----------------
__global__ void k_gstart(const int* __restrict__ batch, int* __restrict__ gstart) {
  int g = blockIdx.x * 256 + threadIdx.x;
  if (g > NG) return;
  int lo = 0, hi = N_NODES;
  while (lo < hi) {
    int mid = (lo + hi) >> 1;
    if (batch[mid] < g) lo = mid + 1; else hi = mid;
  }
  gstart[g] = lo;
}

// ---------------- global attention pooling (bf16 h) ----------------
__global__ void k_pool(const ushort* __restrict__ hb, const float* __restrict__ gate,
                       const int* __restrict__ gstart, float* __restrict__ hg) {
  __shared__ float red[256];
  __shared__ float wbuf[256];
  int g = blockIdx.x, tid = threadIdx.x;
  int b = gstart[g], e = gstart[g + 1];
  float m = -1e30f;
  for (int r = b + tid; r < e; r += 256) m = fmaxf(m, gate[r]);
  red[tid] = m;
  __syncthreads();
  for (int o = 128; o > 0; o >>= 1) {
    if (tid < o) red[tid] = fmaxf(red[tid], red[tid + o]);
    __syncthreads();
  }
  m = red[0];
  __syncthreads();
  float s = 0.f;
  for (int r = b + tid; r < e; r += 256) s += __expf(gate[r] - m);
  red[tid] = s;
  __syncthreads();
  for (int o = 128; o > 0; o >>= 1) {
    if (tid < o) red[tid] += red[tid + o];
    __syncthreads();
  }
  float inv = 1.0f / fmaxf(red[0], 1e-16f);
  __syncthreads();
  float acc = 0.f;
  for (int cb = b; cb < e; cb += 256) {
    int r = cb + tid;
    wbuf[tid] = (r < e) ? __expf(gate[r] - m) : 0.f;
    __syncthreads();
    int n = min(256, e - cb);
    for (int j = 0; j < n; j++)
      acc = fmaf(bfu(hb[(size_t)(cb + j) * HID + tid]), wbuf[j], acc);
    __syncthreads();
  }
  hg[(size_t)g * HID + tid] = acc * inv;
}

// ---------------- MLP head ----------------
__global__ void k_mlp(const float* __restrict__ hg, const float* __restrict__ W1,
                      const float* __restrict__ b1, const float* __restrict__ lng,
                      const float* __restrict__ lnb, const float* __restrict__ W2,
                      const float* __restrict__ b2, float* __restrict__ out) {
  __shared__ float row[HID];
  __shared__ float z[HID];
  __shared__ float red[HID];
  int g = blockIdx.x, tid = threadIdx.x;
  row[tid] = hg[(size_t)g * HID + tid];
  __syncthreads();
  float acc = b1[tid];
  for (int k = 0; k < HID; k++) acc = fmaf(row[k], W1[(size_t)k * HID + tid], acc);
  red[tid] = acc;
  __syncthreads();
  for (int o = 128; o > 0; o >>= 1) {
    if (tid < o) red[tid] += red[tid + o];
    __syncthreads();
  }
  float mu = red[0] * (1.0f / HID);
  __syncthreads();
  red[tid] = acc * acc;
  __syncthreads();
  for (int o = 128; o > 0; o >>= 1) {
    if (tid < o) red[tid] += red[tid + o];
    __syncthreads();
  }
  float var = red[0] * (1.0f / HID) - mu * mu;
  float zz = (acc - mu) * rsqrtf(var + EPS) * lng[tid] + lnb[tid];
  z[tid] = fmaxf(zz, 0.f);
  __syncthreads();
  if (tid < 64) {
    float o = b2[tid];
    for (int k = 0; k < HID; k++) o = fmaf(z[k], W2[(size_t)k * 64 + tid], o);
    out[(size_t)g * 64 + tid] = o;
  }
}

// ---------------- launch ----------------
extern "C" void kernel_launch(void* const* d_in, const int* in_sizes, int n_in,
                              void* d_out, int out_size, void* d_ws, size_t ws_size,
                              hipStream_t stream) {
  const float* x     = (const float*)d_in[0];
  const float* W_emb = (const float*)d_in[1];
  const float* b_emb = (const float*)d_in[2];
  const float* W_gcn = (const float*)d_in[3];
  const float* b_gcn = (const float*)d_in[4];
  const float* W_gat = (const float*)d_in[5];
  const float* a_src = (const float*)d_in[6];
  const float* a_dst = (const float*)d_in[7];
  const float* b_gat = (const float*)d_in[8];
  const float* W_l   = (const float*)d_in[9];
  const float* b_l   = (const float*)d_in[10];
  const float* W_r   = (const float*)d_in[11];
  const float* bn_g  = (const float*)d_in[12];
  const float* bn_b  = (const float*)d_in[13];
  const float* Wg1   = (const float*)d_in[14];
  const float* bg1   = (const float*)d_in[15];
  const float* Wg2   = (const float*)d_in[16];
  const float* bg2   = (const float*)d_in[17];
  const float* Wm1   = (const float*)d_in[18];
  const float* bm1   = (const float*)d_in[19];
  const float* lnmg  = (const float*)d_in[20];
  const float* lnmb  = (const float*)d_in[21];
  const float* Wm2   = (const float*)d_in[22];
  const float* bm2   = (const float*)d_in[23];
  const float* Wv1   = (const float*)d_in[24];
  const float* bv1   = (const float*)d_in[25];
  const float* lnvg  = (const float*)d_in[26];
  const float* lnvb  = (const float*)d_in[27];
  const float* Wv2   = (const float*)d_in[28];
  const float* bv2   = (const float*)d_in[29];
  const int* ei      = (const int*)d_in[30];
  const int* batch   = (const int*)d_in[31];
  float* out = (float*)d_out;

  float* ws = (float*)d_ws;
  float* h     = ws;                          // spare region
  float* t1    = h + (size_t)N_NODES * HID;   // reused as bf16 t1b
  float* alsrc = t1 + (size_t)N_NODES * HID;  // [N][8]
  float* aldst = alsrc + N_NODES * 8;         // [N][8]
  float* dis   = aldst + N_NODES * 8;
  float* gate  = dis + N_NODES;
  float* hg    = gate + N_NODES;
  float* zbase = hg + NG * HID;
  float* bnst  = zbase;                // 3 * 512
  int* row_cnt = (int*)(zbase + 3 * 512);
  int* fill    = row_cnt + N_NODES;
  int* row_ptr = fill + N_NODES;
  int* col_src = row_ptr + N_NODES + 1;
  int* gstart  = col_src + N_EDGES;
  int* psum    = gstart + NG + 1;
  int* boff    = psum + 64;
  float* scsh  = (float*)(boff + 64);  // 3 * 512 coefficients

  ushort* t1b = (ushort*)t1;

  size_t off = (size_t)((char*)(scsh + 3 * 512) - (char*)d_ws);
  off = (off + 15) & ~(size_t)15;
  ushort* h_bf   = (ushort*)((char*)d_ws + off);
  ushort* t0_bf  = h_bf + (size_t)N_NODES * HID;
  ushort* wemb_t = t0_bf + (size_t)N_NODES * HID;
  ushort* wgcn_t = wemb_t + 128 * 256;
  ushort* wgat_t = wgcn_t + 256 * 256;
  ushort* wr_t   = wgat_t + 256 * 256;
  ushort* wl_t   = wr_t + 256 * 256;
  ushort* wg1_t  = wl_t + 256 * 256;   // 256*128

  size_t zbytes = (size_t)3 * 512 * 4 + 2 * (size_t)N_NODES * 4;
  hipMemsetAsync(zbase, 0, zbytes, stream);

  // CSR by dst (hierarchical scan + fused dis)
  k_csr_count<<<(N_EDGES + 255) / 256, 256, 0, stream>>>(ei, row_cnt);
  k_scan_part<<<SCB, 256, 0, stream>>>(row_cnt, psum);
  k_scan_top<<<1, 64, 0, stream>>>(psum, boff, row_ptr);
  k_scan_out<<<SCB, 256, 0, stream>>>(row_cnt, boff, row_ptr, dis);
  k_csr_fill<<<(N_EDGES + 255) / 256, 256, 0, stream>>>(ei, row_ptr, fill, col_src);

  // all weight transposes in one launch
  WtArgs wa;
  wa.src[0] = W_emb; wa.dst[0] = wemb_t; wa.K[0] = 128; wa.C[0] = 256; wa.off[0] = 0;
  wa.src[1] = W_gcn; wa.dst[1] = wgcn_t; wa.K[1] = 256; wa.C[1] = 256; wa.off[1] = 128;
  wa.src[2] = W_gat; wa.dst[2] = wgat_t; wa.K[2] = 256; wa.C[2] = 256; wa.off[2] = 384;
  wa.src[3] = W_r;   wa.dst[3] = wr_t;   wa.K[3] = 256; wa.C[3] = 256; wa.off[3] = 640;
  wa.src[4] = W_l;   wa.dst[4] = wl_t;   wa.K[4] = 256; wa.C[4] = 256; wa.off[4] = 896;
  wa.src[5] = Wg1;   wa.dst[5] = wg1_t;  wa.K[5] = 256; wa.C[5] = 128; wa.off[5] = 1152;
  k_wt_all<<<1280, 256, 0, stream>>>(wa);

  const int RB = (N_NODES + 127) / 128;  // 391 gemm blocks (512 thr)
  const int AB = (N_NODES + 3) / 4;      // 12500 agg blocks

  // embedding: h_bf = x @ W_emb + b_emb  (fp32 A converted on load)
  k_mgemm<128, 256, false, true, false, false><<<RB, 512, 0, stream>>>(
      x, wemb_t, nullptr, nullptr, b_emb, h_bf, nullptr, nullptr, nullptr,
      nullptr, nullptr, nullptr, nullptr, N_NODES, 0);

  // --- GCN ---
  k_mgemm<256, 256, false, false, false, false><<<RB, 512, 0, stream>>>(
      h_bf, wgcn_t, nullptr, nullptr, nullptr, t0_bf, nullptr, nullptr, nullptr,
      nullptr, nullptr, nullptr, nullptr, N_NODES, 0);
  k_gcn_agg<<<AB, 256, 0, stream>>>(t0_bf, dis, row_ptr, col_src, b_gcn, t1b);
  k_bn_stats<<<1024, 256, 0, stream>>>(t1b, bnst);
  k_bn_coef<<<1, 256, 0, stream>>>(bnst, bn_g, bn_b, scsh);
  k_bn_apply<<<1024, 256, 0, stream>>>(t1b, scsh, h_bf);

  // --- GAT (al fused into GEMM epilogue; single-pass softmax in agg) ---
  k_mgemm<256, 256, false, false, false, true><<<RB, 512, 0, stream>>>(
      h_bf, wgat_t, nullptr, nullptr, nullptr, t0_bf, nullptr, nullptr, nullptr,
      a_src, a_dst, alsrc, aldst, N_NODES, 0);
  k_gat_agg<<<AB, 256, 0, stream>>>(t0_bf, alsrc, aldst, row_ptr, col_src, b_gat, t1b);
  k_bn_stats<<<1024, 256, 0, stream>>>(t1b, bnst + 512);
  k_bn_coef<<<1, 256, 0, stream>>>(bnst + 512, bn_g + HID, bn_b + HID, scsh + 512);
  k_bn_apply<<<1024, 256, 0, stream>>>(t1b, scsh + 512, h_bf);

  // --- SAGE: t1b = h@W_r + b_l + mean@W_l (dual, double-buffered) ---
  k_sage_agg<<<AB, 256, 0, stream>>>(h_bf, row_ptr, col_src, t0_bf);
  k_mgemm<256, 256, true, false, false, false><<<RB, 512, 0, stream>>>(
      h_bf, wr_t, t0_bf, wl_t, b_l, t1b, nullptr, nullptr, nullptr,
      nullptr, nullptr, nullptr, nullptr, N_NODES, 0);
  k_bn_stats<<<1024, 256, 0, stream>>>(t1b, bnst + 1024);
  k_bn_coef<<<1, 256, 0, stream>>>(bnst + 1024, bn_g + 2 * HID, bn_b + 2 * HID, scsh + 1024);
  k_bn_apply<<<1024, 256, 0, stream>>>(t1b, scsh + 1024, h_bf);

  // --- gate (fully fused GEMM epilogue) + pooling ---
  k_mgemm<256, 128, false, false, true, false><<<RB, 512, 0, stream>>>(
      h_bf, wg1_t, nullptr, nullptr, bg1, nullptr, Wg2, bg2, gate,
      nullptr, nullptr, nullptr, nullptr, N_NODES, 1);
  k_gstart<<<3, 256, 0, stream>>>(batch, gstart);
  k_pool<<<NG, 256, 0, stream>>>(h_bf, gate, gstart, hg);

  // --- heads ---
  k_mlp<<<NG, 256, 0, stream>>>(hg, Wm1, bm1, lnmg, lnmb, Wm2, bm2, out);
  k_mlp<<<NG, 256, 0, stream>>>(hg, Wv1, bv1, lnvg, lnvb, Wv2, bv2, out + (size_t)NG * 64);
}

// Round 16
// 545.189 us; speedup vs baseline: 1.0350x; 1.0172x over previous
//
#include <hip/hip_runtime.h>
#include <cstdint>
#include <cstddef>

#define N_NODES 50000
#define N_EDGES 500000
#define NG 512
#define HID 256
#define EPS 1e-5f
#define SCB 49  // scan blocks: ceil(50000/1024)

typedef __attribute__((ext_vector_type(8))) __bf16 bf16x8;
typedef __attribute__((ext_vector_type(8))) ushort u16x8;
typedef __attribute__((ext_vector_type(4))) float f32x4;

__device__ __forceinline__ ushort f2bf(float f) {
  uint32_t u = __float_as_uint(f);
  uint32_t r = (u + 0x7fffu + ((u >> 16) & 1u)) >> 16;
  return (ushort)r;
}
__device__ __forceinline__ float bfu(ushort u) { return __uint_as_float(((uint32_t)u) << 16); }
__device__ __forceinline__ float4 bf4(ushort4 u) {
  return make_float4(bfu(u.x), bfu(u.y), bfu(u.z), bfu(u.w));
}

// ---------------- CSR build ----------------
__global__ void k_csr_count(const int* __restrict__ ei, int* __restrict__ cnt) {
  int e = blockIdx.x * 256 + threadIdx.x;
  if (e < N_EDGES) atomicAdd(&cnt[ei[N_EDGES + e]], 1);
}

__global__ void k_scan_part(const int* __restrict__ cnt, int* __restrict__ psum) {
  __shared__ int red[256];
  int tid = threadIdx.x;
  int i0 = blockIdx.x * 1024 + tid * 4;
  int s = 0;
  if (i0 + 4 <= N_NODES) {
    int4 v = *reinterpret_cast<const int4*>(cnt + i0);
    s = v.x + v.y + v.z + v.w;
  } else {
    for (int k = 0; k < 4; k++)
      if (i0 + k < N_NODES) s += cnt[i0 + k];
  }
  red[tid] = s;
  __syncthreads();
  for (int o = 128; o > 0; o >>= 1) {
    if (tid < o) red[tid] += red[tid + o];
    __syncthreads();
  }
  if (tid == 0) psum[blockIdx.x] = red[0];
}

__global__ void k_scan_top(const int* __restrict__ psum, int* __restrict__ boff,
                           int* __restrict__ row_ptr) {
  int t = threadIdx.x;  // 64
  int v = (t < SCB) ? psum[t] : 0;
  int own = v;
  for (int o = 1; o < 64; o <<= 1) {
    int u = __shfl_up(v, o);
    if (t >= o) v += u;
  }
  if (t < SCB) boff[t] = v - own;
  if (t == 63) row_ptr[N_NODES] = v;
}

__global__ void k_scan_out(const int* __restrict__ cnt, const int* __restrict__ boff,
                           int* __restrict__ row_ptr, float* __restrict__ dis) {
  __shared__ int ps[256];
  int tid = threadIdx.x;
  int i0 = blockIdx.x * 1024 + tid * 4;
  int v[4];
#pragma unroll
  for (int k = 0; k < 4; k++) v[k] = (i0 + k < N_NODES) ? cnt[i0 + k] : 0;
  int s = v[0] + v[1] + v[2] + v[3];
  ps[tid] = s;
  __syncthreads();
  for (int o = 1; o < 256; o <<= 1) {
    int add = (tid >= o) ? ps[tid - o] : 0;
    __syncthreads();
    ps[tid] += add;
    __syncthreads();
  }
  int run = boff[blockIdx.x] + ((tid > 0) ? ps[tid - 1] : 0);
#pragma unroll
  for (int k = 0; k < 4; k++) {
    if (i0 + k < N_NODES) {
      row_ptr[i0 + k] = run;
      dis[i0 + k] = rsqrtf((float)v[k] + 1.0f);
      run += v[k];
    }
  }
}

__global__ void k_csr_fill(const int* __restrict__ ei, const int* __restrict__ row_ptr,
                           int* __restrict__ fill, int* __restrict__ col_src) {
  int e = blockIdx.x * 256 + threadIdx.x;
  if (e >= N_EDGES) return;
  int s = ei[e], d = ei[N_EDGES + e];
  int pos = row_ptr[d] + atomicAdd(&fill[d], 1);
  col_src[pos] = s;
}

// ---------------- batched weight transpose: W[K,C] fp32 -> Wt[C,K] bf16 ----------------
struct WtArgs {
  const float* src[6];
  ushort* dst[6];
  int K[6];
  int C[6];
  int off[6];
};

__global__ void k_wt_all(WtArgs a) {
  int b = blockIdx.x;
  int ji = 0;
#pragma unroll
  for (int t = 1; t < 6; t++)
    if (b >= a.off[t]) ji = t;
  int K = a.K[ji], C = a.C[ji];
  int i = (b - a.off[ji]) * 256 + threadIdx.x;
  int c = i / K, k = i - c * K;
  a.dst[ji][i] = f2bf(a.src[ji][k * C + c]);
}

// ---------------- MFMA GEMM: 64-row blocks, K-split dbuf panels, column-split grid ----------
// out_bf[M,C] = A1@W1t^T (+A2@W2t^T) + bias. Wt [C,K] bf16. Grid: (ceil(M/64), CSPLIT).
// Sub-step = (panel, pass, k-half); 16KB half-panels double-buffered (32KB LDS) -> high
// residency (5 blocks/CU). Each y-block handles NPAN/CSPLIT panels (A re-read per split).
// GATE: fused gate head via atomicAdd (gate zeroed). GATAL: fused attention logits
// -> als/ald[node][head] (y-blocks own disjoint heads).
template <int K, int C, int CSPLIT, bool DUAL, bool AFP32, bool GATE, bool GATAL>
__global__ __launch_bounds__(256) void k_mgemm(
    const void* __restrict__ A1v, const ushort* __restrict__ W1t,
    const ushort* __restrict__ A2, const ushort* __restrict__ W2t,
    const float* __restrict__ bias, ushort* __restrict__ out_bf,
    const float* __restrict__ gw, const float* __restrict__ gb,
    float* __restrict__ gate, const float* __restrict__ asv,
    const float* __restrict__ adv, float* __restrict__ als,
    float* __restrict__ ald, int M, int relu) {
  constexpr int KS = K / 32;             // MFMA k-steps total
  constexpr int KSH = KS / 2;            // k-steps per half
  constexpr int KHALF = K / 2;
  constexpr int CHKH = KHALF / 8;        // 16B chunks per col per half
  constexpr int NPAN = C / 64;
  constexpr int NPANL = NPAN / CSPLIT;   // panels per y-block
  constexpr int LOWB = DUAL ? 4 : 2;     // sub-steps per panel
  constexpr int NTOT = NPANL * LOWB;
  constexpr int NISS = (64 * CHKH) / 256;
  constexpr int PELEM = 64 * KHALF;      // ushorts per half-panel buffer
  __shared__ ushort wlds[2 * PELEM];
  const int tid = threadIdx.x;
  const int lane = tid & 63;
  const int wid = tid >> 6;
  const int r16 = lane & 15;
  const int kg = lane >> 4;
  const int rbase = blockIdx.x * 64 + wid * 16;
  const int pbase = blockIdx.y * NPANL;

  int arow = rbase + r16;
  if (arow >= M) arow = M - 1;

  // A fragments, loaded once
  bf16x8 af[KS], af2[KS];
  if constexpr (AFP32) {
    const float* ap = (const float*)A1v + (size_t)arow * K + kg * 8;
#pragma unroll
    for (int ks = 0; ks < KS; ks++) {
      float4 lo = *reinterpret_cast<const float4*>(ap + ks * 32);
      float4 hi = *reinterpret_cast<const float4*>(ap + ks * 32 + 4);
      union { u16x8 u; bf16x8 b; } cv;
      cv.u = (u16x8){f2bf(lo.x), f2bf(lo.y), f2bf(lo.z), f2bf(lo.w),
                     f2bf(hi.x), f2bf(hi.y), f2bf(hi.z), f2bf(hi.w)};
      af[ks] = cv.b;
    }
  } else {
    const ushort* ap = (const ushort*)A1v + (size_t)arow * K + kg * 8;
#pragma unroll
    for (int ks = 0; ks < KS; ks++)
      af[ks] = *reinterpret_cast<const bf16x8*>(ap + ks * 32);
  }
  if constexpr (DUAL) {
    const ushort* ap = A2 + (size_t)arow * K + kg * 8;
#pragma unroll
    for (int ks = 0; ks < KS; ks++)
      af2[ks] = *reinterpret_cast<const bf16x8*>(ap + ks * 32);
  }

  float greg[4] = {0.f, 0.f, 0.f, 0.f};
  f32x4 acc[4];

  // async stage of one K-half panel; linear LDS chunk p = c*CHKH + jj holds
  // W[c, kh*KHALF + (jj^(c&7))*8 ..]; read-side swizzle matches.
#define STAGE_ASYNC(WSRC, PAN, KH, BUF)                                        \
  {                                                                            \
    const ushort* base_ = (WSRC) + (size_t)((PAN) * 64) * K + (KH) * KHALF;    \
    _Pragma("unroll") for (int j = 0; j < NISS; j++) {                         \
      int p_ = j * 256 + tid;                                                  \
      int c_ = p_ / CHKH, jj_ = p_ % CHKH;                                     \
      const ushort* g_ = base_ + c_ * K + (jj_ ^ (c_ & 7)) * 8;                \
      ushort* l_ = &wlds[(BUF) * PELEM + (j * 256 + wid * 64) * 8];            \
      __builtin_amdgcn_global_load_lds(                                        \
          (const __attribute__((address_space(1))) void*)(g_),                 \
          (__attribute__((address_space(3))) void*)(l_), 16, 0, 0);            \
    }                                                                          \
  }

#define COMPUTE(AF, KH, BUF)                                                   \
  {                                                                            \
    const ushort* wb_ = &wlds[(BUF) * PELEM];                                  \
    _Pragma("unroll") for (int ct = 0; ct < 4; ct++) {                         \
      bf16x8 wf[KSH];                                                          \
      int colr = ct * 16 + r16;                                                \
      _Pragma("unroll") for (int ksl = 0; ksl < KSH; ksl++) {                  \
        int slot = colr * CHKH + ((ksl * 4 + kg) ^ (r16 & 7));                 \
        wf[ksl] = *reinterpret_cast<const bf16x8*>(&wb_[slot * 8]);            \
      }                                                                        \
      _Pragma("unroll") for (int ksl = 0; ksl < KSH; ksl++)                    \
        acc[ct] = __builtin_amdgcn_mfma_f32_16x16x32_bf16(                     \
            (AF)[(KH) * KSH + ksl], wf[ksl], acc[ct], 0, 0, 0);                \
    }                                                                          \
  }

  // prologue: stage sub-step 0 into buffer 0
  STAGE_ASYNC(W1t, pbase, 0, 0);
  __syncthreads();

#pragma unroll
  for (int q = 0; q < NTOT; q++) {
    const int kh = q & 1;
    const int pass = DUAL ? ((q >> 1) & 1) : 0;
    const int pan = pbase + (DUAL ? (q >> 2) : (q >> 1));
    const int bufq = q & 1;
    const int c0 = pan * 64;
    if ((q & (LOWB - 1)) == 0) {
#pragma unroll
      for (int ct = 0; ct < 4; ct++) acc[ct] = (f32x4){0.f, 0.f, 0.f, 0.f};
    }
    if (q + 1 < NTOT) {
      const int nkh = (q + 1) & 1;
      const int npass = DUAL ? (((q + 1) >> 1) & 1) : 0;
      const int npan = pbase + (DUAL ? ((q + 1) >> 2) : ((q + 1) >> 1));
      const ushort* Wq = (DUAL && npass) ? W2t : W1t;
      STAGE_ASYNC(Wq, npan, nkh, bufq ^ 1);
    }
    if (DUAL && pass) {
      COMPUTE(af2, kh, bufq);
    } else {
      COMPUTE(af, kh, bufq);
    }
    if ((q & (LOWB - 1)) == (LOWB - 1)) {
      if constexpr (GATE) {
#pragma unroll
        for (int ct = 0; ct < 4; ct++) {
          int col = c0 + ct * 16 + r16;
          float bv = bias[col];
          float wv = gw[col];
#pragma unroll
          for (int i = 0; i < 4; i++) {
            float v = fmaxf(acc[ct][i] + bv, 0.f);
            greg[i] = fmaf(v, wv, greg[i]);
          }
        }
      } else {
#pragma unroll
        for (int ct = 0; ct < 4; ct++) {
          int col = c0 + ct * 16 + r16;
          float bv = bias ? bias[col] : 0.f;
#pragma unroll
          for (int i = 0; i < 4; i++) {
            int row = rbase + kg * 4 + i;
            if (row < M) {
              float v = acc[ct][i] + bv;
              if (relu) v = fmaxf(v, 0.f);
              out_bf[(size_t)row * C + col] = f2bf(v);
            }
          }
        }
      }
      if constexpr (GATAL) {
        float ps_[2][4], pd_[2][4];
#pragma unroll
        for (int h2 = 0; h2 < 2; h2++)
#pragma unroll
          for (int i = 0; i < 4; i++) { ps_[h2][i] = 0.f; pd_[h2][i] = 0.f; }
#pragma unroll
        for (int ct = 0; ct < 4; ct++) {
          int col = c0 + ct * 16 + r16;
          float as_ = asv[col], ad_ = adv[col];
          int h2 = ct >> 1;
#pragma unroll
          for (int i = 0; i < 4; i++) {
            ps_[h2][i] = fmaf(acc[ct][i], as_, ps_[h2][i]);
            pd_[h2][i] = fmaf(acc[ct][i], ad_, pd_[h2][i]);
          }
        }
#pragma unroll
        for (int h2 = 0; h2 < 2; h2++)
#pragma unroll
          for (int i = 0; i < 4; i++) {
#pragma unroll
            for (int o = 1; o < 16; o <<= 1) {
              ps_[h2][i] += __shfl_xor(ps_[h2][i], o);
              pd_[h2][i] += __shfl_xor(pd_[h2][i], o);
            }
          }
        if (r16 == 0) {
#pragma unroll
          for (int i = 0; i < 4; i++) {
            int row = rbase + kg * 4 + i;
            if (row < M) {
              als[row * 8 + pan * 2 + 0] = ps_[0][i];
              ald[row * 8 + pan * 2 + 0] = pd_[0][i];
              als[row * 8 + pan * 2 + 1] = ps_[1][i];
              ald[row * 8 + pan * 2 + 1] = pd_[1][i];
            }
          }
        }
      }
    }
    __syncthreads();
  }

  if constexpr (GATE) {
#pragma unroll
    for (int i = 0; i < 4; i++) {
#pragma unroll
      for (int o = 1; o < 16; o <<= 1) greg[i] += __shfl_xor(greg[i], o);
    }
    if (r16 == 0) {
      float b0 = (blockIdx.y == 0) ? gb[0] : 0.f;
#pragma unroll
      for (int i = 0; i < 4; i++) {
        int row = rbase + kg * 4 + i;
        if (row < M) atomicAdd(&gate[row], greg[i] + b0);
      }
    }
  }
#undef STAGE_ASYNC
#undef COMPUTE
}

// ---------------- GCN aggregation: wave/node, 32 lanes/row, 8-edge ILP, bf16 out ------------
__global__ void k_gcn_agg(const ushort* __restrict__ xt, const float* __restrict__ dis,
                          const int* __restrict__ row_ptr, const int* __restrict__ col_src,
                          const float* __restrict__ b_gcn, ushort* __restrict__ outb) {
  int node = blockIdx.x * 4 + (threadIdx.x >> 6);
  if (node >= N_NODES) return;
  int lane = threadIdx.x & 63;
  int half = lane >> 5;
  int c0 = (lane & 31) * 8;
  float di = dis[node];
  float acc[8];
#pragma unroll
  for (int j = 0; j < 8; j++) acc[j] = 0.f;
  int b = row_ptr[node], e = row_ptr[node + 1];
  int g0 = b;
  for (; g0 + 8 <= e; g0 += 8) {
    int i0 = g0 + half * 4;
    int s0 = col_src[i0], s1 = col_src[i0 + 1], s2 = col_src[i0 + 2], s3 = col_src[i0 + 3];
    float w0 = di * dis[s0], w1 = di * dis[s1], w2 = di * dis[s2], w3 = di * dis[s3];
    u16x8 u0 = *reinterpret_cast<const u16x8*>(xt + (size_t)s0 * HID + c0);
    u16x8 u1 = *reinterpret_cast<const u16x8*>(xt + (size_t)s1 * HID + c0);
    u16x8 u2 = *reinterpret_cast<const u16x8*>(xt + (size_t)s2 * HID + c0);
    u16x8 u3 = *reinterpret_cast<const u16x8*>(xt + (size_t)s3 * HID + c0);
#pragma unroll
    for (int j = 0; j < 8; j++) {
      acc[j] = fmaf(bfu(u0[j]), w0, acc[j]);
      acc[j] = fmaf(bfu(u1[j]), w1, acc[j]);
      acc[j] = fmaf(bfu(u2[j]), w2, acc[j]);
      acc[j] = fmaf(bfu(u3[j]), w3, acc[j]);
    }
  }
  for (; g0 + 4 <= e; g0 += 4) {
    int i0 = g0 + half * 2;
    int s0 = col_src[i0], s1 = col_src[i0 + 1];
    float w0 = di * dis[s0], w1 = di * dis[s1];
    u16x8 u0 = *reinterpret_cast<const u16x8*>(xt + (size_t)s0 * HID + c0);
    u16x8 u1 = *reinterpret_cast<const u16x8*>(xt + (size_t)s1 * HID + c0);
#pragma unroll
    for (int j = 0; j < 8; j++) {
      acc[j] = fmaf(bfu(u0[j]), w0, acc[j]);
      acc[j] = fmaf(bfu(u1[j]), w1, acc[j]);
    }
  }
  {  // tail (0..3 edges), guarded
    int i0 = g0 + half * 2;
    int s0 = 0, s1 = 0;
    float w0 = 0.f, w1 = 0.f;
    if (i0 < e) { s0 = col_src[i0]; w0 = di * dis[s0]; }
    if (i0 + 1 < e) { s1 = col_src[i0 + 1]; w1 = di * dis[s1]; }
    u16x8 u0 = *reinterpret_cast<const u16x8*>(xt + (size_t)s0 * HID + c0);
    u16x8 u1 = *reinterpret_cast<const u16x8*>(xt + (size_t)s1 * HID + c0);
#pragma unroll
    for (int j = 0; j < 8; j++) {
      acc[j] = fmaf(bfu(u0[j]), w0, acc[j]);
      acc[j] = fmaf(bfu(u1[j]), w1, acc[j]);
    }
  }
#pragma unroll
  for (int j = 0; j < 8; j++) acc[j] += __shfl_xor(acc[j], 32);
  if (!half) {
    u16x8 un = *reinterpret_cast<const u16x8*>(xt + (size_t)node * HID + c0);
    float w0 = di * di;
    u16x8 r;
#pragma unroll
    for (int j = 0; j < 8; j++) {
      float v = fmaf(bfu(un[j]), w0, acc[j]) + b_gcn[c0 + j];
      r[j] = f2bf(v);
    }
    *reinterpret_cast<u16x8*>(outb + (size_t)node * HID + c0) = r;
  }
}

__device__ __forceinline__ float leaky02(float x) { return x > 0.f ? x : 0.2f * x; }

// ---------------- Single-pass GAT agg, 32 lanes/row, 8-edge ILP; al in [node][head] ---------
__global__ void k_gat_agg(const ushort* __restrict__ xt, const float* __restrict__ alsrc,
                          const float* __restrict__ aldst, const int* __restrict__ row_ptr,
                          const int* __restrict__ col_src, const float* __restrict__ b_gat,
                          ushort* __restrict__ outb) {
  int node = blockIdx.x * 4 + (threadIdx.x >> 6);
  if (node >= N_NODES) return;
  int lane = threadIdx.x & 63;
  int half = lane >> 5;
  int l32 = lane & 31;
  int c0 = l32 * 8;
  int hh = l32 >> 2;
  float ad = aldst[node * 8 + hh];
  float acc[8];
#pragma unroll
  for (int j = 0; j < 8; j++) acc[j] = 0.f;
  float s = 0.f;
  int b = row_ptr[node], e = row_ptr[node + 1];
  int g0 = b;
  for (; g0 + 8 <= e; g0 += 8) {
    int i0 = g0 + half * 4;
    int s0 = col_src[i0], s1 = col_src[i0 + 1], s2 = col_src[i0 + 2], s3 = col_src[i0 + 3];
    float g0v = alsrc[s0 * 8 + hh], g1v = alsrc[s1 * 8 + hh];
    float g2v = alsrc[s2 * 8 + hh], g3v = alsrc[s3 * 8 + hh];
    u16x8 u0 = *reinterpret_cast<const u16x8*>(xt + (size_t)s0 * HID + c0);
    u16x8 u1 = *reinterpret_cast<const u16x8*>(xt + (size_t)s1 * HID + c0);
    u16x8 u2 = *reinterpret_cast<const u16x8*>(xt + (size_t)s2 * HID + c0);
    u16x8 u3 = *reinterpret_cast<const u16x8*>(xt + (size_t)s3 * HID + c0);
    float a0 = __expf(leaky02(g0v + ad));
    float a1 = __expf(leaky02(g1v + ad));
    float a2 = __expf(leaky02(g2v + ad));
    float a3 = __expf(leaky02(g3v + ad));
    s += a0 + a1 + a2 + a3;
#pragma unroll
    for (int j = 0; j < 8; j++) {
      acc[j] = fmaf(bfu(u0[j]), a0, acc[j]);
      acc[j] = fmaf(bfu(u1[j]), a1, acc[j]);
      acc[j] = fmaf(bfu(u2[j]), a2, acc[j]);
      acc[j] = fmaf(bfu(u3[j]), a3, acc[j]);
    }
  }
  for (; g0 + 4 <= e; g0 += 4) {
    int i0 = g0 + half * 2;
    int s0 = col_src[i0], s1 = col_src[i0 + 1];
    float a0 = __expf(leaky02(alsrc[s0 * 8 + hh] + ad));
    float a1 = __expf(leaky02(alsrc[s1 * 8 + hh] + ad));
    u16x8 u0 = *reinterpret_cast<const u16x8*>(xt + (size_t)s0 * HID + c0);
    u16x8 u1 = *reinterpret_cast<const u16x8*>(xt + (size_t)s1 * HID + c0);
    s += a0 + a1;
#pragma unroll
    for (int j = 0; j < 8; j++) {
      acc[j] = fmaf(bfu(u0[j]), a0, acc[j]);
      acc[j] = fmaf(bfu(u1[j]), a1, acc[j]);
    }
  }
  {  // tail, guarded
    int i0 = g0 + half * 2;
    int s0 = 0, s1 = 0;
    float a0 = 0.f, a1 = 0.f;
    if (i0 < e) { s0 = col_src[i0]; a0 = __expf(leaky02(alsrc[s0 * 8 + hh] + ad)); }
    if (i0 + 1 < e) { s1 = col_src[i0 + 1]; a1 = __expf(leaky02(alsrc[s1 * 8 + hh] + ad)); }
    u16x8 u0 = *reinterpret_cast<const u16x8*>(xt + (size_t)s0 * HID + c0);
    u16x8 u1 = *reinterpret_cast<const u16x8*>(xt + (size_t)s1 * HID + c0);
    s += a0 + a1;
#pragma unroll
    for (int j = 0; j < 8; j++) {
      acc[j] = fmaf(bfu(u0[j]), a0, acc[j]);
      acc[j] = fmaf(bfu(u1[j]), a1, acc[j]);
    }
  }
#pragma unroll
  for (int j = 0; j < 8; j++) acc[j] += __shfl_xor(acc[j], 32);
  s += __shfl_xor(s, 32);
  if (!half) {
    float e0 = __expf(leaky02(alsrc[node * 8 + hh] + ad));
    u16x8 un = *reinterpret_cast<const u16x8*>(xt + (size_t)node * HID + c0);
    float inv_s = 1.0f / (s + e0);
    u16x8 r;
#pragma unroll
    for (int j = 0; j < 8; j++) {
      float v = fmaf(bfu(un[j]), e0, acc[j]) * inv_s + b_gat[c0 + j];
      r[j] = f2bf(v);
    }
    *reinterpret_cast<u16x8*>(outb + (size_t)node * HID + c0) = r;
  }
}

// ---------------- SAGE mean aggregation: 32 lanes/row, 8-edge ILP, bf16 in/out --------------
__global__ void k_sage_agg(const ushort* __restrict__ h, const int* __restrict__ row_ptr,
                           const int* __restrict__ col_src, ushort* __restrict__ outb) {
  int node = blockIdx.x * 4 + (threadIdx.x >> 6);
  if (node >= N_NODES) return;
  int lane = threadIdx.x & 63;
  int half = lane >> 5;
  int c0 = (lane & 31) * 8;
  float acc[8];
#pragma unroll
  for (int j = 0; j < 8; j++) acc[j] = 0.f;
  int b = row_ptr[node], e = row_ptr[node + 1];
  int g0 = b;
  for (; g0 + 8 <= e; g0 += 8) {
    int i0 = g0 + half * 4;
    int s0 = col_src[i0], s1 = col_src[i0 + 1], s2 = col_src[i0 + 2], s3 = col_src[i0 + 3];
    u16x8 u0 = *reinterpret_cast<const u16x8*>(h + (size_t)s0 * HID + c0);
    u16x8 u1 = *reinterpret_cast<const u16x8*>(h + (size_t)s1 * HID + c0);
    u16x8 u2 = *reinterpret_cast<const u16x8*>(h + (size_t)s2 * HID + c0);
    u16x8 u3 = *reinterpret_cast<const u16x8*>(h + (size_t)s3 * HID + c0);
#pragma unroll
    for (int j = 0; j < 8; j++)
      acc[j] += (bfu(u0[j]) + bfu(u1[j])) + (bfu(u2[j]) + bfu(u3[j]));
  }
  for (; g0 + 4 <= e; g0 += 4) {
    int i0 = g0 + half * 2;
    int s0 = col_src[i0], s1 = col_src[i0 + 1];
    u16x8 u0 = *reinterpret_cast<const u16x8*>(h + (size_t)s0 * HID + c0);
    u16x8 u1 = *reinterpret_cast<const u16x8*>(h + (size_t)s1 * HID + c0);
#pragma unroll
    for (int j = 0; j < 8; j++) acc[j] += bfu(u0[j]) + bfu(u1[j]);
  }
  {
    int i0 = g0 + half * 2;
    int s0 = 0, s1 = 0;
    float w0 = 0.f, w1 = 0.f;
    if (i0 < e) { s0 = col_src[i0]; w0 = 1.f; }
    if (i0 + 1 < e) { s1 = col_src[i0 + 1]; w1 = 1.f; }
    u16x8 u0 = *reinterpret_cast<const u16x8*>(h + (size_t)s0 * HID + c0);
    u16x8 u1 = *reinterpret_cast<const u16x8*>(h + (size_t)s1 * HID + c0);
#pragma unroll
    for (int j = 0; j < 8; j++) {
      acc[j] = fmaf(bfu(u0[j]), w0, acc[j]);
      acc[j] = fmaf(bfu(u1[j]), w1, acc[j]);
    }
  }
#pragma unroll
  for (int j = 0; j < 8; j++) acc[j] += __shfl_xor(acc[j], 32);
  if (!half) {
    float inv = 1.0f / fmaxf((float)(e - b), 1.0f);
    u16x8 r;
#pragma unroll
    for (int j = 0; j < 8; j++) r[j] = f2bf(acc[j] * inv);
    *reinterpret_cast<u16x8*>(outb + (size_t)node * HID + c0) = r;
  }
}

// ---------------- BatchNorm stats: vectorized 16B loads, LDS reduce, 1024 blocks ------------
__global__ __launch_bounds__(256) void k_bn_stats(const ushort* __restrict__ x,
                                                  float* __restrict__ stats) {
  int tid = threadIdx.x;
  int cg = tid & 31;
  int rs = tid >> 5;
  int c0 = cg * 8;
  float s[8], q[8];
#pragma unroll
  for (int j = 0; j < 8; j++) { s[j] = 0.f; q[j] = 0.f; }
  for (int r = blockIdx.x * 8 + rs; r < N_NODES; r += gridDim.x * 8) {
    u16x8 v = *reinterpret_cast<const u16x8*>(x + (size_t)r * HID + c0);
#pragma unroll
    for (int j = 0; j < 8; j++) {
      float f = bfu(v[j]);
      s[j] += f;
      q[j] = fmaf(f, f, q[j]);
    }
  }
  __shared__ float ls[512];
  ls[tid] = 0.f;
  ls[tid + 256] = 0.f;
  __syncthreads();
#pragma unroll
  for (int j = 0; j < 8; j++) {
    atomicAdd(&ls[c0 + j], s[j]);
    atomicAdd(&ls[256 + c0 + j], q[j]);
  }
  __syncthreads();
  atomicAdd(&stats[tid], ls[tid]);
  atomicAdd(&stats[tid + 256], ls[tid + 256]);
}

// h_bf += relu(bn(x)); per-thread column coefs computed once (i&63 is thread-invariant)
__global__ void k_bn_apply(const ushort* __restrict__ x, const float* __restrict__ stats,
                           const float* __restrict__ gamma, const float* __restrict__ beta,
                           ushort* __restrict__ h_bf) {
  int tid = threadIdx.x;
  int c4 = (tid & 63) * 4;
  const float invN = 1.0f / (float)N_NODES;
  float sc[4], sh[4];
#pragma unroll
  for (int j = 0; j < 4; j++) {
    int c = c4 + j;
    float mu = stats[c] * invN;
    float var = stats[256 + c] * invN - mu * mu;
    float s = gamma[c] * rsqrtf(var + EPS);
    sc[j] = s;
    sh[j] = beta[c] - mu * s;
  }
  int total = N_NODES * 64;
  for (int i = blockIdx.x * 256 + tid; i < total; i += gridDim.x * 256) {
    float4 xv = bf4(*reinterpret_cast<const ushort4*>(x + (size_t)i * 4));
    float4 hv = bf4(*reinterpret_cast<const ushort4*>(h_bf + (size_t)i * 4));
    hv.x += fmaxf(fmaf(xv.x, sc[0], sh[0]), 0.f);
    hv.y += fmaxf(fmaf(xv.y, sc[1], sh[1]), 0.f);
    hv.z += fmaxf(fmaf(xv.z, sc[2], sh[2]), 0.f);
    hv.w += fmaxf(fmaf(xv.w, sc[3], sh[3]), 0.f);
    *reinterpret_cast<ushort4*>(h_bf + (size_t)i * 4) =
        make_ushort4(f2bf(hv.x), f2bf(hv.y), f2bf(hv.z), f2bf(hv.w));
  }
}

// ---------------- global attention pooling (bf16 h, inline segment search) ----------------
__global__ void k_pool(const ushort* __restrict__ hb, const float* __restrict__ gate,
                       const int* __restrict__ batch, float* __restrict__ hg) {
  __shared__ float red[256];
  __shared__ float wbuf[256];
  __shared__ int seg[2];
  int g = blockIdx.x, tid = threadIdx.x;
  if (tid < 2) {
    int target = g + tid;
    int lo = 0, hi = N_NODES;
    while (lo < hi) {
      int mid = (lo + hi) >> 1;
      if (batch[mid] < target) lo = mid + 1; else hi = mid;
    }
    seg[tid] = lo;
  }
  __syncthreads();
  int b = seg[0], e = seg[1];
  float m = -1e30f;
  for (int r = b + tid; r < e; r += 256) m = fmaxf(m, gate[r]);
  red[tid] = m;
  __syncthreads();
  for (int o = 128; o > 0; o >>= 1) {
    if (tid < o) red[tid] = fmaxf(red[tid], red[tid + o]);
    __syncthreads();
  }
  m = red[0];
  __syncthreads();
  float s = 0.f;
  for (int r = b + tid; r < e; r += 256) s += __expf(gate[r] - m);
  red[tid] = s;
  __syncthreads();
  for (int o = 128; o > 0; o >>= 1) {
    if (tid < o) red[tid] += red[tid + o];
    __syncthreads();
  }
  float inv = 1.0f / fmaxf(red[0], 1e-16f);
  __syncthreads();
  float acc = 0.f;
  for (int cb = b; cb < e; cb += 256) {
    int r = cb + tid;
    wbuf[tid] = (r < e) ? __expf(gate[r] - m) : 0.f;
    __syncthreads();
    int n = min(256, e - cb);
    for (int j = 0; j < n; j++)
      acc = fmaf(bfu(hb[(size_t)(cb + j) * HID + tid]), wbuf[j], acc);
    __syncthreads();
  }
  hg[(size_t)g * HID + tid] = acc * inv;
}

// ---------------- MLP head ----------------
__global__ void k_mlp(const float* __restrict__ hg, const float* __restrict__ W1,
                      const float* __restrict__ b1, const float* __restrict__ lng,
                      const float* __restrict__ lnb, const float* __restrict__ W2,
                      const float* __restrict__ b2, float* __restrict__ out) {
  __shared__ float row[HID];
  __shared__ float z[HID];
  __shared__ float red[HID];
  int g = blockIdx.x, tid = threadIdx.x;
  row[tid] = hg[(size_t)g * HID + tid];
  __syncthreads();
  float acc = b1[tid];
  for (int k = 0; k < HID; k++) acc = fmaf(row[k], W1[(size_t)k * HID + tid], acc);
  red[tid] = acc;
  __syncthreads();
  for (int o = 128; o > 0; o >>= 1) {
    if (tid < o) red[tid] += red[tid + o];
    __syncthreads();
  }
  float mu = red[0] * (1.0f / HID);
  __syncthreads();
  red[tid] = acc * acc;
  __syncthreads();
  for (int o = 128; o > 0; o >>= 1) {
    if (tid < o) red[tid] += red[tid + o];
    __syncthreads();
  }
  float var = red[0] * (1.0f / HID) - mu * mu;
  float zz = (acc - mu) * rsqrtf(var + EPS) * lng[tid] + lnb[tid];
  z[tid] = fmaxf(zz, 0.f);
  __syncthreads();
  if (tid < 64) {
    float o = b2[tid];
    for (int k = 0; k < HID; k++) o = fmaf(z[k], W2[(size_t)k * 64 + tid], o);
    out[(size_t)g * 64 + tid] = o;
  }
}

// ---------------- launch ----------------
extern "C" void kernel_launch(void* const* d_in, const int* in_sizes, int n_in,
                              void* d_out, int out_size, void* d_ws, size_t ws_size,
                              hipStream_t stream) {
  const float* x     = (const float*)d_in[0];
  const float* W_emb = (const float*)d_in[1];
  const float* b_emb = (const float*)d_in[2];
  const float* W_gcn = (const float*)d_in[3];
  const float* b_gcn = (const float*)d_in[4];
  const float* W_gat = (const float*)d_in[5];
  const float* a_src = (const float*)d_in[6];
  const float* a_dst = (const float*)d_in[7];
  const float* b_gat = (const float*)d_in[8];
  const float* W_l   = (const float*)d_in[9];
  const float* b_l   = (const float*)d_in[10];
  const float* W_r   = (const float*)d_in[11];
  const float* bn_g  = (const float*)d_in[12];
  const float* bn_b  = (const float*)d_in[13];
  const float* Wg1   = (const float*)d_in[14];
  const float* bg1   = (const float*)d_in[15];
  const float* Wg2   = (const float*)d_in[16];
  const float* bg2   = (const float*)d_in[17];
  const float* Wm1   = (const float*)d_in[18];
  const float* bm1   = (const float*)d_in[19];
  const float* lnmg  = (const float*)d_in[20];
  const float* lnmb  = (const float*)d_in[21];
  const float* Wm2   = (const float*)d_in[22];
  const float* bm2   = (const float*)d_in[23];
  const float* Wv1   = (const float*)d_in[24];
  const float* bv1   = (const float*)d_in[25];
  const float* lnvg  = (const float*)d_in[26];
  const float* lnvb  = (const float*)d_in[27];
  const float* Wv2   = (const float*)d_in[28];
  const float* bv2   = (const float*)d_in[29];
  const int* ei      = (const int*)d_in[30];
  const int* batch   = (const int*)d_in[31];
  float* out = (float*)d_out;

  float* ws = (float*)d_ws;
  float* h     = ws;                          // spare region
  float* t1    = h + (size_t)N_NODES * HID;   // reused as bf16 t1b
  float* alsrc = t1 + (size_t)N_NODES * HID;  // [N][8]
  float* aldst = alsrc + N_NODES * 8;         // [N][8]
  float* dis   = aldst + N_NODES * 8;
  float* gate  = dis + N_NODES;
  float* hg    = gate + N_NODES;
  float* zbase = hg + NG * HID;
  float* bnst  = zbase;                // 3 * 512
  int* row_cnt = (int*)(zbase + 3 * 512);
  int* fill    = row_cnt + N_NODES;
  int* row_ptr = fill + N_NODES;
  int* col_src = row_ptr + N_NODES + 1;
  int* psum    = col_src + N_EDGES;
  int* boff    = psum + 64;

  ushort* t1b = (ushort*)t1;

  size_t off = (size_t)((char*)(boff + 64) - (char*)d_ws);
  off = (off + 15) & ~(size_t)15;
  ushort* h_bf   = (ushort*)((char*)d_ws + off);
  ushort* t0_bf  = h_bf + (size_t)N_NODES * HID;
  ushort* wemb_t = t0_bf + (size_t)N_NODES * HID;
  ushort* wgcn_t = wemb_t + 128 * 256;
  ushort* wgat_t = wgcn_t + 256 * 256;
  ushort* wr_t   = wgat_t + 256 * 256;
  ushort* wl_t   = wr_t + 256 * 256;
  ushort* wg1_t  = wl_t + 256 * 256;   // 256*128

  size_t zbytes = (size_t)3 * 512 * 4 + 2 * (size_t)N_NODES * 4;
  hipMemsetAsync(zbase, 0, zbytes, stream);

  // CSR by dst (hierarchical scan + fused dis)
  k_csr_count<<<(N_EDGES + 255) / 256, 256, 0, stream>>>(ei, row_cnt);
  k_scan_part<<<SCB, 256, 0, stream>>>(row_cnt, psum);
  k_scan_top<<<1, 64, 0, stream>>>(psum, boff, row_ptr);
  k_scan_out<<<SCB, 256, 0, stream>>>(row_cnt, boff, row_ptr, dis);
  k_csr_fill<<<(N_EDGES + 255) / 256, 256, 0, stream>>>(ei, row_ptr, fill, col_src);

  // all weight transposes in one launch
  WtArgs wa;
  wa.src[0] = W_emb; wa.dst[0] = wemb_t; wa.K[0] = 128; wa.C[0] = 256; wa.off[0] = 0;
  wa.src[1] = W_gcn; wa.dst[1] = wgcn_t; wa.K[1] = 256; wa.C[1] = 256; wa.off[1] = 128;
  wa.src[2] = W_gat; wa.dst[2] = wgat_t; wa.K[2] = 256; wa.C[2] = 256; wa.off[2] = 384;
  wa.src[3] = W_r;   wa.dst[3] = wr_t;   wa.K[3] = 256; wa.C[3] = 256; wa.off[3] = 640;
  wa.src[4] = W_l;   wa.dst[4] = wl_t;   wa.K[4] = 256; wa.C[4] = 256; wa.off[4] = 896;
  wa.src[5] = Wg1;   wa.dst[5] = wg1_t;  wa.K[5] = 256; wa.C[5] = 128; wa.off[5] = 1152;
  k_wt_all<<<1280, 256, 0, stream>>>(wa);

  const int RB = (N_NODES + 63) / 64;   // 782 gemm row-blocks (256 thr)
  const int AB = (N_NODES + 3) / 4;     // 12500 agg blocks

  // embedding: h_bf = x @ W_emb + b_emb  (fp32 A converted on load)
  k_mgemm<128, 256, 1, false, true, false, false><<<dim3(RB, 1), 256, 0, stream>>>(
      x, wemb_t, nullptr, nullptr, b_emb, h_bf, nullptr, nullptr, nullptr,
      nullptr, nullptr, nullptr, nullptr, N_NODES, 0);

  // --- GCN (column-split x2, K-split panels) ---
  k_mgemm<256, 256, 2, false, false, false, false><<<dim3(RB, 2), 256, 0, stream>>>(
      h_bf, wgcn_t, nullptr, nullptr, nullptr, t0_bf, nullptr, nullptr, nullptr,
      nullptr, nullptr, nullptr, nullptr, N_NODES, 0);
  k_gcn_agg<<<AB, 256, 0, stream>>>(t0_bf, dis, row_ptr, col_src, b_gcn, t1b);
  k_bn_stats<<<1024, 256, 0, stream>>>(t1b, bnst);
  k_bn_apply<<<1024, 256, 0, stream>>>(t1b, bnst, bn_g, bn_b, h_bf);

  // --- GAT (al fused into GEMM epilogue; single-pass softmax in agg) ---
  k_mgemm<256, 256, 2, false, false, false, true><<<dim3(RB, 2), 256, 0, stream>>>(
      h_bf, wgat_t, nullptr, nullptr, nullptr, t0_bf, nullptr, nullptr, nullptr,
      a_src, a_dst, alsrc, aldst, N_NODES, 0);
  k_gat_agg<<<AB, 256, 0, stream>>>(t0_bf, alsrc, aldst, row_ptr, col_src, b_gat, t1b);
  k_bn_stats<<<1024, 256, 0, stream>>>(t1b, bnst + 512);
  k_bn_apply<<<1024, 256, 0, stream>>>(t1b, bnst + 512, bn_g + HID, bn_b + HID, h_bf);

  // --- SAGE: t1b = h@W_r + b_l + mean@W_l (dual, column-split x2) ---
  k_sage_agg<<<AB, 256, 0, stream>>>(h_bf, row_ptr, col_src, t0_bf);
  k_mgemm<256, 256, 2, true, false, false, false><<<dim3(RB, 2), 256, 0, stream>>>(
      h_bf, wr_t, t0_bf, wl_t, b_l, t1b, nullptr, nullptr, nullptr,
      nullptr, nullptr, nullptr, nullptr, N_NODES, 0);
  k_bn_stats<<<1024, 256, 0, stream>>>(t1b, bnst + 1024);
  k_bn_apply<<<1024, 256, 0, stream>>>(t1b, bnst + 1024, bn_g + 2 * HID, bn_b + 2 * HID, h_bf);

  // --- gate (fused GEMM epilogue, atomics) + pooling (inline segment search) ---
  hipMemsetAsync(gate, 0, (size_t)N_NODES * 4, stream);
  k_mgemm<256, 128, 2, false, false, true, false><<<dim3(RB, 2), 256, 0, stream>>>(
      h_bf, wg1_t, nullptr, nullptr, bg1, nullptr, Wg2, bg2, gate,
      nullptr, nullptr, nullptr, nullptr, N_NODES, 1);
  k_pool<<<NG, 256, 0, stream>>>(h_bf, gate, batch, hg);

  // --- heads ---
  k_mlp<<<NG, 256, 0, stream>>>(hg, Wm1, bm1, lnmg, lnmb, Wm2, bm2, out);
  k_mlp<<<NG, 256, 0, stream>>>(hg, Wv1, bv1, lnvg, lnvb, Wv2, bv2, out + (size_t)NG * 64);
}

// Round 17
// 543.712 us; speedup vs baseline: 1.0379x; 1.0027x over previous
//
#include <hip/hip_runtime.h>
#include <cstdint>
#include <cstddef>

#define N_NODES 50000
#define N_EDGES 500000
#define NG 512
#define HID 256
#define EPS 1e-5f
#define SCB 49  // scan blocks: ceil(50000/1024)

typedef __attribute__((ext_vector_type(8))) __bf16 bf16x8;
typedef __attribute__((ext_vector_type(8))) ushort u16x8;
typedef __attribute__((ext_vector_type(4))) float f32x4;

__device__ __forceinline__ ushort f2bf(float f) {
  uint32_t u = __float_as_uint(f);
  uint32_t r = (u + 0x7fffu + ((u >> 16) & 1u)) >> 16;
  return (ushort)r;
}
__device__ __forceinline__ float bfu(ushort u) { return __uint_as_float(((uint32_t)u) << 16); }
__device__ __forceinline__ float4 bf4(ushort4 u) {
  return make_float4(bfu(u.x), bfu(u.y), bfu(u.z), bfu(u.w));
}

// ---------------- CSR build ----------------
__global__ void k_csr_count(const int* __restrict__ ei, int* __restrict__ cnt) {
  int e = blockIdx.x * 256 + threadIdx.x;
  if (e < N_EDGES) atomicAdd(&cnt[ei[N_EDGES + e]], 1);
}

__global__ void k_scan_part(const int* __restrict__ cnt, int* __restrict__ psum) {
  __shared__ int red[256];
  int tid = threadIdx.x;
  int i0 = blockIdx.x * 1024 + tid * 4;
  int s = 0;
  if (i0 + 4 <= N_NODES) {
    int4 v = *reinterpret_cast<const int4*>(cnt + i0);
    s = v.x + v.y + v.z + v.w;
  } else {
    for (int k = 0; k < 4; k++)
      if (i0 + k < N_NODES) s += cnt[i0 + k];
  }
  red[tid] = s;
  __syncthreads();
  for (int o = 128; o > 0; o >>= 1) {
    if (tid < o) red[tid] += red[tid + o];
    __syncthreads();
  }
  if (tid == 0) psum[blockIdx.x] = red[0];
}

__global__ void k_scan_top(const int* __restrict__ psum, int* __restrict__ boff,
                           int* __restrict__ row_ptr) {
  int t = threadIdx.x;  // 64
  int v = (t < SCB) ? psum[t] : 0;
  int own = v;
  for (int o = 1; o < 64; o <<= 1) {
    int u = __shfl_up(v, o);
    if (t >= o) v += u;
  }
  if (t < SCB) boff[t] = v - own;
  if (t == 63) row_ptr[N_NODES] = v;
}

__global__ void k_scan_out(const int* __restrict__ cnt, const int* __restrict__ boff,
                           int* __restrict__ row_ptr, float* __restrict__ dis) {
  __shared__ int ps[256];
  int tid = threadIdx.x;
  int i0 = blockIdx.x * 1024 + tid * 4;
  int v[4];
#pragma unroll
  for (int k = 0; k < 4; k++) v[k] = (i0 + k < N_NODES) ? cnt[i0 + k] : 0;
  int s = v[0] + v[1] + v[2] + v[3];
  ps[tid] = s;
  __syncthreads();
  for (int o = 1; o < 256; o <<= 1) {
    int add = (tid >= o) ? ps[tid - o] : 0;
    __syncthreads();
    ps[tid] += add;
    __syncthreads();
  }
  int run = boff[blockIdx.x] + ((tid > 0) ? ps[tid - 1] : 0);
#pragma unroll
  for (int k = 0; k < 4; k++) {
    if (i0 + k < N_NODES) {
      row_ptr[i0 + k] = run;
      dis[i0 + k] = rsqrtf((float)v[k] + 1.0f);
      run += v[k];
    }
  }
}

__global__ void k_csr_fill(const int* __restrict__ ei, const int* __restrict__ row_ptr,
                           int* __restrict__ fill, int* __restrict__ col_src) {
  int e = blockIdx.x * 256 + threadIdx.x;
  if (e >= N_EDGES) return;
  int s = ei[e], d = ei[N_EDGES + e];
  int pos = row_ptr[d] + atomicAdd(&fill[d], 1);
  col_src[pos] = s;
}

// ---------------- batched weight transpose: W[K,C] fp32 -> Wt[C,K] bf16 ----------------
struct WtArgs {
  const float* src[6];
  ushort* dst[6];
  int K[6];
  int C[6];
  int off[6];
};

__global__ void k_wt_all(WtArgs a) {
  int b = blockIdx.x;
  int ji = 0;
#pragma unroll
  for (int t = 1; t < 6; t++)
    if (b >= a.off[t]) ji = t;
  int K = a.K[ji], C = a.C[ji];
  int i = (b - a.off[ji]) * 256 + threadIdx.x;
  int c = i / K, k = i - c * K;
  a.dst[ji][i] = f2bf(a.src[ji][k * C + c]);
}

// identity fp32 -> bf16 cast (row-major copy), 4 elems/thread
__global__ void k_cast_bf(const float* __restrict__ src, ushort* __restrict__ dst) {
  int i = (blockIdx.x * 256 + threadIdx.x) * 4;
  float4 v = *reinterpret_cast<const float4*>(src + i);
  *reinterpret_cast<ushort4*>(dst + i) =
      make_ushort4(f2bf(v.x), f2bf(v.y), f2bf(v.z), f2bf(v.w));
}

// bc[c] = sum_j b_emb[j] * W_gcn[j][c]   (coalesced: threads c consecutive)
__global__ void k_bvec(const float* __restrict__ b_emb, const float* __restrict__ W_gcn,
                       float* __restrict__ bc) {
  int c = threadIdx.x;
  float s0 = 0.f, s1 = 0.f, s2 = 0.f, s3 = 0.f;
  for (int j = 0; j < 256; j += 4) {
    s0 = fmaf(b_emb[j + 0], W_gcn[(j + 0) * 256 + c], s0);
    s1 = fmaf(b_emb[j + 1], W_gcn[(j + 1) * 256 + c], s1);
    s2 = fmaf(b_emb[j + 2], W_gcn[(j + 2) * 256 + c], s2);
    s3 = fmaf(b_emb[j + 3], W_gcn[(j + 3) * 256 + c], s3);
  }
  bc[c] = (s0 + s1) + (s2 + s3);
}

// ---------------- MFMA GEMM: 64-row blocks, K-split dbuf panels, column-split grid ----------
// out_bf[M,C] = A1@W1t^T (+A2@W2t^T) + bias. Wt [C,K] bf16. Grid: (ceil(M/64), CSPLIT).
// GATE: fused gate head (CSPLIT==1: direct store; else atomicAdd into zeroed gate).
// GATAL: fused attention logits -> als/ald[node][head].
template <int K, int C, int CSPLIT, bool DUAL, bool AFP32, bool GATE, bool GATAL>
__global__ __launch_bounds__(256) void k_mgemm(
    const void* __restrict__ A1v, const ushort* __restrict__ W1t,
    const ushort* __restrict__ A2, const ushort* __restrict__ W2t,
    const float* __restrict__ bias, ushort* __restrict__ out_bf,
    const float* __restrict__ gw, const float* __restrict__ gb,
    float* __restrict__ gate, const float* __restrict__ asv,
    const float* __restrict__ adv, float* __restrict__ als,
    float* __restrict__ ald, int M, int relu) {
  constexpr int KS = K / 32;             // MFMA k-steps total
  constexpr int KSH = KS / 2;            // k-steps per half
  constexpr int KHALF = K / 2;
  constexpr int CHKH = KHALF / 8;        // 16B chunks per col per half
  constexpr int NPAN = C / 64;
  constexpr int NPANL = NPAN / CSPLIT;   // panels per y-block
  constexpr int LOWB = DUAL ? 4 : 2;     // sub-steps per panel
  constexpr int NTOT = NPANL * LOWB;
  constexpr int NISS = (64 * CHKH) / 256;
  constexpr int PELEM = 64 * KHALF;      // ushorts per half-panel buffer
  __shared__ ushort wlds[2 * PELEM];
  const int tid = threadIdx.x;
  const int lane = tid & 63;
  const int wid = tid >> 6;
  const int r16 = lane & 15;
  const int kg = lane >> 4;
  const int rbase = blockIdx.x * 64 + wid * 16;
  const int pbase = blockIdx.y * NPANL;

  int arow = rbase + r16;
  if (arow >= M) arow = M - 1;

  // A fragments, loaded once
  bf16x8 af[KS], af2[KS];
  if constexpr (AFP32) {
    const float* ap = (const float*)A1v + (size_t)arow * K + kg * 8;
#pragma unroll
    for (int ks = 0; ks < KS; ks++) {
      float4 lo = *reinterpret_cast<const float4*>(ap + ks * 32);
      float4 hi = *reinterpret_cast<const float4*>(ap + ks * 32 + 4);
      union { u16x8 u; bf16x8 b; } cv;
      cv.u = (u16x8){f2bf(lo.x), f2bf(lo.y), f2bf(lo.z), f2bf(lo.w),
                     f2bf(hi.x), f2bf(hi.y), f2bf(hi.z), f2bf(hi.w)};
      af[ks] = cv.b;
    }
  } else {
    const ushort* ap = (const ushort*)A1v + (size_t)arow * K + kg * 8;
#pragma unroll
    for (int ks = 0; ks < KS; ks++)
      af[ks] = *reinterpret_cast<const bf16x8*>(ap + ks * 32);
  }
  if constexpr (DUAL) {
    const ushort* ap = A2 + (size_t)arow * K + kg * 8;
#pragma unroll
    for (int ks = 0; ks < KS; ks++)
      af2[ks] = *reinterpret_cast<const bf16x8*>(ap + ks * 32);
  }

  float greg[4] = {0.f, 0.f, 0.f, 0.f};
  f32x4 acc[4];

#define STAGE_ASYNC(WSRC, PAN, KH, BUF)                                        \
  {                                                                            \
    const ushort* base_ = (WSRC) + (size_t)((PAN) * 64) * K + (KH) * KHALF;    \
    _Pragma("unroll") for (int j = 0; j < NISS; j++) {                         \
      int p_ = j * 256 + tid;                                                  \
      int c_ = p_ / CHKH, jj_ = p_ % CHKH;                                     \
      const ushort* g_ = base_ + c_ * K + (jj_ ^ (c_ & 7)) * 8;                \
      ushort* l_ = &wlds[(BUF) * PELEM + (j * 256 + wid * 64) * 8];            \
      __builtin_amdgcn_global_load_lds(                                        \
          (const __attribute__((address_space(1))) void*)(g_),                 \
          (__attribute__((address_space(3))) void*)(l_), 16, 0, 0);            \
    }                                                                          \
  }

#define COMPUTE(AF, KH, BUF)                                                   \
  {                                                                            \
    const ushort* wb_ = &wlds[(BUF) * PELEM];                                  \
    _Pragma("unroll") for (int ct = 0; ct < 4; ct++) {                         \
      bf16x8 wf[KSH];                                                          \
      int colr = ct * 16 + r16;                                                \
      _Pragma("unroll") for (int ksl = 0; ksl < KSH; ksl++) {                  \
        int slot = colr * CHKH + ((ksl * 4 + kg) ^ (r16 & 7));                 \
        wf[ksl] = *reinterpret_cast<const bf16x8*>(&wb_[slot * 8]);            \
      }                                                                        \
      _Pragma("unroll") for (int ksl = 0; ksl < KSH; ksl++)                    \
        acc[ct] = __builtin_amdgcn_mfma_f32_16x16x32_bf16(                     \
            (AF)[(KH) * KSH + ksl], wf[ksl], acc[ct], 0, 0, 0);                \
    }                                                                          \
  }

  // prologue: stage sub-step 0 into buffer 0
  STAGE_ASYNC(W1t, pbase, 0, 0);
  __syncthreads();

#pragma unroll
  for (int q = 0; q < NTOT; q++) {
    const int kh = q & 1;
    const int pass = DUAL ? ((q >> 1) & 1) : 0;
    const int pan = pbase + (DUAL ? (q >> 2) : (q >> 1));
    const int bufq = q & 1;
    const int c0 = pan * 64;
    if ((q & (LOWB - 1)) == 0) {
#pragma unroll
      for (int ct = 0; ct < 4; ct++) acc[ct] = (f32x4){0.f, 0.f, 0.f, 0.f};
    }
    if (q + 1 < NTOT) {
      const int nkh = (q + 1) & 1;
      const int npass = DUAL ? (((q + 1) >> 1) & 1) : 0;
      const int npan = pbase + (DUAL ? ((q + 1) >> 2) : ((q + 1) >> 1));
      const ushort* Wq = (DUAL && npass) ? W2t : W1t;
      STAGE_ASYNC(Wq, npan, nkh, bufq ^ 1);
    }
    if (DUAL && pass) {
      COMPUTE(af2, kh, bufq);
    } else {
      COMPUTE(af, kh, bufq);
    }
    if ((q & (LOWB - 1)) == (LOWB - 1)) {
      if constexpr (GATE) {
#pragma unroll
        for (int ct = 0; ct < 4; ct++) {
          int col = c0 + ct * 16 + r16;
          float bv = bias[col];
          float wv = gw[col];
#pragma unroll
          for (int i = 0; i < 4; i++) {
            float v = fmaxf(acc[ct][i] + bv, 0.f);
            greg[i] = fmaf(v, wv, greg[i]);
          }
        }
      } else {
#pragma unroll
        for (int ct = 0; ct < 4; ct++) {
          int col = c0 + ct * 16 + r16;
          float bv = bias ? bias[col] : 0.f;
#pragma unroll
          for (int i = 0; i < 4; i++) {
            int row = rbase + kg * 4 + i;
            if (row < M) {
              float v = acc[ct][i] + bv;
              if (relu) v = fmaxf(v, 0.f);
              out_bf[(size_t)row * C + col] = f2bf(v);
            }
          }
        }
      }
      if constexpr (GATAL) {
        float ps_[2][4], pd_[2][4];
#pragma unroll
        for (int h2 = 0; h2 < 2; h2++)
#pragma unroll
          for (int i = 0; i < 4; i++) { ps_[h2][i] = 0.f; pd_[h2][i] = 0.f; }
#pragma unroll
        for (int ct = 0; ct < 4; ct++) {
          int col = c0 + ct * 16 + r16;
          float as_ = asv[col], ad_ = adv[col];
          int h2 = ct >> 1;
#pragma unroll
          for (int i = 0; i < 4; i++) {
            ps_[h2][i] = fmaf(acc[ct][i], as_, ps_[h2][i]);
            pd_[h2][i] = fmaf(acc[ct][i], ad_, pd_[h2][i]);
          }
        }
#pragma unroll
        for (int h2 = 0; h2 < 2; h2++)
#pragma unroll
          for (int i = 0; i < 4; i++) {
#pragma unroll
            for (int o = 1; o < 16; o <<= 1) {
              ps_[h2][i] += __shfl_xor(ps_[h2][i], o);
              pd_[h2][i] += __shfl_xor(pd_[h2][i], o);
            }
          }
        if (r16 == 0) {
#pragma unroll
          for (int i = 0; i < 4; i++) {
            int row = rbase + kg * 4 + i;
            if (row < M) {
              als[row * 8 + pan * 2 + 0] = ps_[0][i];
              ald[row * 8 + pan * 2 + 0] = pd_[0][i];
              als[row * 8 + pan * 2 + 1] = ps_[1][i];
              ald[row * 8 + pan * 2 + 1] = pd_[1][i];
            }
          }
        }
      }
    }
    __syncthreads();
  }

  if constexpr (GATE) {
#pragma unroll
    for (int i = 0; i < 4; i++) {
#pragma unroll
      for (int o = 1; o < 16; o <<= 1) greg[i] += __shfl_xor(greg[i], o);
    }
    if (r16 == 0) {
      if constexpr (CSPLIT == 1) {
        float b0 = gb[0];
#pragma unroll
        for (int i = 0; i < 4; i++) {
          int row = rbase + kg * 4 + i;
          if (row < M) gate[row] = greg[i] + b0;
        }
      } else {
        float b0 = (blockIdx.y == 0) ? gb[0] : 0.f;
#pragma unroll
        for (int i = 0; i < 4; i++) {
          int row = rbase + kg * 4 + i;
          if (row < M) atomicAdd(&gate[row], greg[i] + b0);
        }
      }
    }
  }
#undef STAGE_ASYNC
#undef COMPUTE
}

// ---------------- GCN aggregation: wave/node, 32 lanes/row, 8-edge ILP, bf16 out ------------
__global__ void k_gcn_agg(const ushort* __restrict__ xt, const float* __restrict__ dis,
                          const int* __restrict__ row_ptr, const int* __restrict__ col_src,
                          const float* __restrict__ b_gcn, ushort* __restrict__ outb) {
  int node = blockIdx.x * 4 + (threadIdx.x >> 6);
  if (node >= N_NODES) return;
  int lane = threadIdx.x & 63;
  int half = lane >> 5;
  int c0 = (lane & 31) * 8;
  float di = dis[node];
  float acc[8];
#pragma unroll
  for (int j = 0; j < 8; j++) acc[j] = 0.f;
  int b = row_ptr[node], e = row_ptr[node + 1];
  int g0 = b;
  for (; g0 + 8 <= e; g0 += 8) {
    int i0 = g0 + half * 4;
    int s0 = col_src[i0], s1 = col_src[i0 + 1], s2 = col_src[i0 + 2], s3 = col_src[i0 + 3];
    float w0 = di * dis[s0], w1 = di * dis[s1], w2 = di * dis[s2], w3 = di * dis[s3];
    u16x8 u0 = *reinterpret_cast<const u16x8*>(xt + (size_t)s0 * HID + c0);
    u16x8 u1 = *reinterpret_cast<const u16x8*>(xt + (size_t)s1 * HID + c0);
    u16x8 u2 = *reinterpret_cast<const u16x8*>(xt + (size_t)s2 * HID + c0);
    u16x8 u3 = *reinterpret_cast<const u16x8*>(xt + (size_t)s3 * HID + c0);
#pragma unroll
    for (int j = 0; j < 8; j++) {
      acc[j] = fmaf(bfu(u0[j]), w0, acc[j]);
      acc[j] = fmaf(bfu(u1[j]), w1, acc[j]);
      acc[j] = fmaf(bfu(u2[j]), w2, acc[j]);
      acc[j] = fmaf(bfu(u3[j]), w3, acc[j]);
    }
  }
  for (; g0 + 4 <= e; g0 += 4) {
    int i0 = g0 + half * 2;
    int s0 = col_src[i0], s1 = col_src[i0 + 1];
    float w0 = di * dis[s0], w1 = di * dis[s1];
    u16x8 u0 = *reinterpret_cast<const u16x8*>(xt + (size_t)s0 * HID + c0);
    u16x8 u1 = *reinterpret_cast<const u16x8*>(xt + (size_t)s1 * HID + c0);
#pragma unroll
    for (int j = 0; j < 8; j++) {
      acc[j] = fmaf(bfu(u0[j]), w0, acc[j]);
      acc[j] = fmaf(bfu(u1[j]), w1, acc[j]);
    }
  }
  {  // tail (0..3 edges), guarded
    int i0 = g0 + half * 2;
    int s0 = 0, s1 = 0;
    float w0 = 0.f, w1 = 0.f;
    if (i0 < e) { s0 = col_src[i0]; w0 = di * dis[s0]; }
    if (i0 + 1 < e) { s1 = col_src[i0 + 1]; w1 = di * dis[s1]; }
    u16x8 u0 = *reinterpret_cast<const u16x8*>(xt + (size_t)s0 * HID + c0);
    u16x8 u1 = *reinterpret_cast<const u16x8*>(xt + (size_t)s1 * HID + c0);
#pragma unroll
    for (int j = 0; j < 8; j++) {
      acc[j] = fmaf(bfu(u0[j]), w0, acc[j]);
      acc[j] = fmaf(bfu(u1[j]), w1, acc[j]);
    }
  }
#pragma unroll
  for (int j = 0; j < 8; j++) acc[j] += __shfl_xor(acc[j], 32);
  if (!half) {
    u16x8 un = *reinterpret_cast<const u16x8*>(xt + (size_t)node * HID + c0);
    float w0 = di * di;
    u16x8 r;
#pragma unroll
    for (int j = 0; j < 8; j++) {
      float v = fmaf(bfu(un[j]), w0, acc[j]) + b_gcn[c0 + j];
      r[j] = f2bf(v);
    }
    *reinterpret_cast<u16x8*>(outb + (size_t)node * HID + c0) = r;
  }
}

__device__ __forceinline__ float leaky02(float x) { return x > 0.f ? x : 0.2f * x; }

// ---------------- Single-pass GAT agg, 32 lanes/row, 8-edge ILP; al in [node][head] ---------
__global__ void k_gat_agg(const ushort* __restrict__ xt, const float* __restrict__ alsrc,
                          const float* __restrict__ aldst, const int* __restrict__ row_ptr,
                          const int* __restrict__ col_src, const float* __restrict__ b_gat,
                          ushort* __restrict__ outb) {
  int node = blockIdx.x * 4 + (threadIdx.x >> 6);
  if (node >= N_NODES) return;
  int lane = threadIdx.x & 63;
  int half = lane >> 5;
  int l32 = lane & 31;
  int c0 = l32 * 8;
  int hh = l32 >> 2;
  float ad = aldst[node * 8 + hh];
  float acc[8];
#pragma unroll
  for (int j = 0; j < 8; j++) acc[j] = 0.f;
  float s = 0.f;
  int b = row_ptr[node], e = row_ptr[node + 1];
  int g0 = b;
  for (; g0 + 8 <= e; g0 += 8) {
    int i0 = g0 + half * 4;
    int s0 = col_src[i0], s1 = col_src[i0 + 1], s2 = col_src[i0 + 2], s3 = col_src[i0 + 3];
    float g0v = alsrc[s0 * 8 + hh], g1v = alsrc[s1 * 8 + hh];
    float g2v = alsrc[s2 * 8 + hh], g3v = alsrc[s3 * 8 + hh];
    u16x8 u0 = *reinterpret_cast<const u16x8*>(xt + (size_t)s0 * HID + c0);
    u16x8 u1 = *reinterpret_cast<const u16x8*>(xt + (size_t)s1 * HID + c0);
    u16x8 u2 = *reinterpret_cast<const u16x8*>(xt + (size_t)s2 * HID + c0);
    u16x8 u3 = *reinterpret_cast<const u16x8*>(xt + (size_t)s3 * HID + c0);
    float a0 = __expf(leaky02(g0v + ad));
    float a1 = __expf(leaky02(g1v + ad));
    float a2 = __expf(leaky02(g2v + ad));
    float a3 = __expf(leaky02(g3v + ad));
    s += a0 + a1 + a2 + a3;
#pragma unroll
    for (int j = 0; j < 8; j++) {
      acc[j] = fmaf(bfu(u0[j]), a0, acc[j]);
      acc[j] = fmaf(bfu(u1[j]), a1, acc[j]);
      acc[j] = fmaf(bfu(u2[j]), a2, acc[j]);
      acc[j] = fmaf(bfu(u3[j]), a3, acc[j]);
    }
  }
  for (; g0 + 4 <= e; g0 += 4) {
    int i0 = g0 + half * 2;
    int s0 = col_src[i0], s1 = col_src[i0 + 1];
    float a0 = __expf(leaky02(alsrc[s0 * 8 + hh] + ad));
    float a1 = __expf(leaky02(alsrc[s1 * 8 + hh] + ad));
    u16x8 u0 = *reinterpret_cast<const u16x8*>(xt + (size_t)s0 * HID + c0);
    u16x8 u1 = *reinterpret_cast<const u16x8*>(xt + (size_t)s1 * HID + c0);
    s += a0 + a1;
#pragma unroll
    for (int j = 0; j < 8; j++) {
      acc[j] = fmaf(bfu(u0[j]), a0, acc[j]);
      acc[j] = fmaf(bfu(u1[j]), a1, acc[j]);
    }
  }
  {  // tail, guarded
    int i0 = g0 + half * 2;
    int s0 = 0, s1 = 0;
    float a0 = 0.f, a1 = 0.f;
    if (i0 < e) { s0 = col_src[i0]; a0 = __expf(leaky02(alsrc[s0 * 8 + hh] + ad)); }
    if (i0 + 1 < e) { s1 = col_src[i0 + 1]; a1 = __expf(leaky02(alsrc[s1 * 8 + hh] + ad)); }
    u16x8 u0 = *reinterpret_cast<const u16x8*>(xt + (size_t)s0 * HID + c0);
    u16x8 u1 = *reinterpret_cast<const u16x8*>(xt + (size_t)s1 * HID + c0);
    s += a0 + a1;
#pragma unroll
    for (int j = 0; j < 8; j++) {
      acc[j] = fmaf(bfu(u0[j]), a0, acc[j]);
      acc[j] = fmaf(bfu(u1[j]), a1, acc[j]);
    }
  }
#pragma unroll
  for (int j = 0; j < 8; j++) acc[j] += __shfl_xor(acc[j], 32);
  s += __shfl_xor(s, 32);
  if (!half) {
    float e0 = __expf(leaky02(alsrc[node * 8 + hh] + ad));
    u16x8 un = *reinterpret_cast<const u16x8*>(xt + (size_t)node * HID + c0);
    float inv_s = 1.0f / (s + e0);
    u16x8 r;
#pragma unroll
    for (int j = 0; j < 8; j++) {
      float v = fmaf(bfu(un[j]), e0, acc[j]) * inv_s + b_gat[c0 + j];
      r[j] = f2bf(v);
    }
    *reinterpret_cast<u16x8*>(outb + (size_t)node * HID + c0) = r;
  }
}

// ---------------- SAGE mean aggregation: 32 lanes/row, 8-edge ILP, bf16 in/out --------------
__global__ void k_sage_agg(const ushort* __restrict__ h, const int* __restrict__ row_ptr,
                           const int* __restrict__ col_src, ushort* __restrict__ outb) {
  int node = blockIdx.x * 4 + (threadIdx.x >> 6);
  if (node >= N_NODES) return;
  int lane = threadIdx.x & 63;
  int half = lane >> 5;
  int c0 = (lane & 31) * 8;
  float acc[8];
#pragma unroll
  for (int j = 0; j < 8; j++) acc[j] = 0.f;
  int b = row_ptr[node], e = row_ptr[node + 1];
  int g0 = b;
  for (; g0 + 8 <= e; g0 += 8) {
    int i0 = g0 + half * 4;
    int s0 = col_src[i0], s1 = col_src[i0 + 1], s2 = col_src[i0 + 2], s3 = col_src[i0 + 3];
    u16x8 u0 = *reinterpret_cast<const u16x8*>(h + (size_t)s0 * HID + c0);
    u16x8 u1 = *reinterpret_cast<const u16x8*>(h + (size_t)s1 * HID + c0);
    u16x8 u2 = *reinterpret_cast<const u16x8*>(h + (size_t)s2 * HID + c0);
    u16x8 u3 = *reinterpret_cast<const u16x8*>(h + (size_t)s3 * HID + c0);
#pragma unroll
    for (int j = 0; j < 8; j++)
      acc[j] += (bfu(u0[j]) + bfu(u1[j])) + (bfu(u2[j]) + bfu(u3[j]));
  }
  for (; g0 + 4 <= e; g0 += 4) {
    int i0 = g0 + half * 2;
    int s0 = col_src[i0], s1 = col_src[i0 + 1];
    u16x8 u0 = *reinterpret_cast<const u16x8*>(h + (size_t)s0 * HID + c0);
    u16x8 u1 = *reinterpret_cast<const u16x8*>(h + (size_t)s1 * HID + c0);
#pragma unroll
    for (int j = 0; j < 8; j++) acc[j] += bfu(u0[j]) + bfu(u1[j]);
  }
  {
    int i0 = g0 + half * 2;
    int s0 = 0, s1 = 0;
    float w0 = 0.f, w1 = 0.f;
    if (i0 < e) { s0 = col_src[i0]; w0 = 1.f; }
    if (i0 + 1 < e) { s1 = col_src[i0 + 1]; w1 = 1.f; }
    u16x8 u0 = *reinterpret_cast<const u16x8*>(h + (size_t)s0 * HID + c0);
    u16x8 u1 = *reinterpret_cast<const u16x8*>(h + (size_t)s1 * HID + c0);
#pragma unroll
    for (int j = 0; j < 8; j++) {
      acc[j] = fmaf(bfu(u0[j]), w0, acc[j]);
      acc[j] = fmaf(bfu(u1[j]), w1, acc[j]);
    }
  }
#pragma unroll
  for (int j = 0; j < 8; j++) acc[j] += __shfl_xor(acc[j], 32);
  if (!half) {
    float inv = 1.0f / fmaxf((float)(e - b), 1.0f);
    u16x8 r;
#pragma unroll
    for (int j = 0; j < 8; j++) r[j] = f2bf(acc[j] * inv);
    *reinterpret_cast<u16x8*>(outb + (size_t)node * HID + c0) = r;
  }
}

// ---------------- BatchNorm stats: vectorized 16B loads, LDS reduce, 1024 blocks ------------
__global__ __launch_bounds__(256) void k_bn_stats(const ushort* __restrict__ x,
                                                  float* __restrict__ stats) {
  int tid = threadIdx.x;
  int cg = tid & 31;
  int rs = tid >> 5;
  int c0 = cg * 8;
  float s[8], q[8];
#pragma unroll
  for (int j = 0; j < 8; j++) { s[j] = 0.f; q[j] = 0.f; }
  for (int r = blockIdx.x * 8 + rs; r < N_NODES; r += gridDim.x * 8) {
    u16x8 v = *reinterpret_cast<const u16x8*>(x + (size_t)r * HID + c0);
#pragma unroll
    for (int j = 0; j < 8; j++) {
      float f = bfu(v[j]);
      s[j] += f;
      q[j] = fmaf(f, f, q[j]);
    }
  }
  __shared__ float ls[512];
  ls[tid] = 0.f;
  ls[tid + 256] = 0.f;
  __syncthreads();
#pragma unroll
  for (int j = 0; j < 8; j++) {
    atomicAdd(&ls[c0 + j], s[j]);
    atomicAdd(&ls[256 + c0 + j], q[j]);
  }
  __syncthreads();
  atomicAdd(&stats[tid], ls[tid]);
  atomicAdd(&stats[tid + 256], ls[tid + 256]);
}

// h_bf += relu(bn(x)); per-thread column coefs computed once (i&63 is thread-invariant)
__global__ void k_bn_apply(const ushort* __restrict__ x, const float* __restrict__ stats,
                           const float* __restrict__ gamma, const float* __restrict__ beta,
                           ushort* __restrict__ h_bf) {
  int tid = threadIdx.x;
  int c4 = (tid & 63) * 4;
  const float invN = 1.0f / (float)N_NODES;
  float sc[4], sh[4];
#pragma unroll
  for (int j = 0; j < 4; j++) {
    int c = c4 + j;
    float mu = stats[c] * invN;
    float var = stats[256 + c] * invN - mu * mu;
    float s = gamma[c] * rsqrtf(var + EPS);
    sc[j] = s;
    sh[j] = beta[c] - mu * s;
  }
  int total = N_NODES * 64;
  for (int i = blockIdx.x * 256 + tid; i < total; i += gridDim.x * 256) {
    float4 xv = bf4(*reinterpret_cast<const ushort4*>(x + (size_t)i * 4));
    float4 hv = bf4(*reinterpret_cast<const ushort4*>(h_bf + (size_t)i * 4));
    hv.x += fmaxf(fmaf(xv.x, sc[0], sh[0]), 0.f);
    hv.y += fmaxf(fmaf(xv.y, sc[1], sh[1]), 0.f);
    hv.z += fmaxf(fmaf(xv.z, sc[2], sh[2]), 0.f);
    hv.w += fmaxf(fmaf(xv.w, sc[3], sh[3]), 0.f);
    *reinterpret_cast<ushort4*>(h_bf + (size_t)i * 4) =
        make_ushort4(f2bf(hv.x), f2bf(hv.y), f2bf(hv.z), f2bf(hv.w));
  }
}

// ---------------- global attention pooling (bf16 h, inline segment search) ----------------
__global__ void k_pool(const ushort* __restrict__ hb, const float* __restrict__ gate,
                       const int* __restrict__ batch, float* __restrict__ hg) {
  __shared__ float red[256];
  __shared__ float wbuf[256];
  __shared__ int seg[2];
  int g = blockIdx.x, tid = threadIdx.x;
  if (tid < 2) {
    int target = g + tid;
    int lo = 0, hi = N_NODES;
    while (lo < hi) {
      int mid = (lo + hi) >> 1;
      if (batch[mid] < target) lo = mid + 1; else hi = mid;
    }
    seg[tid] = lo;
  }
  __syncthreads();
  int b = seg[0], e = seg[1];
  float m = -1e30f;
  for (int r = b + tid; r < e; r += 256) m = fmaxf(m, gate[r]);
  red[tid] = m;
  __syncthreads();
  for (int o = 128; o > 0; o >>= 1) {
    if (tid < o) red[tid] = fmaxf(red[tid], red[tid + o]);
    __syncthreads();
  }
  m = red[0];
  __syncthreads();
  float s = 0.f;
  for (int r = b + tid; r < e; r += 256) s += __expf(gate[r] - m);
  red[tid] = s;
  __syncthreads();
  for (int o = 128; o > 0; o >>= 1) {
    if (tid < o) red[tid] += red[tid + o];
    __syncthreads();
  }
  float inv = 1.0f / fmaxf(red[0], 1e-16f);
  __syncthreads();
  float acc = 0.f;
  for (int cb = b; cb < e; cb += 256) {
    int r = cb + tid;
    wbuf[tid] = (r < e) ? __expf(gate[r] - m) : 0.f;
    __syncthreads();
    int n = min(256, e - cb);
    for (int j = 0; j < n; j++)
      acc = fmaf(bfu(hb[(size_t)(cb + j) * HID + tid]), wbuf[j], acc);
    __syncthreads();
  }
  hg[(size_t)g * HID + tid] = acc * inv;
}

// ---------------- MLP heads (both in one launch; head = blockIdx.x >> 9) ----------------
__global__ void k_mlp2(const float* __restrict__ hg,
                       const float* __restrict__ W1a, const float* __restrict__ b1a,
                       const float* __restrict__ lga, const float* __restrict__ lba,
                       const float* __restrict__ W2a, const float* __restrict__ b2a,
                       const float* __restrict__ W1b, const float* __restrict__ b1b,
                       const float* __restrict__ lgb, const float* __restrict__ lbb,
                       const float* __restrict__ W2b, const float* __restrict__ b2b,
                       float* __restrict__ out) {
  __shared__ float row[HID];
  __shared__ float z[HID];
  __shared__ float red[HID];
  int head = blockIdx.x >> 9;
  int g = blockIdx.x & (NG - 1);
  int tid = threadIdx.x;
  const float* W1 = head ? W1b : W1a;
  const float* b1 = head ? b1b : b1a;
  const float* lng = head ? lgb : lga;
  const float* lnb = head ? lbb : lba;
  const float* W2 = head ? W2b : W2a;
  const float* b2 = head ? b2b : b2a;
  float* op = out + (size_t)head * NG * 64;
  row[tid] = hg[(size_t)g * HID + tid];
  __syncthreads();
  float acc = b1[tid];
  for (int k = 0; k < HID; k++) acc = fmaf(row[k], W1[(size_t)k * HID + tid], acc);
  red[tid] = acc;
  __syncthreads();
  for (int o = 128; o > 0; o >>= 1) {
    if (tid < o) red[tid] += red[tid + o];
    __syncthreads();
  }
  float mu = red[0] * (1.0f / HID);
  __syncthreads();
  red[tid] = acc * acc;
  __syncthreads();
  for (int o = 128; o > 0; o >>= 1) {
    if (tid < o) red[tid] += red[tid + o];
    __syncthreads();
  }
  float var = red[0] * (1.0f / HID) - mu * mu;
  float zz = (acc - mu) * rsqrtf(var + EPS) * lng[tid] + lnb[tid];
  z[tid] = fmaxf(zz, 0.f);
  __syncthreads();
  if (tid < 64) {
    float o = b2[tid];
    for (int k = 0; k < HID; k++) o = fmaf(z[k], W2[(size_t)k * 64 + tid], o);
    op[(size_t)g * 64 + tid] = o;
  }
}

// ---------------- launch ----------------
extern "C" void kernel_launch(void* const* d_in, const int* in_sizes, int n_in,
                              void* d_out, int out_size, void* d_ws, size_t ws_size,
                              hipStream_t stream) {
  const float* x     = (const float*)d_in[0];
  const float* W_emb = (const float*)d_in[1];
  const float* b_emb = (const float*)d_in[2];
  const float* W_gcn = (const float*)d_in[3];
  const float* b_gcn = (const float*)d_in[4];
  const float* W_gat = (const float*)d_in[5];
  const float* a_src = (const float*)d_in[6];
  const float* a_dst = (const float*)d_in[7];
  const float* b_gat = (const float*)d_in[8];
  const float* W_l   = (const float*)d_in[9];
  const float* b_l   = (const float*)d_in[10];
  const float* W_r   = (const float*)d_in[11];
  const float* bn_g  = (const float*)d_in[12];
  const float* bn_b  = (const float*)d_in[13];
  const float* Wg1   = (const float*)d_in[14];
  const float* bg1   = (const float*)d_in[15];
  const float* Wg2   = (const float*)d_in[16];
  const float* bg2   = (const float*)d_in[17];
  const float* Wm1   = (const float*)d_in[18];
  const float* bm1   = (const float*)d_in[19];
  const float* lnmg  = (const float*)d_in[20];
  const float* lnmb  = (const float*)d_in[21];
  const float* Wm2   = (const float*)d_in[22];
  const float* bm2   = (const float*)d_in[23];
  const float* Wv1   = (const float*)d_in[24];
  const float* bv1   = (const float*)d_in[25];
  const float* lnvg  = (const float*)d_in[26];
  const float* lnvb  = (const float*)d_in[27];
  const float* Wv2   = (const float*)d_in[28];
  const float* bv2   = (const float*)d_in[29];
  const int* ei      = (const int*)d_in[30];
  const int* batch   = (const int*)d_in[31];
  float* out = (float*)d_out;

  float* ws = (float*)d_ws;
  float* h     = ws;                          // spare region
  float* t1    = h + (size_t)N_NODES * HID;   // reused as bf16 t1b
  float* alsrc = t1 + (size_t)N_NODES * HID;  // [N][8]
  float* aldst = alsrc + N_NODES * 8;         // [N][8]
  float* dis   = aldst + N_NODES * 8;
  float* gate  = dis + N_NODES;
  float* hg    = gate + N_NODES;
  float* zbase = hg + NG * HID;
  float* bnst  = zbase;                // 3 * 512
  int* row_cnt = (int*)(zbase + 3 * 512);
  int* fill    = row_cnt + N_NODES;
  int* row_ptr = fill + N_NODES;
  int* col_src = row_ptr + N_NODES + 1;
  int* psum    = col_src + N_EDGES;
  int* boff    = psum + 64;
  float* bc    = (float*)(boff + 64);  // folded GCN bias (256)

  ushort* t1b = (ushort*)t1;

  size_t off = (size_t)((char*)(bc + 256) - (char*)d_ws);
  off = (off + 15) & ~(size_t)15;
  ushort* h_bf   = (ushort*)((char*)d_ws + off);
  ushort* t0_bf  = h_bf + (size_t)N_NODES * HID;
  ushort* wemb_t = t0_bf + (size_t)N_NODES * HID;
  ushort* wgcn_t = wemb_t + 128 * 256;
  ushort* wgat_t = wgcn_t + 256 * 256;
  ushort* wr_t   = wgat_t + 256 * 256;
  ushort* wl_t   = wr_t + 256 * 256;
  ushort* wg1_t  = wl_t + 256 * 256;   // 256*128
  ushort* wembr  = wg1_t + 256 * 128;  // W_emb row-major bf16 [128][256]
  ushort* wc_t   = wembr + 128 * 256;  // folded GCN weight [256][128]

  size_t zbytes = (size_t)3 * 512 * 4 + 2 * (size_t)N_NODES * 4;
  hipMemsetAsync(zbase, 0, zbytes, stream);

  // CSR by dst (hierarchical scan + fused dis)
  k_csr_count<<<(N_EDGES + 255) / 256, 256, 0, stream>>>(ei, row_cnt);
  k_scan_part<<<SCB, 256, 0, stream>>>(row_cnt, psum);
  k_scan_top<<<1, 64, 0, stream>>>(psum, boff, row_ptr);
  k_scan_out<<<SCB, 256, 0, stream>>>(row_cnt, boff, row_ptr, dis);
  k_csr_fill<<<(N_EDGES + 255) / 256, 256, 0, stream>>>(ei, row_ptr, fill, col_src);

  // all weight transposes in one launch
  WtArgs wa;
  wa.src[0] = W_emb; wa.dst[0] = wemb_t; wa.K[0] = 128; wa.C[0] = 256; wa.off[0] = 0;
  wa.src[1] = W_gcn; wa.dst[1] = wgcn_t; wa.K[1] = 256; wa.C[1] = 256; wa.off[1] = 128;
  wa.src[2] = W_gat; wa.dst[2] = wgat_t; wa.K[2] = 256; wa.C[2] = 256; wa.off[2] = 384;
  wa.src[3] = W_r;   wa.dst[3] = wr_t;   wa.K[3] = 256; wa.C[3] = 256; wa.off[3] = 640;
  wa.src[4] = W_l;   wa.dst[4] = wl_t;   wa.K[4] = 256; wa.C[4] = 256; wa.off[4] = 896;
  wa.src[5] = Wg1;   wa.dst[5] = wg1_t;  wa.K[5] = 256; wa.C[5] = 128; wa.off[5] = 1152;
  k_wt_all<<<1280, 256, 0, stream>>>(wa);

  // GCN weight fold: wc_t[c][k] = sum_j W_gcn[j][c]*W_emb[k][j], via MFMA GEMM (M=256)
  k_cast_bf<<<32, 256, 0, stream>>>(W_emb, wembr);
  k_mgemm<256, 128, 1, false, false, false, false><<<dim3(4, 1), 256, 0, stream>>>(
      wgcn_t, wembr, nullptr, nullptr, nullptr, wc_t, nullptr, nullptr, nullptr,
      nullptr, nullptr, nullptr, nullptr, 256, 0);
  k_bvec<<<1, 256, 0, stream>>>(b_emb, W_gcn, bc);

  const int RB = (N_NODES + 63) / 64;   // 782 gemm row-blocks (256 thr)
  const int AB = (N_NODES + 3) / 4;     // 12500 agg blocks

  // embedding: h_bf = x @ W_emb + b_emb  (fp32 A converted on load)
  k_mgemm<128, 256, 1, false, true, false, false><<<dim3(RB, 1), 256, 0, stream>>>(
      x, wemb_t, nullptr, nullptr, b_emb, h_bf, nullptr, nullptr, nullptr,
      nullptr, nullptr, nullptr, nullptr, N_NODES, 0);

  // --- GCN: xt = x @ (W_emb@W_gcn) + b_emb@W_gcn  (K=128, folded) ---
  k_mgemm<128, 256, 1, false, true, false, false><<<dim3(RB, 1), 256, 0, stream>>>(
      x, wc_t, nullptr, nullptr, bc, t0_bf, nullptr, nullptr, nullptr,
      nullptr, nullptr, nullptr, nullptr, N_NODES, 0);
  k_gcn_agg<<<AB, 256, 0, stream>>>(t0_bf, dis, row_ptr, col_src, b_gcn, t1b);
  k_bn_stats<<<1024, 256, 0, stream>>>(t1b, bnst);
  k_bn_apply<<<1024, 256, 0, stream>>>(t1b, bnst, bn_g, bn_b, h_bf);

  // --- GAT (al fused into GEMM epilogue; single-pass softmax in agg) ---
  k_mgemm<256, 256, 2, false, false, false, true><<<dim3(RB, 2), 256, 0, stream>>>(
      h_bf, wgat_t, nullptr, nullptr, nullptr, t0_bf, nullptr, nullptr, nullptr,
      a_src, a_dst, alsrc, aldst, N_NODES, 0);
  k_gat_agg<<<AB, 256, 0, stream>>>(t0_bf, alsrc, aldst, row_ptr, col_src, b_gat, t1b);
  k_bn_stats<<<1024, 256, 0, stream>>>(t1b, bnst + 512);
  k_bn_apply<<<1024, 256, 0, stream>>>(t1b, bnst + 512, bn_g + HID, bn_b + HID, h_bf);

  // --- SAGE: t1b = h@W_r + b_l + mean@W_l (dual, column-split x2) ---
  k_sage_agg<<<AB, 256, 0, stream>>>(h_bf, row_ptr, col_src, t0_bf);
  k_mgemm<256, 256, 2, true, false, false, false><<<dim3(RB, 2), 256, 0, stream>>>(
      h_bf, wr_t, t0_bf, wl_t, b_l, t1b, nullptr, nullptr, nullptr,
      nullptr, nullptr, nullptr, nullptr, N_NODES, 0);
  k_bn_stats<<<1024, 256, 0, stream>>>(t1b, bnst + 1024);
  k_bn_apply<<<1024, 256, 0, stream>>>(t1b, bnst + 1024, bn_g + 2 * HID, bn_b + 2 * HID, h_bf);

  // --- gate (fused GEMM epilogue, direct store) + pooling ---
  k_mgemm<256, 128, 1, false, false, true, false><<<dim3(RB, 1), 256, 0, stream>>>(
      h_bf, wg1_t, nullptr, nullptr, bg1, nullptr, Wg2, bg2, gate,
      nullptr, nullptr, nullptr, nullptr, N_NODES, 1);
  k_pool<<<NG, 256, 0, stream>>>(h_bf, gate, batch, hg);

  // --- heads (both in one launch) ---
  k_mlp2<<<2 * NG, 256, 0, stream>>>(hg, Wm1, bm1, lnmg, lnmb, Wm2, bm2,
                                     Wv1, bv1, lnvg, lnvb, Wv2, bv2, out);
}